// Round 9
// baseline (661.573 us; speedup 1.0000x reference)
//
#include <hip/hip_runtime.h>
#include <cmath>

// ---------------------------------------------------------------------------
// VQ-VAE forward. B=256, C=3, HW=64, D=256, K=8192, LAT=128
// R16: mfmaconv gains OUTBF (packed-bf16 output via B-column permutation:
// slot f*16+l -> channel 4l+f; memory stays natural order). conv2/conv3/
// t1/t2 now write bf16 (a2,a3,g1,g2); conv4 keeps fp32 out (loss precision).
// INBF consumers updated (conv3,conv4,t2,t3). t3 NSTRIP 2->4, t31 4->8.
// R15 gemm_bf_abt, R14 pipelined k-loop, R13 conv1_mfma, R11 convt4 ring,
// R10 multi-strip convt_mfma, R9 packed tail retained.
// ---------------------------------------------------------------------------

#define EPS_BN 1e-5f
typedef unsigned short ushort;
typedef short short8 __attribute__((ext_vector_type(8)));
typedef ushort us4 __attribute__((ext_vector_type(4)));
typedef float f32x4 __attribute__((ext_vector_type(4)));

__device__ __forceinline__ float lrelu(float v) { return v >= 0.f ? v : 0.01f * v; }
__device__ __forceinline__ ushort f2bf(float f) {
  unsigned u = __float_as_uint(f);
  return (ushort)((u + 0x7FFF + ((u >> 16) & 1)) >> 16);
}
__device__ __forceinline__ float bf2f(ushort u) {
  return __uint_as_float(((unsigned)u) << 16);
}

// ======================= weight transposes (once per launch) ===============
// conv (COUT,CIN,3,3) -> bf16 [co_slot][t*CIN+ci]; perm!=0: within each
// 64-channel block, row slot (cr&3)*16+(cr>>2) holds channel cr (OUTBF).
__global__ __launch_bounds__(256) void tr_convw_bf(const float* __restrict__ w,
                                                   ushort* __restrict__ wT,
                                                   int CIN, int COUT, int total,
                                                   int perm) {
  int i = blockIdx.x * 256 + threadIdx.x;
  if (i >= total) return;
  int co = i / (9 * CIN);
  int r = i - co * 9 * CIN;
  int t = r / CIN, ci = r - t * CIN;
  int co_s = co;
  if (perm) {
    const int cr = co & 63;
    co_s = (co - cr) + ((cr & 3) << 4) + (cr >> 2);
  }
  wT[(size_t)co_s * 9 * CIN + r] = f2bf(w[((size_t)co * CIN + ci) * 9 + t]);
}

// convT (CIN,COUT,3,3) -> bf16 parity-concat [p][co_slot][k], OUTBF-permuted
__global__ __launch_bounds__(256) void tr_convtw_bf(const float* __restrict__ w,
                                                    ushort* __restrict__ wT,
                                                    int CIN, int COUT, int total) {
  int i = blockIdx.x * 256 + threadIdx.x;
  if (i >= total) return;
  const int cc = CIN * COUT;
  int p, base, Kp;
  if (i < cc) { p = 0; base = 0; Kp = CIN; }
  else if (i < 3 * cc) { p = 1; base = cc; Kp = 2 * CIN; }
  else if (i < 5 * cc) { p = 2; base = 3 * cc; Kp = 2 * CIN; }
  else { p = 3; base = 5 * cc; Kp = 4 * CIN; }
  const int r = i - base;
  const int co = r / Kp;
  const int q = r - co * Kp;
  const int tix = q / CIN, ci = q - (q / CIN) * CIN;
  const int py = p >> 1, px = p & 1;
  const int nx = px ? 2 : 1;
  const int kyi = tix / nx, kxi = tix - kyi * nx;
  const int ky = py ? (kyi == 0 ? 0 : 2) : 1;
  const int kx = px ? (kxi == 0 ? 0 : 2) : 1;
  const int cr = co & 63;
  const int co_s = (co - cr) + ((cr & 3) << 4) + (cr >> 2);
  wT[base + (size_t)co_s * Kp + q] =
      f2bf(w[((size_t)ci * COUT + co) * 9 + ky * 3 + kx]);
}

// convT (CIN,COUT=32,3,3) -> bf16 [t][co_slot][ci] (tap-major, columns
// PERMUTED so slot f*16+ln15 holds channel 2*ln15+f -> packed bf16 stores)
__global__ __launch_bounds__(256) void tr_convtw_tc(const float* __restrict__ w,
                                                    ushort* __restrict__ wT,
                                                    int CIN, int COUT, int total) {
  int i = blockIdx.x * 256 + threadIdx.x;
  if (i >= total) return;
  int ci = i % CIN;
  int tmp = i / CIN;
  int co = tmp % COUT;
  int t = tmp / COUT;
  const int co_slot = ((co & 1) << 4) | (co >> 1);
  wT[((size_t)t * COUT + co_slot) * CIN + ci] =
      f2bf(w[((size_t)ci * COUT + co) * 9 + t]);
}

// convt4 weights (CIN=32, COUT=3, 3,3) -> per-lane B fragments
__global__ __launch_bounds__(256) void tr_w4(const float* __restrict__ w,
                                             ushort* __restrict__ wT) {
  int i = blockIdx.x * 256 + threadIdx.x;
  if (i >= 4608) return;
  const int s = i >> 9;
  const int l = (i >> 3) & 63;
  const int j = i & 7;
  const int nn = l & 15;
  const int ci = ((l >> 4) << 3) + j;
  const int ty = s / 3, tx = s - ty * 3;
  ushort v = 0;
  if (nn < 3)
    v = f2bf(w[((size_t)ci * 3 + nn) * 9 + (2 - ty) * 3 + (2 - tx)]);
  wT[i] = v;
}

// conv1 weights (32,3,3,3) -> MFMA B fragments, channel-pair permuted
__global__ __launch_bounds__(256) void tr_w1b(const float* __restrict__ w,
                                              ushort* __restrict__ wT) {
  int i = blockIdx.x * 256 + threadIdx.x;
  if (i >= 1024) return;
  const int j = i & 7, l = (i >> 3) & 63, f = i >> 9;
  const int c = 2 * (l & 15) + f;
  const int k = ((l >> 4) << 3) + j;
  ushort v = 0;
  if (k < 27) {
    const int ci = k / 9, r = k - ci * 9;
    v = f2bf(w[((size_t)c * 3 + ci) * 9 + r]);
  }
  wT[i] = v;
}

// a4 NHWC [256,4,4,256] -> NCHW [256,256,4,4]
__global__ __launch_bounds__(256) void tr_a4(const float* __restrict__ in,
                                             float* __restrict__ out) {
  int i = blockIdx.x * 256 + threadIdx.x;
  int n = i >> 12, k = i & 4095;
  out[i] = in[(size_t)(n << 12) + ((k & 15) << 8) + (k >> 4)];
}

// wfc [4096,256] + bfc: permute ROWS from (c,y,x) to (y,x,c)
__global__ __launch_bounds__(256) void tr_fcdec(const float* __restrict__ in,
                                                const float* __restrict__ bin,
                                                float* __restrict__ out,
                                                float* __restrict__ bout) {
  int i = blockIdx.x * 256 + threadIdx.x;
  int k = i >> 8, d = i & 255;
  int kp = (k & 15) * 256 + (k >> 4);
  out[(size_t)kp * 256 + d] = in[i];
  if (d == 0) bout[kp] = bin[k];
}

// ======================= bf16 MFMA implicit-GEMM conv / convT ==============
// R14 pipeline. OUTBF: packed-bf16 output, slot f*16+l = channel 4l+f.
template <int TN, int MODE, int IH, int CIN, int COUT, bool HASN, bool INBF,
          bool OUTBF>
__global__ __launch_bounds__(256) void mfmaconv(
    const float* __restrict__ X, const ushort* __restrict__ WT,
    const float* __restrict__ bias, const float* __restrict__ st, float invN,
    float* __restrict__ Y, float* __restrict__ stOut) {
  constexpr int OH = (MODE == 0) ? IH / 2 : 2 * IH;
  constexpr int NF = TN / 16;
  static_assert(!OUTBF || NF == 4, "OUTBF requires NF==4");
  __shared__ short As[2][64][40];
  __shared__ short Bs[2][TN][40];
  __shared__ float nrm0[HASN ? CIN : 4], nrm1[HASN ? CIN : 4];
  __shared__ float redS[4][TN], redQ[4][TN];
  const int tid = threadIdx.x;
  const int wv = tid >> 6, lane = tid & 63;
  const int quad = lane >> 4, ln15 = tid & 15;
  if (HASN) {
    for (int c = tid; c < CIN; c += 256) {
      float m = st[c] * invN;
      float var = st[256 + c] * invN - m * m;
      float s = rsqrtf(var + EPS_BN);
      nrm0[c] = s;
      nrm1[c] = m * s;
    }
    __syncthreads();
  }
  int py = 0, px = 0, nx = 1, K = 9 * CIN;
  const ushort* W = WT;
  if (MODE == 1) {
    const int pz = blockIdx.z;
    py = pz >> 1;
    px = pz & 1;
    nx = px ? 2 : 1;
    const int ny = py ? 2 : 1;
    K = ny * nx * CIN;
    const int pre[4] = {0, 1, 3, 5};
    W = WT + (size_t)pre[pz] * CIN * COUT;
  }
  const int gyTM = blockIdx.y * 64;
  const int gxTN = blockIdx.x * TN;

  const int sm = tid & 63, skg = (tid >> 6) * 8;
  const int bn = tid >> 2, bkg = (tid & 3) * 8;
  int baseNB, baseIY, baseIX;
  {
    const int gm = gyTM + sm;
    if (MODE == 0) {
      const int ni = gm / (OH * OH), r = gm % (OH * OH);
      baseNB = ni * IH * IH;
      baseIY = 2 * (r / OH) - 1;
      baseIX = 2 * (r % OH) - 1;
    } else {
      const int ni = gm / (IH * IH), r = gm % (IH * IH);
      baseNB = ni * IH * IH;
      baseIY = r / IH;
      baseIX = r % IH;
    }
  }
  f32x4 acc[NF];
#pragma unroll
  for (int f = 0; f < NF; ++f) acc[f] = (f32x4){0.f, 0.f, 0.f, 0.f};

  const int nsteps = K / 32;

  // ---- prologue: stage step 0 into buf 0 ----
  {
    int iy, ix;
    if (MODE == 0) {
      iy = baseIY;
      ix = baseIX;
    } else {
      iy = baseIY + (py ? 1 : 0);
      ix = baseIX + (px ? 1 : 0);
    }
    const bool ok =
        ((unsigned)iy < (unsigned)IH) && ((unsigned)ix < (unsigned)IH);
    float v[8] = {0.f, 0.f, 0.f, 0.f, 0.f, 0.f, 0.f, 0.f};
    if (ok) {
      if constexpr (INBF) {
        const ushort* xp =
            (const ushort*)X + ((size_t)baseNB + iy * IH + ix) * CIN + skg;
        const short8 raw = *(const short8*)xp;
#pragma unroll
        for (int u = 0; u < 8; ++u) v[u] = bf2f((ushort)raw[u]);
      } else {
        const float* xp = &X[((size_t)baseNB + iy * IH + ix) * CIN + skg];
        const float4 va = *(const float4*)xp, vb = *(const float4*)(xp + 4);
        v[0] = va.x; v[1] = va.y; v[2] = va.z; v[3] = va.w;
        v[4] = vb.x; v[5] = vb.y; v[6] = vb.z; v[7] = vb.w;
      }
      if (HASN) {
#pragma unroll
        for (int u = 0; u < 8; ++u)
          v[u] = fmaf(v[u], nrm0[skg + u], -nrm1[skg + u]);
      }
    }
    short8 o;
#pragma unroll
    for (int u = 0; u < 8; ++u) o[u] = (short)f2bf(v[u]);
    *(short8*)&As[0][sm][skg] = o;
    if (tid < TN * 4)
      *(short8*)&Bs[0][bn][bkg] =
          *(const short8*)&W[(size_t)(gxTN + bn) * K + bkg];
  }
  __syncthreads();

  for (int kk = 0; kk < nsteps; ++kk) {
    const int cur = kk & 1, nxt = cur ^ 1;

    // ---- issue next step's global loads into regs ----
    bool okN = false;
    int ci0N = 0;
    short8 rawN;
    float4 vaN, vbN;
    short8 rawBN;
    const bool hasNext = (kk + 1 < nsteps);
    if (hasNext) {
      const int k0n = (kk + 1) * 32;
      const int t = k0n / CIN;
      ci0N = k0n - t * CIN;
      int iy, ix;
      if (MODE == 0) {
        iy = baseIY + t / 3;
        ix = baseIX + (t - (t / 3) * 3);
      } else {
        const int kyi = t / nx, kxi = t - (t / nx) * nx;
        iy = baseIY + ((py && kyi == 0) ? 1 : 0);
        ix = baseIX + ((px && kxi == 0) ? 1 : 0);
      }
      okN = ((unsigned)iy < (unsigned)IH) && ((unsigned)ix < (unsigned)IH);
      if (okN) {
        if constexpr (INBF) {
          const ushort* xp = (const ushort*)X +
                             ((size_t)baseNB + iy * IH + ix) * CIN + ci0N + skg;
          rawN = *(const short8*)xp;
        } else {
          const float* xp =
              &X[((size_t)baseNB + iy * IH + ix) * CIN + ci0N + skg];
          vaN = *(const float4*)xp;
          vbN = *(const float4*)(xp + 4);
        }
      }
      if (tid < TN * 4)
        rawBN = *(const short8*)&W[(size_t)(gxTN + bn) * K + k0n + bkg];
    }

    // ---- MFMAs on buf[cur] ----
    const short8 a = *(const short8*)&As[cur][wv * 16 + ln15][quad * 8];
#pragma unroll
    for (int f = 0; f < NF; ++f) {
      const short8 b = *(const short8*)&Bs[cur][f * 16 + ln15][quad * 8];
      acc[f] = __builtin_amdgcn_mfma_f32_16x16x32_bf16(a, b, acc[f], 0, 0, 0);
    }

    // ---- convert + write next step into buf[nxt] ----
    if (hasNext) {
      float v[8] = {0.f, 0.f, 0.f, 0.f, 0.f, 0.f, 0.f, 0.f};
      if (okN) {
        if constexpr (INBF) {
#pragma unroll
          for (int u = 0; u < 8; ++u) v[u] = bf2f((ushort)rawN[u]);
        } else {
          v[0] = vaN.x; v[1] = vaN.y; v[2] = vaN.z; v[3] = vaN.w;
          v[4] = vbN.x; v[5] = vbN.y; v[6] = vbN.z; v[7] = vbN.w;
        }
        if (HASN) {
          const int c = ci0N + skg;
#pragma unroll
          for (int u = 0; u < 8; ++u)
            v[u] = fmaf(v[u], nrm0[c + u], -nrm1[c + u]);
        }
      }
      short8 o;
#pragma unroll
      for (int u = 0; u < 8; ++u) o[u] = (short)f2bf(v[u]);
      *(short8*)&As[nxt][sm][skg] = o;
      if (tid < TN * 4) *(short8*)&Bs[nxt][bn][bkg] = rawBN;
    }
    __syncthreads();
  }

  size_t maddr[4];
#pragma unroll
  for (int r = 0; r < 4; ++r) {
    const int m = gyTM + wv * 16 + quad * 4 + r;
    if (MODE == 0) {
      const int ni = m / (OH * OH), rr = m % (OH * OH);
      maddr[r] = (((size_t)ni * OH + rr / OH) * OH + rr % OH) * COUT;
    } else {
      const int ni = m / (IH * IH), rr = m % (IH * IH);
      const int oy = 2 * (rr / IH) + py, ox = 2 * (rr % IH) + px;
      maddr[r] = (((size_t)ni * OH + oy) * OH + ox) * COUT;
    }
  }
  if constexpr (OUTBF) {
    // lane owns channels ch0..ch0+3 (slot f*16+l = channel 4l+f)
    const int ch0 = gxTN + 4 * ln15;
    const float b0 = bias[ch0 + 0], b1 = bias[ch0 + 1];
    const float b2 = bias[ch0 + 2], b3 = bias[ch0 + 3];
    ushort* Yb = (ushort*)Y;
    float cS[4] = {0.f, 0.f, 0.f, 0.f}, cQ[4] = {0.f, 0.f, 0.f, 0.f};
#pragma unroll
    for (int r = 0; r < 4; ++r) {
      const float o0 = lrelu(acc[0][r] + b0);
      const float o1 = lrelu(acc[1][r] + b1);
      const float o2 = lrelu(acc[2][r] + b2);
      const float o3 = lrelu(acc[3][r] + b3);
      cS[0] += o0; cQ[0] += o0 * o0;
      cS[1] += o1; cQ[1] += o1 * o1;
      cS[2] += o2; cQ[2] += o2 * o2;
      cS[3] += o3; cQ[3] += o3 * o3;
      uint2 pk;
      pk.x = (unsigned)f2bf(o0) | ((unsigned)f2bf(o1) << 16);
      pk.y = (unsigned)f2bf(o2) | ((unsigned)f2bf(o3) << 16);
      *(uint2*)&Yb[maddr[r] + ch0] = pk;
    }
#pragma unroll
    for (int f = 0; f < 4; ++f) {
      float s_ = cS[f], q_ = cQ[f];
      s_ += __shfl_down(s_, 32); s_ += __shfl_down(s_, 16);
      q_ += __shfl_down(q_, 32); q_ += __shfl_down(q_, 16);
      if (lane < 16) { redS[wv][f * 16 + ln15] = s_; redQ[wv][f * 16 + ln15] = q_; }
    }
    __syncthreads();
    if (tid < TN) {
      float S = redS[0][tid] + redS[1][tid] + redS[2][tid] + redS[3][tid];
      float Q = redQ[0][tid] + redQ[1][tid] + redQ[2][tid] + redQ[3][tid];
      const int ch = gxTN + 4 * (tid & 15) + (tid >> 4);
      atomicAdd(&stOut[ch], S);
      atomicAdd(&stOut[256 + ch], Q);
    }
  } else {
#pragma unroll
    for (int f = 0; f < NF; ++f) {
      const int col = gxTN + f * 16 + ln15;
      const float bv = bias[col];
      float cS = 0.f, cQ = 0.f;
#pragma unroll
      for (int r = 0; r < 4; ++r) {
        const float o = lrelu(acc[f][r] + bv);
        cS += o;
        cQ += o * o;
        Y[maddr[r] + col] = o;
      }
      cS += __shfl_down(cS, 32); cS += __shfl_down(cS, 16);
      cQ += __shfl_down(cQ, 32); cQ += __shfl_down(cQ, 16);
      if (lane < 16) { redS[wv][f * 16 + ln15] = cS; redQ[wv][f * 16 + ln15] = cQ; }
    }
    __syncthreads();
    if (tid < TN) {
      float S = redS[0][tid] + redS[1][tid] + redS[2][tid] + redS[3][tid];
      float Q = redQ[0][tid] + redQ[1][tid] + redQ[2][tid] + redQ[3][tid];
      atomicAdd(&stOut[gxTN + tid], S);
      atomicAdd(&stOut[256 + gxTN + tid], Q);
    }
  }
}

// ======================= bf16 MFMA dense GEMM: C = alpha*(A.B^T) + bias ====
__global__ __launch_bounds__(256) void gemm_bf_abt(
    const float* __restrict__ A, const float* __restrict__ B,
    const float* __restrict__ bias, float* __restrict__ C, int K, int N,
    float alpha) {
  __shared__ short As[2][64][40];
  __shared__ short Bs[2][64][40];
  const int tid = threadIdx.x;
  const int wv = tid >> 6, lane = tid & 63;
  const int quad = lane >> 4, ln15 = lane & 15;
  const int gm0 = blockIdx.y * 64, gn0 = blockIdx.x * 64;
  const int sm = tid & 63, skg = (tid >> 6) * 8;
  const int bn = tid >> 2, bkg = (tid & 3) * 8;
  const float* Ap = A + (size_t)(gm0 + sm) * K + skg;
  const float* Bp = B + (size_t)(gn0 + bn) * K + bkg;
  f32x4 acc[4];
#pragma unroll
  for (int f = 0; f < 4; ++f) acc[f] = (f32x4){0.f, 0.f, 0.f, 0.f};
  const int nsteps = K / 32;

  {
    const float4 va = *(const float4*)Ap, vb = *(const float4*)(Ap + 4);
    short8 o;
    o[0] = (short)f2bf(va.x); o[1] = (short)f2bf(va.y);
    o[2] = (short)f2bf(va.z); o[3] = (short)f2bf(va.w);
    o[4] = (short)f2bf(vb.x); o[5] = (short)f2bf(vb.y);
    o[6] = (short)f2bf(vb.z); o[7] = (short)f2bf(vb.w);
    *(short8*)&As[0][sm][skg] = o;
    const float4 wa = *(const float4*)Bp, wb = *(const float4*)(Bp + 4);
    short8 p;
    p[0] = (short)f2bf(wa.x); p[1] = (short)f2bf(wa.y);
    p[2] = (short)f2bf(wa.z); p[3] = (short)f2bf(wa.w);
    p[4] = (short)f2bf(wb.x); p[5] = (short)f2bf(wb.y);
    p[6] = (short)f2bf(wb.z); p[7] = (short)f2bf(wb.w);
    *(short8*)&Bs[0][bn][bkg] = p;
  }
  __syncthreads();

  for (int kk = 0; kk < nsteps; ++kk) {
    const int cur = kk & 1, nxt = cur ^ 1;
    const bool hasNext = (kk + 1 < nsteps);
    float4 vaN, vbN, waN, wbN;
    if (hasNext) {
      const int k0n = (kk + 1) * 32;
      vaN = *(const float4*)(Ap + k0n);
      vbN = *(const float4*)(Ap + k0n + 4);
      waN = *(const float4*)(Bp + k0n);
      wbN = *(const float4*)(Bp + k0n + 4);
    }

    const short8 a = *(const short8*)&As[cur][wv * 16 + ln15][quad * 8];
#pragma unroll
    for (int f = 0; f < 4; ++f) {
      const short8 b = *(const short8*)&Bs[cur][f * 16 + ln15][quad * 8];
      acc[f] = __builtin_amdgcn_mfma_f32_16x16x32_bf16(a, b, acc[f], 0, 0, 0);
    }

    if (hasNext) {
      short8 o;
      o[0] = (short)f2bf(vaN.x); o[1] = (short)f2bf(vaN.y);
      o[2] = (short)f2bf(vaN.z); o[3] = (short)f2bf(vaN.w);
      o[4] = (short)f2bf(vbN.x); o[5] = (short)f2bf(vbN.y);
      o[6] = (short)f2bf(vbN.z); o[7] = (short)f2bf(vbN.w);
      *(short8*)&As[nxt][sm][skg] = o;
      short8 p;
      p[0] = (short)f2bf(waN.x); p[1] = (short)f2bf(waN.y);
      p[2] = (short)f2bf(waN.z); p[3] = (short)f2bf(waN.w);
      p[4] = (short)f2bf(wbN.x); p[5] = (short)f2bf(wbN.y);
      p[6] = (short)f2bf(wbN.z); p[7] = (short)f2bf(wbN.w);
      *(short8*)&Bs[nxt][bn][bkg] = p;
    }
    __syncthreads();
  }

#pragma unroll
  for (int f = 0; f < 4; ++f) {
    const int col = gn0 + f * 16 + ln15;
    const float bv = bias[col];
#pragma unroll
    for (int r = 0; r < 4; ++r) {
      const int row = gm0 + wv * 16 + quad * 4 + r;
      C[(size_t)row * N + col] = fmaf(alpha, acc[f][r], bv);
    }
  }
}

// ======================= halo-tile merged convT (COUT=32, CIN<=64) =========
template <int IH, int CIN, bool HASN, bool INBF, int NSTRIP>
__global__ __launch_bounds__(256) void convt_mfma(
    const float* __restrict__ X, const ushort* __restrict__ WT,
    const float* __restrict__ bias, const float* __restrict__ st, float invN,
    float* __restrict__ Y, float* __restrict__ stOut) {
  constexpr int OH = 2 * IH;
  constexpr int L = (IH == 32) ? 5 : 4;
  constexpr int RSPAN = 64 / IH;
  constexpr int NP = (RSPAN + 1) * (IH + 1);
  constexpr int LK = CIN + 8;
  constexpr int TI = NP * (CIN / 8);
  constexpr int ITER = (TI + 255) / 256;
  __shared__ short As[2][NP][LK];
  __shared__ short Ws[9 * 32][LK];
  __shared__ float nrm0[HASN ? CIN : 4], nrm1[HASN ? CIN : 4];
  __shared__ float redS[4][32], redQ[4][32];
  const int tid = threadIdx.x;
  const int wv = tid >> 6, lane = tid & 63;
  const int quad = lane >> 4, ln15 = lane & 15;
  if (HASN) {
    for (int c = tid; c < CIN; c += 256) {
      float m = st[c] * invN;
      float var = st[256 + c] * invN - m * m;
      float s = rsqrtf(var + EPS_BN);
      nrm0[c] = s;
      nrm1[c] = m * s;
    }
  }
  for (int i = tid; i < 9 * 32 * (CIN / 8); i += 256) {
    const int row = i / (CIN / 8), kg = (i % (CIN / 8)) * 8;
    *(short8*)&Ws[row][kg] = *(const short8*)&WT[(size_t)row * CIN + kg];
  }
  __syncthreads();

  const int strip0 = blockIdx.x * NSTRIP;
  const int n = (strip0 * 64) / (IH * IH);
  const int iy0base = (strip0 * 64 - n * (IH * IH)) >> L;

#pragma unroll
  for (int it = 0; it < ITER; ++it) {
    const int i = tid + it * 256;
    if (i < TI) {
      const int slot = i / (CIN / 8), kg = (i % (CIN / 8)) * 8;
      const int ty = slot / (IH + 1), tx = slot - ty * (IH + 1);
      const int iy = iy0base + ty;
      short8 o = {0, 0, 0, 0, 0, 0, 0, 0};
      if (iy < IH && tx < IH) {
        float v[8];
        if constexpr (INBF) {
          const ushort* xp =
              (const ushort*)X + (((size_t)n * IH + iy) * IH + tx) * CIN + kg;
          const short8 raw = *(const short8*)xp;
#pragma unroll
          for (int u = 0; u < 8; ++u) v[u] = bf2f((ushort)raw[u]);
        } else {
          const float* xp = &X[(((size_t)n * IH + iy) * IH + tx) * CIN + kg];
          const float4 va = *(const float4*)xp, vb = *(const float4*)(xp + 4);
          v[0] = va.x; v[1] = va.y; v[2] = va.z; v[3] = va.w;
          v[4] = vb.x; v[5] = vb.y; v[6] = vb.z; v[7] = vb.w;
        }
        if (HASN) {
#pragma unroll
          for (int u = 0; u < 8; ++u)
            v[u] = fmaf(v[u], nrm0[kg + u], -nrm1[kg + u]);
        }
#pragma unroll
        for (int u = 0; u < 8; ++u) o[u] = (short)f2bf(v[u]);
      }
      *(short8*)&As[0][slot][kg] = o;
    }
  }
  __syncthreads();

  const int rA = wv * 16 + ln15;
  const int baseIdx = (rA >> L) * (IH + 1) + (rA & (IH - 1));
  constexpr int NT[4] = {4, 2, 2, 1};
  constexpr int TT[4][4] = {{4, 5, 7, 8}, {3, 6, 0, 0}, {1, 2, 0, 0}, {0, 0, 0, 0}};
  const float bv0 = bias[2 * ln15], bv1 = bias[2 * ln15 + 1];
  unsigned* Yp = (unsigned*)Y;
  float cS[2] = {0.f, 0.f}, cQ[2] = {0.f, 0.f};

#pragma unroll
  for (int s = 0; s < NSTRIP; ++s) {
    const int cur = s & 1, nxt = cur ^ 1;
    const int iy0 = iy0base + s * RSPAN;

    short8 rbf[ITER];
    float4 rva[ITER], rvb[ITER];
    bool vld[ITER];
    if (s + 1 < NSTRIP) {
      const int iyN0 = iy0 + RSPAN;
#pragma unroll
      for (int it = 0; it < ITER; ++it) {
        vld[it] = false;
        const int i = tid + it * 256;
        if (i < TI) {
          const int slot = i / (CIN / 8), kg = (i % (CIN / 8)) * 8;
          const int ty = slot / (IH + 1), tx = slot - ty * (IH + 1);
          const int iy = iyN0 + ty;
          if (iy < IH && tx < IH) {
            vld[it] = true;
            if constexpr (INBF) {
              const ushort* xp = (const ushort*)X +
                                 (((size_t)n * IH + iy) * IH + tx) * CIN + kg;
              rbf[it] = *(const short8*)xp;
            } else {
              const float* xp =
                  &X[(((size_t)n * IH + iy) * IH + tx) * CIN + kg];
              rva[it] = *(const float4*)xp;
              rvb[it] = *(const float4*)(xp + 4);
            }
          }
        }
      }
    }

    f32x4 acc[4][2];
#pragma unroll
    for (int p = 0; p < 4; ++p)
#pragma unroll
      for (int f = 0; f < 2; ++f) acc[p][f] = (f32x4){0.f, 0.f, 0.f, 0.f};
#pragma unroll
    for (int sh = 0; sh < 4; ++sh) {
      const int off = (sh >> 1) * (IH + 1) + (sh & 1);
#pragma unroll
      for (int j = 0; j < NT[sh]; ++j) {
        const int t = TT[sh][j];
        const int ky = t / 3, kx = t - ky * 3;
        const int par = ((ky == 1) ? 0 : 2) + ((kx == 1) ? 0 : 1);
#pragma unroll
        for (int ks = 0; ks < CIN / 32; ++ks) {
          const short8 a =
              *(const short8*)&As[cur][baseIdx + off][ks * 32 + quad * 8];
#pragma unroll
          for (int f = 0; f < 2; ++f) {
            const short8 b =
                *(const short8*)&Ws[t * 32 + f * 16 + ln15][ks * 32 + quad * 8];
            acc[par][f] = __builtin_amdgcn_mfma_f32_16x16x32_bf16(
                a, b, acc[par][f], 0, 0, 0);
          }
        }
      }
    }

#pragma unroll
    for (int i = 0; i < 4; ++i) {
      const int rD = wv * 16 + quad * 4 + i;
      const int ry = rD >> L, rx = rD & (IH - 1);
      const int iy = iy0 + ry;
#pragma unroll
      for (int p = 0; p < 4; ++p) {
        const int a = p >> 1, b = p & 1;
        const size_t base =
            (((size_t)n * OH + 2 * iy + a) * OH + 2 * rx + b) * 32;
        const float o0 = lrelu(acc[p][0][i] + bv0);
        const float o1 = lrelu(acc[p][1][i] + bv1);
        cS[0] += o0; cQ[0] += o0 * o0;
        cS[1] += o1; cQ[1] += o1 * o1;
        Yp[(base >> 1) + ln15] = (unsigned)f2bf(o0) | ((unsigned)f2bf(o1) << 16);
      }
    }

    if (s + 1 < NSTRIP) {
#pragma unroll
      for (int it = 0; it < ITER; ++it) {
        const int i = tid + it * 256;
        if (i < TI) {
          const int slot = i / (CIN / 8), kg = (i % (CIN / 8)) * 8;
          short8 o = {0, 0, 0, 0, 0, 0, 0, 0};
          if (vld[it]) {
            float v[8];
            if constexpr (INBF) {
#pragma unroll
              for (int u = 0; u < 8; ++u) v[u] = bf2f((ushort)rbf[it][u]);
            } else {
              v[0] = rva[it].x; v[1] = rva[it].y;
              v[2] = rva[it].z; v[3] = rva[it].w;
              v[4] = rvb[it].x; v[5] = rvb[it].y;
              v[6] = rvb[it].z; v[7] = rvb[it].w;
            }
            if (HASN) {
#pragma unroll
              for (int u = 0; u < 8; ++u)
                v[u] = fmaf(v[u], nrm0[kg + u], -nrm1[kg + u]);
            }
#pragma unroll
            for (int u = 0; u < 8; ++u) o[u] = (short)f2bf(v[u]);
          }
          *(short8*)&As[nxt][slot][kg] = o;
        }
      }
    }
    __syncthreads();
  }

#pragma unroll
  for (int f = 0; f < 2; ++f) {
    float s_ = cS[f], q_ = cQ[f];
    s_ += __shfl_down(s_, 32); s_ += __shfl_down(s_, 16);
    q_ += __shfl_down(q_, 32); q_ += __shfl_down(q_, 16);
    if (lane < 16) { redS[wv][f * 16 + ln15] = s_; redQ[wv][f * 16 + ln15] = q_; }
  }
  __syncthreads();
  if (tid < 32) {
    float S = redS[0][tid] + redS[1][tid] + redS[2][tid] + redS[3][tid];
    float Q = redQ[0][tid] + redQ[1][tid] + redQ[2][tid] + redQ[3][tid];
    const int ch = ((tid & 15) << 1) | (tid >> 4);
    atomicAdd(&stOut[ch], S);
    atomicAdd(&stOut[256 + ch], Q);
  }
}

// ======================= conv1 via MFMA im2col =============================
__global__ __launch_bounds__(256) void conv1_mfma(
    const float* __restrict__ x, const ushort* __restrict__ WT,
    const float* __restrict__ bias, ushort* __restrict__ y,
    float* __restrict__ st) {
  __shared__ float xin[3][17][67];
  __shared__ float redS[4][32], redQ[4][32];
  const int tid = threadIdx.x;
  const int wv = tid >> 6, lane = tid & 63;
  const int quad = lane >> 4, ln15 = lane & 15;
  const short8 bf0 = *(const short8*)&WT[(size_t)lane * 8];
  const short8 bf1 = *(const short8*)&WT[(size_t)(64 + lane) * 8];
  const int n = blockIdx.x >> 2;
  const int oy0 = (blockIdx.x & 3) * 8;
  const int iy0 = 2 * oy0 - 1;
  if (tid < 51) {
    const int ci = tid / 17, r = tid - ci * 17;
    xin[ci][r][0] = 0.f;
  }
  for (int i = tid; i < 816; i += 256) {
    const int ci = i / 272;
    const int r = (i - ci * 272) >> 4;
    const int c4 = (i & 15) << 2;
    const int iy = iy0 + r;
    float4 v = make_float4(0.f, 0.f, 0.f, 0.f);
    if ((unsigned)iy < 64u)
      v = *(const float4*)&x[((size_t)(n * 3 + ci) * 64 + iy) * 64 + c4];
    xin[ci][r][1 + c4] = v.x;
    xin[ci][r][2 + c4] = v.y;
    xin[ci][r][3 + c4] = v.z;
    xin[ci][r][4 + c4] = v.w;
  }
  __syncthreads();

  const float bv0 = bias[2 * ln15], bv1 = bias[2 * ln15 + 1];
  unsigned* Yp = (unsigned*)y;
  float cS[2] = {0.f, 0.f}, cQ[2] = {0.f, 0.f};
#pragma unroll
  for (int rr = 0; rr < 2; ++rr) {
    const int row = 2 * wv + rr;
#pragma unroll
    for (int h = 0; h < 2; ++h) {
      short8 a;
#pragma unroll
      for (int j = 0; j < 8; ++j) {
        const int k = quad * 8 + j;
        float val = 0.f;
        if (k < 27) {
          const int ci = k / 9, r2 = k - ci * 9;
          const int ky = r2 / 3, kx = r2 - ky * 3;
          val = xin[ci][2 * row + ky][2 * (h * 16 + ln15) + kx];
        }
        a[j] = (short)f2bf(val);
      }
      f32x4 acc0 = (f32x4){0.f, 0.f, 0.f, 0.f};
      f32x4 acc1 = (f32x4){0.f, 0.f, 0.f, 0.f};
      acc0 = __builtin_amdgcn_mfma_f32_16x16x32_bf16(a, bf0, acc0, 0, 0, 0);
      acc1 = __builtin_amdgcn_mfma_f32_16x16x32_bf16(a, bf1, acc1, 0, 0, 0);
#pragma unroll
      for (int r = 0; r < 4; ++r) {
        const int px = h * 16 + quad * 4 + r;
        const float o0 = lrelu(acc0[r] + bv0);
        const float o1 = lrelu(acc1[r] + bv1);
        cS[0] += o0; cQ[0] += o0 * o0;
        cS[1] += o1; cQ[1] += o1 * o1;
        Yp[((size_t)n * 1024 + (oy0 + row) * 32 + px) * 16 + ln15] =
            (unsigned)f2bf(o0) | ((unsigned)f2bf(o1) << 16);
      }
    }
  }
#pragma unroll
  for (int f = 0; f < 2; ++f) {
    float s_ = cS[f], q_ = cQ[f];
    s_ += __shfl_down(s_, 32); s_ += __shfl_down(s_, 16);
    q_ += __shfl_down(q_, 32); q_ += __shfl_down(q_, 16);
    if (lane < 16) { redS[wv][f * 16 + ln15] = s_; redQ[wv][f * 16 + ln15] = q_; }
  }
  __syncthreads();
  if (tid < 32) {
    float S = redS[0][tid] + redS[1][tid] + redS[2][tid] + redS[3][tid];
    float Q = redQ[0][tid] + redQ[1][tid] + redQ[2][tid] + redQ[3][tid];
    const int ch = ((tid & 15) << 1) | (tid >> 4);
    atomicAdd(&st[ch], S);
    atomicAdd(&st[256 + ch], Q);
  }
}

// ======================= final convT via MFMA + 4-row LDS ring =============
__global__ __launch_bounds__(256) void convt4_mfma(
    const float* __restrict__ X, const ushort* __restrict__ WT,
    const float* __restrict__ bias, const float* __restrict__ st, float invN,
    float* __restrict__ out) {
  __shared__ short ring[4][66][32];
  __shared__ float s0[32], s1[32];
  const int tid = threadIdx.x;
  const int wv = tid >> 6, lane = tid & 63;
  const int quad = lane >> 4, ln15 = lane & 15;
  if (tid < 32) {
    float m = st[tid] * invN;
    float var = st[256 + tid] * invN - m * m;
    float s = rsqrtf(var + EPS_BN);
    s0[tid] = s;
    s1[tid] = m * s;
  }
  if (tid >= 32 && tid < 64) {
    const int t = tid - 32;
    const int slot = t >> 3, h = (t >> 2) & 1, kg = (t & 3) * 8;
    short8 z = {0, 0, 0, 0, 0, 0, 0, 0};
    *(short8*)&ring[slot][h ? 65 : 0][kg] = z;
  }
  short8 bfrag[9];
#pragma unroll
  for (int s = 0; s < 9; ++s)
    bfrag[s] = *(const short8*)&WT[((size_t)s * 64 + lane) * 8];
  __syncthreads();

  const int n = blockIdx.x >> 2;
  const int y0 = (blockIdx.x & 3) * 16;
  const ushort* xn = (const ushort*)X + (size_t)n * 131072;
  const int spx = tid >> 2, skg = (tid & 3) * 8;

#pragma unroll
  for (int pr = 0; pr < 3; ++pr) {
    const int Y = y0 - 1 + pr;
    short8 o = {0, 0, 0, 0, 0, 0, 0, 0};
    if ((unsigned)Y < 64u) {
      const short8 raw = *(const short8*)&xn[((size_t)Y * 64 + spx) * 32 + skg];
#pragma unroll
      for (int u = 0; u < 8; ++u)
        o[u] = (short)f2bf(fmaf(bf2f((ushort)raw[u]), s0[skg + u], -s1[skg + u]));
    }
    *(short8*)&ring[Y & 3][spx + 1][skg] = o;
  }
  __syncthreads();

  const int x0 = wv * 16;
  const float bv = (ln15 < 3) ? bias[ln15] : 0.f;
  float* op = out + (size_t)n * 3 * 4096;

  for (int y = y0; y < y0 + 16; ++y) {
    const int Ypf = y + 2;
    const bool pre = (Ypf <= y0 + 16);
    short8 raw;
    bool vld = false;
    if (pre && (unsigned)Ypf < 64u) {
      raw = *(const short8*)&xn[((size_t)Ypf * 64 + spx) * 32 + skg];
      vld = true;
    }

    f32x4 acc0 = (f32x4){0.f, 0.f, 0.f, 0.f};
    f32x4 acc1 = (f32x4){0.f, 0.f, 0.f, 0.f};
#pragma unroll
    for (int ty = 0; ty < 3; ++ty) {
      const short* rp = &ring[(y - 1 + ty) & 3][0][0];
#pragma unroll
      for (int tx = 0; tx < 3; ++tx) {
        const short8 a = *(const short8*)&rp[(x0 + ln15 + tx) * 32 + quad * 8];
        const int s = ty * 3 + tx;
        if (s & 1)
          acc1 = __builtin_amdgcn_mfma_f32_16x16x32_bf16(a, bfrag[s], acc1, 0, 0, 0);
        else
          acc0 = __builtin_amdgcn_mfma_f32_16x16x32_bf16(a, bfrag[s], acc0, 0, 0, 0);
      }
    }

    if (ln15 < 3) {
      float4 o;
      float v;
      v = acc0[0] + acc1[0] + bv; o.x = 1.f / (1.f + __expf(-2.f * v));
      v = acc0[1] + acc1[1] + bv; o.y = 1.f / (1.f + __expf(-2.f * v));
      v = acc0[2] + acc1[2] + bv; o.z = 1.f / (1.f + __expf(-2.f * v));
      v = acc0[3] + acc1[3] + bv; o.w = 1.f / (1.f + __expf(-2.f * v));
      *(float4*)&op[(size_t)ln15 * 4096 + y * 64 + x0 + quad * 4] = o;
    }

    if (pre) {
      short8 o = {0, 0, 0, 0, 0, 0, 0, 0};
      if (vld) {
#pragma unroll
        for (int u = 0; u < 8; ++u)
          o[u] = (short)f2bf(
              fmaf(bf2f((ushort)raw[u]), s0[skg + u], -s1[skg + u]));
      }
      *(short8*)&ring[Ypf & 3][spx + 1][skg] = o;
    }
    __syncthreads();
  }
}

// ======================= dense GEMM (encoder FC), fp32 =====================
__global__ __launch_bounds__(256) void gemm_abt(
    const float* __restrict__ A, const float* __restrict__ B,
    const float* __restrict__ bias, const float* __restrict__ stA, float invN,
    float* __restrict__ C, float* __restrict__ P, int K, int ldc, int col0,
    float alpha, int act) {
  __shared__ float As[16][68];
  __shared__ float Bsh[16][68];
  __shared__ float nrm[2][256];
  const int tid = threadIdx.x;
  if (stA) {
    const int c = tid;
    float m = stA[c] * invN;
    float var = stA[256 + c] * invN - m * m;
    float s = rsqrtf(var + EPS_BN);
    nrm[0][c] = s;
    nrm[1][c] = m * s;
    __syncthreads();
  }
  const int lm = tid >> 2, lk = (tid & 3) << 2;
  const int KS = gridDim.z;
  const int kChunk = K / KS;
  const int kStart = blockIdx.z * kChunk;
  const float* Arow = A + (size_t)(blockIdx.y * 64 + lm) * K + lk;
  const float* Brow = B + (size_t)(blockIdx.x * 64 + lm) * K + lk;
  float acc[4][4] = {};
  const int m0 = (tid >> 4) << 2, n0 = (tid & 15) << 2;

  for (int k0 = kStart; k0 < kStart + kChunk; k0 += 16) {
    float4 av = *(const float4*)(Arow + k0);
    float4 bv = *(const float4*)(Brow + k0);
    if (stA) {
      const int ch = (k0 + lk) >> 4;
      const float s = nrm[0][ch], ms = nrm[1][ch];
      av.x = fmaf(av.x, s, -ms);
      av.y = fmaf(av.y, s, -ms);
      av.z = fmaf(av.z, s, -ms);
      av.w = fmaf(av.w, s, -ms);
    }
    As[lk + 0][lm] = av.x; As[lk + 1][lm] = av.y;
    As[lk + 2][lm] = av.z; As[lk + 3][lm] = av.w;
    Bsh[lk + 0][lm] = bv.x; Bsh[lk + 1][lm] = bv.y;
    Bsh[lk + 2][lm] = bv.z; Bsh[lk + 3][lm] = bv.w;
    __syncthreads();
#pragma unroll
    for (int kk = 0; kk < 16; ++kk) {
      const float4 a = *(const float4*)&As[kk][m0];
      const float4 b = *(const float4*)&Bsh[kk][n0];
      acc[0][0] = fmaf(a.x, b.x, acc[0][0]); acc[0][1] = fmaf(a.x, b.y, acc[0][1]);
      acc[0][2] = fmaf(a.x, b.z, acc[0][2]); acc[0][3] = fmaf(a.x, b.w, acc[0][3]);
      acc[1][0] = fmaf(a.y, b.x, acc[1][0]); acc[1][1] = fmaf(a.y, b.y, acc[1][1]);
      acc[1][2] = fmaf(a.y, b.z, acc[1][2]); acc[1][3] = fmaf(a.y, b.w, acc[1][3]);
      acc[2][0] = fmaf(a.z, b.x, acc[2][0]); acc[2][1] = fmaf(a.z, b.y, acc[2][1]);
      acc[2][2] = fmaf(a.z, b.z, acc[2][2]); acc[2][3] = fmaf(a.z, b.w, acc[2][3]);
      acc[3][0] = fmaf(a.w, b.x, acc[3][0]); acc[3][1] = fmaf(a.w, b.y, acc[3][1]);
      acc[3][2] = fmaf(a.w, b.z, acc[3][2]); acc[3][3] = fmaf(a.w, b.w, acc[3][3]);
    }
    __syncthreads();
  }

  const int gm = blockIdx.y * 64 + m0;
  const int gn = blockIdx.x * 64 + n0;
  if (KS == 1) {
#pragma unroll
    for (int i = 0; i < 4; ++i) {
      float4 o;
      o.x = alpha * acc[i][0] + bias[gn + 0];
      o.y = alpha * acc[i][1] + bias[gn + 1];
      o.z = alpha * acc[i][2] + bias[gn + 2];
      o.w = alpha * acc[i][3] + bias[gn + 3];
      if (act == 1) {
        o.x = fmaxf(o.x, 0.f); o.y = fmaxf(o.y, 0.f);
        o.z = fmaxf(o.z, 0.f); o.w = fmaxf(o.w, 0.f);
      }
      *(float4*)&C[(size_t)(gm + i) * ldc + col0 + gn] = o;
    }
  } else {
    const int M = gridDim.y * 64, N = gridDim.x * 64;
#pragma unroll
    for (int i = 0; i < 4; ++i)
      *(float4*)&P[((size_t)blockIdx.z * M + gm + i) * N + gn] =
          make_float4(acc[i][0], acc[i][1], acc[i][2], acc[i][3]);
  }
}

__global__ __launch_bounds__(256) void gemm_reduce(
    const float* __restrict__ P, float* __restrict__ C,
    const float* __restrict__ bias, int M, int N, int ldc, int col0,
    float alpha, int act, int KS) {
  const int idx = blockIdx.x * 256 + threadIdx.x;
  if (idx >= M * N) return;
  const int m = idx / N, n = idx % N;
  float s = 0.f;
  for (int z = 0; z < KS; ++z) s += P[((size_t)z * M + m) * N + n];
  float v = alpha * s + bias[n];
  if (act == 1) v = fmaxf(v, 0.f);
  C[(size_t)m * ldc + col0 + n] = v;
}

// ======================= VQ =================================================
__global__ __launch_bounds__(256) void rowsq(const float* __restrict__ cb,
                                             float* __restrict__ csq) {
  const int row = blockIdx.x * 4 + (threadIdx.x >> 6);
  const int ln = threadIdx.x & 63;
  const float4 v = ((const float4*)(cb + (size_t)row * 256))[ln];
  float s = v.x * v.x + v.y * v.y + v.z * v.z + v.w * v.w;
#pragma unroll
  for (int off = 32; off > 0; off >>= 1) s += __shfl_down(s, off);
  if (ln == 0) csq[row] = s;
}

__global__ __launch_bounds__(256) void argmin_d2(const float* __restrict__ d2,
                                                 int* __restrict__ idx) {
  const int b = blockIdx.x, t = threadIdx.x;
  const float* row = d2 + (size_t)b * 8192;
  float best = 3.4e38f;
  int bi = 0x7fffffff;
  for (int k = t; k < 8192; k += 256) {
    const float v = row[k];
    if (v < best) { best = v; bi = k; }
  }
  __shared__ float bval[256];
  __shared__ int bidx[256];
  bval[t] = best;
  bidx[t] = bi;
  __syncthreads();
  for (int s = 128; s > 0; s >>= 1) {
    if (t < s) {
      const float ov = bval[t + s];
      const int oi = bidx[t + s];
      if (ov < bval[t] || (ov == bval[t] && oi < bidx[t])) {
        bval[t] = ov;
        bidx[t] = oi;
      }
    }
    __syncthreads();
  }
  if (t == 0) idx[b] = bidx[0];
}

__global__ __launch_bounds__(256) void vq_gather_loss(
    const float* __restrict__ ze, const float* __restrict__ cb,
    const int* __restrict__ idx, float* __restrict__ zq,
    float* __restrict__ lossacc) {
  const int b = blockIdx.x, d = threadIdx.x;
  const int i = b * 256 + d;
  const float q = cb[(size_t)idx[b] * 256 + d];
  zq[i] = q;
  const float df = ze[i] - q;
  float v = df * df;
  __shared__ float sh[256];
  sh[d] = v;
  __syncthreads();
  for (int s = 128; s > 0; s >>= 1) {
    if (d < s) sh[d] += sh[d + s];
    __syncthreads();
  }
  if (d == 0) atomicAdd(lossacc, sh[0]);
}

__global__ void write_loss(const float* __restrict__ lossacc,
                           float* __restrict__ out) {
  out[0] = 2.f * lossacc[0];
}

// ---------------------------------------------------------------------------
extern "C" void kernel_launch(void* const* d_in, const int* in_sizes, int n_in,
                              void* d_out, int out_size, void* d_ws,
                              size_t ws_size, hipStream_t stream) {
  const float* x = (const float*)d_in[0];
  const float* ew1 = (const float*)d_in[1];
  const float* eb1 = (const float*)d_in[2];
  const float* ew2 = (const float*)d_in[3];
  const float* eb2 = (const float*)d_in[4];
  const float* ew3 = (const float*)d_in[5];
  const float* eb3 = (const float*)d_in[6];
  const float* ew4 = (const float*)d_in[7];
  const float* eb4 = (const float*)d_in[8];
  const float* wmu = (const float*)d_in[9];
  const float* bmu = (const float*)d_in[10];
  const float* wcov = (const float*)d_in[11];
  const float* bcov = (const float*)d_in[12];
  const float* cb = (const float*)d_in[13];
  const float* wfc = (const float*)d_in[14];
  const float* bfc = (const float*)d_in[15];
  const float* wt1 = (const float*)d_in[16];
  const float* bt1 = (const float*)d_in[17];
  const float* wt2 = (const float*)d_in[18];
  const float* bt2 = (const float*)d_in[19];
  const float* wt3 = (const float*)d_in[20];
  const float* bt3 = (const float*)d_in[21];
  const float* wt31 = (const float*)d_in[22];
  const float* bt31 = (const float*)d_in[23];
  const float* wt4 = (const float*)d_in[24];
  const float* bt4 = (const float*)d_in[25];

  float* ws = (float*)d_ws;
  float* a1 = ws;               // NHWC [256,32,32,32] bf16 (reused as g3, bf16)
  float* a2 = a1 + 8388608;     // NHWC [256,16,16,64] bf16 (reused as g2, bf16)
  float* a3 = a2 + 4194304;     // NHWC [256,8,8,128] bf16  (reused as g1, bf16)
  float* a4 = a3 + 2097152;     // NHWC [256,4,4,256] fp32  (reused as g0, fp32)
  float* g31 = a4 + 1048576;    // NHWC [256,64,64,32] bf16 (region 33554432 f)
  float* d2 = g31;              // [256,8192]
  float* P = g31 + 2097152;     // 262144
  float* csq = g31 + 2359296;   // 8192
  float* a4n = g31 + 2367488;   // NCHW a4 copy
  float* wfcT = g31 + 3416064;  // 1048576
  float* bfcT = g31 + 4464640;  // 4096
  ushort* wTc2 = (ushort*)(g31 + 4468736);  // 18432 bf16
  ushort* wTc3 = (ushort*)(g31 + 4487168);  // 73728 bf16
  ushort* wTc4 = (ushort*)(g31 + 4560896);  // 294912 bf16
  float* ze = g31 + 33554432;   // [256,256]
  float* zq = ze + 65536;
  float* stats = zq + 65536;    // 8 layers x 512
  float* lossacc = stats + 4096;
  int* idx = (int*)(lossacc + 4);
  ushort* wTt1 = (ushort*)(lossacc + 4 + 256);  // 294912 bf16 (parity,perm)
  ushort* wTt2 = wTt1 + 294912;                 // 73728 bf16 (parity,perm)
  ushort* wTt3 = wTt2 + 73728;                  // 18432 bf16 (tap-major,perm)
  ushort* wTt31 = wTt3 + 18432;                 // 9216 bf16 (tap-major,perm)
  ushort* wT4 = wTt31 + 9216;                   // 4608 bf16 (convt4 B frags)
  ushort* wb1 = wT4 + 4608;                     // 1024 bf16 (conv1 B frags)
  float* g3 = a1;   // bf16 content
  float* g2 = a2;   // bf16 content
  float* g1 = a3;   // bf16 content
  float* g0 = a4;   // fp32

  float* st0 = stats + 0 * 512;
  float* st1 = stats + 1 * 512;
  float* st2 = stats + 2 * 512;
  float* st3 = stats + 3 * 512;
  float* st4 = stats + 4 * 512;
  float* st5 = stats + 5 * 512;
  float* st6 = stats + 6 * 512;
  float* st7 = stats + 7 * 512;

  hipMemsetAsync(stats, 0, (4096 + 8) * sizeof(float), stream);

  // ---- weight transposes (bf16) ----
  tr_convw_bf<<<72, 256, 0, stream>>>(ew2, wTc2, 32, 64, 18432, 1);
  tr_convw_bf<<<288, 256, 0, stream>>>(ew3, wTc3, 64, 128, 73728, 1);
  tr_convw_bf<<<1152, 256, 0, stream>>>(ew4, wTc4, 128, 256, 294912, 0);
  tr_convtw_bf<<<1152, 256, 0, stream>>>(wt1, wTt1, 256, 128, 294912);
  tr_convtw_bf<<<288, 256, 0, stream>>>(wt2, wTt2, 128, 64, 73728);
  tr_convtw_tc<<<72, 256, 0, stream>>>(wt3, wTt3, 64, 32, 18432);
  tr_convtw_tc<<<36, 256, 0, stream>>>(wt31, wTt31, 32, 32, 9216);
  tr_w4<<<18, 256, 0, stream>>>(wt4, wT4);
  tr_w1b<<<4, 256, 0, stream>>>(ew1, wb1);
  tr_fcdec<<<4096, 256, 0, stream>>>(wfc, bfc, wfcT, bfcT);
  rowsq<<<2048, 256, 0, stream>>>(cb, csq);

  // ---- encoder ----
  conv1_mfma<<<1024, 256, 0, stream>>>(x, wb1, eb1, (ushort*)a1, st0);
  mfmaconv<64, 0, 32, 32, 64, true, true, true>
      <<<dim3(1, 1024), 256, 0, stream>>>(a1, wTc2, eb2, st0,
                                          1.f / (256.f * 1024.f), a2, st1);
  mfmaconv<64, 0, 16, 64, 128, true, true, true>
      <<<dim3(2, 256), 256, 0, stream>>>(a2, wTc3, eb3, st1,
                                         1.f / (256.f * 256.f), a3, st2);
  mfmaconv<64, 0, 8, 128, 256, true, true, false>
      <<<dim3(4, 64), 256, 0, stream>>>(a3, wTc4, eb4, st2,
                                        1.f / (256.f * 64.f), a4, st3);
  tr_a4<<<4096, 256, 0, stream>>>(a4, a4n);

  // ---- encoder FC (fp32, split-K) ----
  gemm_abt<<<dim3(2, 4, 8), 256, 0, stream>>>(a4n, wmu, nullptr, st3,
                                              1.f / 4096.f, nullptr, P, 4096,
                                              0, 0, 1.f, 0);
  gemm_reduce<<<128, 256, 0, stream>>>(P, ze, bmu, 256, 128, 256, 0, 1.f, 0, 8);
  gemm_abt<<<dim3(2, 4, 8), 256, 0, stream>>>(a4n, wcov, nullptr, st3,
                                              1.f / 4096.f, nullptr, P, 4096,
                                              0, 0, 1.f, 0);
  gemm_reduce<<<128, 256, 0, stream>>>(P, ze, bcov, 256, 128, 256, 128, 1.f, 1, 8);

  // ---- VQ: d2 = csq[n] - 2*ze.cb (|ze|^2 dropped, argmin-invariant) ----
  gemm_bf_abt<<<dim3(128, 4), 256, 0, stream>>>(ze, cb, csq, d2, 256, 8192,
                                                -2.f);
  argmin_d2<<<256, 256, 0, stream>>>(d2, idx);
  vq_gather_loss<<<256, 256, 0, stream>>>(ze, cb, idx, zq, lossacc);

  // ---- decoder FC (bf16 MFMA) ----
  gemm_bf_abt<<<dim3(64, 4), 256, 0, stream>>>(zq, wfcT, bfcT, g0, 256, 4096,
                                               1.f);

  // ---- decoder ----
  mfmaconv<64, 1, 4, 256, 128, false, false, true>
      <<<dim3(2, 64, 4), 256, 0, stream>>>(g0, wTt1, bt1, nullptr, 0.f, g1,
                                           st4);
  mfmaconv<64, 1, 8, 128, 64, true, true, true>
      <<<dim3(1, 256, 4), 256, 0, stream>>>(g1, wTt2, bt2, st4,
                                            1.f / (256.f * 64.f), g2, st5);
  convt_mfma<16, 64, true, true, 4><<<256, 256, 0, stream>>>(
      g2, wTt3, bt3, st5, 1.f / (256.f * 256.f), g3, st6);
  convt_mfma<32, 32, true, true, 8><<<512, 256, 0, stream>>>(
      g3, wTt31, bt31, st6, 1.f / (256.f * 1024.f), g31, st7);

  convt4_mfma<<<1024, 256, 0, stream>>>(g31, wT4, bt4, st7,
                                        1.f / (256.f * 4096.f), (float*)d_out);
  write_loss<<<1, 1, 0, stream>>>(lossacc, (float*)d_out + 3145728);
}

// Round 11
// 497.511 us; speedup vs baseline: 1.3298x; 1.3298x over previous
//
#include <hip/hip_runtime.h>
#include <cmath>

// ---------------------------------------------------------------------------
// VQ-VAE forward. B=256, C=3, HW=64, D=256, K=8192, LAT=128
// R17 (resubmit; prior run died to container acquisition, no kernel signal):
// revert R16's NSTRIP bump (t3 4->2, t31 8->4): the #pragma-unroll'd strip
// loop at NSTRIP=8 exploded VGPR 48->152, occupancy 27->10%, t31 40->97us.
// KEEP R16's OUTBF packed-bf16 conv outputs (a2,a3,g1,g2 bf16; conv4 fp32
// for loss precision). R15 gemm_bf_abt, R14 pipelined k-loop, R13
// conv1_mfma, R11 convt4 ring, R10 multi-strip, R9 packed tail.
// ---------------------------------------------------------------------------

#define EPS_BN 1e-5f
typedef unsigned short ushort;
typedef short short8 __attribute__((ext_vector_type(8)));
typedef ushort us4 __attribute__((ext_vector_type(4)));
typedef float f32x4 __attribute__((ext_vector_type(4)));

__device__ __forceinline__ float lrelu(float v) { return v >= 0.f ? v : 0.01f * v; }
__device__ __forceinline__ ushort f2bf(float f) {
  unsigned u = __float_as_uint(f);
  return (ushort)((u + 0x7FFF + ((u >> 16) & 1)) >> 16);
}
__device__ __forceinline__ float bf2f(ushort u) {
  return __uint_as_float(((unsigned)u) << 16);
}

// ======================= weight transposes (once per launch) ===============
// conv (COUT,CIN,3,3) -> bf16 [co_slot][t*CIN+ci]; perm!=0: within each
// 64-channel block, row slot (cr&3)*16+(cr>>2) holds channel cr (OUTBF).
__global__ __launch_bounds__(256) void tr_convw_bf(const float* __restrict__ w,
                                                   ushort* __restrict__ wT,
                                                   int CIN, int COUT, int total,
                                                   int perm) {
  int i = blockIdx.x * 256 + threadIdx.x;
  if (i >= total) return;
  int co = i / (9 * CIN);
  int r = i - co * 9 * CIN;
  int t = r / CIN, ci = r - t * CIN;
  int co_s = co;
  if (perm) {
    const int cr = co & 63;
    co_s = (co - cr) + ((cr & 3) << 4) + (cr >> 2);
  }
  wT[(size_t)co_s * 9 * CIN + r] = f2bf(w[((size_t)co * CIN + ci) * 9 + t]);
}

// convT (CIN,COUT,3,3) -> bf16 parity-concat [p][co_slot][k], OUTBF-permuted
__global__ __launch_bounds__(256) void tr_convtw_bf(const float* __restrict__ w,
                                                    ushort* __restrict__ wT,
                                                    int CIN, int COUT, int total) {
  int i = blockIdx.x * 256 + threadIdx.x;
  if (i >= total) return;
  const int cc = CIN * COUT;
  int p, base, Kp;
  if (i < cc) { p = 0; base = 0; Kp = CIN; }
  else if (i < 3 * cc) { p = 1; base = cc; Kp = 2 * CIN; }
  else if (i < 5 * cc) { p = 2; base = 3 * cc; Kp = 2 * CIN; }
  else { p = 3; base = 5 * cc; Kp = 4 * CIN; }
  const int r = i - base;
  const int co = r / Kp;
  const int q = r - co * Kp;
  const int tix = q / CIN, ci = q - (q / CIN) * CIN;
  const int py = p >> 1, px = p & 1;
  const int nx = px ? 2 : 1;
  const int kyi = tix / nx, kxi = tix - kyi * nx;
  const int ky = py ? (kyi == 0 ? 0 : 2) : 1;
  const int kx = px ? (kxi == 0 ? 0 : 2) : 1;
  const int cr = co & 63;
  const int co_s = (co - cr) + ((cr & 3) << 4) + (cr >> 2);
  wT[base + (size_t)co_s * Kp + q] =
      f2bf(w[((size_t)ci * COUT + co) * 9 + ky * 3 + kx]);
}

// convT (CIN,COUT=32,3,3) -> bf16 [t][co_slot][ci] (tap-major, columns
// PERMUTED so slot f*16+ln15 holds channel 2*ln15+f -> packed bf16 stores)
__global__ __launch_bounds__(256) void tr_convtw_tc(const float* __restrict__ w,
                                                    ushort* __restrict__ wT,
                                                    int CIN, int COUT, int total) {
  int i = blockIdx.x * 256 + threadIdx.x;
  if (i >= total) return;
  int ci = i % CIN;
  int tmp = i / CIN;
  int co = tmp % COUT;
  int t = tmp / COUT;
  const int co_slot = ((co & 1) << 4) | (co >> 1);
  wT[((size_t)t * COUT + co_slot) * CIN + ci] =
      f2bf(w[((size_t)ci * COUT + co) * 9 + t]);
}

// convt4 weights (CIN=32, COUT=3, 3,3) -> per-lane B fragments
__global__ __launch_bounds__(256) void tr_w4(const float* __restrict__ w,
                                             ushort* __restrict__ wT) {
  int i = blockIdx.x * 256 + threadIdx.x;
  if (i >= 4608) return;
  const int s = i >> 9;
  const int l = (i >> 3) & 63;
  const int j = i & 7;
  const int nn = l & 15;
  const int ci = ((l >> 4) << 3) + j;
  const int ty = s / 3, tx = s - ty * 3;
  ushort v = 0;
  if (nn < 3)
    v = f2bf(w[((size_t)ci * 3 + nn) * 9 + (2 - ty) * 3 + (2 - tx)]);
  wT[i] = v;
}

// conv1 weights (32,3,3,3) -> MFMA B fragments, channel-pair permuted
__global__ __launch_bounds__(256) void tr_w1b(const float* __restrict__ w,
                                              ushort* __restrict__ wT) {
  int i = blockIdx.x * 256 + threadIdx.x;
  if (i >= 1024) return;
  const int j = i & 7, l = (i >> 3) & 63, f = i >> 9;
  const int c = 2 * (l & 15) + f;
  const int k = ((l >> 4) << 3) + j;
  ushort v = 0;
  if (k < 27) {
    const int ci = k / 9, r = k - ci * 9;
    v = f2bf(w[((size_t)c * 3 + ci) * 9 + r]);
  }
  wT[i] = v;
}

// a4 NHWC [256,4,4,256] -> NCHW [256,256,4,4]
__global__ __launch_bounds__(256) void tr_a4(const float* __restrict__ in,
                                             float* __restrict__ out) {
  int i = blockIdx.x * 256 + threadIdx.x;
  int n = i >> 12, k = i & 4095;
  out[i] = in[(size_t)(n << 12) + ((k & 15) << 8) + (k >> 4)];
}

// wfc [4096,256] + bfc: permute ROWS from (c,y,x) to (y,x,c)
__global__ __launch_bounds__(256) void tr_fcdec(const float* __restrict__ in,
                                                const float* __restrict__ bin,
                                                float* __restrict__ out,
                                                float* __restrict__ bout) {
  int i = blockIdx.x * 256 + threadIdx.x;
  int k = i >> 8, d = i & 255;
  int kp = (k & 15) * 256 + (k >> 4);
  out[(size_t)kp * 256 + d] = in[i];
  if (d == 0) bout[kp] = bin[k];
}

// ======================= bf16 MFMA implicit-GEMM conv / convT ==============
// R14 pipeline. OUTBF: packed-bf16 output, slot f*16+l = channel 4l+f.
template <int TN, int MODE, int IH, int CIN, int COUT, bool HASN, bool INBF,
          bool OUTBF>
__global__ __launch_bounds__(256) void mfmaconv(
    const float* __restrict__ X, const ushort* __restrict__ WT,
    const float* __restrict__ bias, const float* __restrict__ st, float invN,
    float* __restrict__ Y, float* __restrict__ stOut) {
  constexpr int OH = (MODE == 0) ? IH / 2 : 2 * IH;
  constexpr int NF = TN / 16;
  static_assert(!OUTBF || NF == 4, "OUTBF requires NF==4");
  __shared__ short As[2][64][40];
  __shared__ short Bs[2][TN][40];
  __shared__ float nrm0[HASN ? CIN : 4], nrm1[HASN ? CIN : 4];
  __shared__ float redS[4][TN], redQ[4][TN];
  const int tid = threadIdx.x;
  const int wv = tid >> 6, lane = tid & 63;
  const int quad = lane >> 4, ln15 = tid & 15;
  if (HASN) {
    for (int c = tid; c < CIN; c += 256) {
      float m = st[c] * invN;
      float var = st[256 + c] * invN - m * m;
      float s = rsqrtf(var + EPS_BN);
      nrm0[c] = s;
      nrm1[c] = m * s;
    }
    __syncthreads();
  }
  int py = 0, px = 0, nx = 1, K = 9 * CIN;
  const ushort* W = WT;
  if (MODE == 1) {
    const int pz = blockIdx.z;
    py = pz >> 1;
    px = pz & 1;
    nx = px ? 2 : 1;
    const int ny = py ? 2 : 1;
    K = ny * nx * CIN;
    const int pre[4] = {0, 1, 3, 5};
    W = WT + (size_t)pre[pz] * CIN * COUT;
  }
  const int gyTM = blockIdx.y * 64;
  const int gxTN = blockIdx.x * TN;

  const int sm = tid & 63, skg = (tid >> 6) * 8;
  const int bn = tid >> 2, bkg = (tid & 3) * 8;
  int baseNB, baseIY, baseIX;
  {
    const int gm = gyTM + sm;
    if (MODE == 0) {
      const int ni = gm / (OH * OH), r = gm % (OH * OH);
      baseNB = ni * IH * IH;
      baseIY = 2 * (r / OH) - 1;
      baseIX = 2 * (r % OH) - 1;
    } else {
      const int ni = gm / (IH * IH), r = gm % (IH * IH);
      baseNB = ni * IH * IH;
      baseIY = r / IH;
      baseIX = r % IH;
    }
  }
  f32x4 acc[NF];
#pragma unroll
  for (int f = 0; f < NF; ++f) acc[f] = (f32x4){0.f, 0.f, 0.f, 0.f};

  const int nsteps = K / 32;

  // ---- prologue: stage step 0 into buf 0 ----
  {
    int iy, ix;
    if (MODE == 0) {
      iy = baseIY;
      ix = baseIX;
    } else {
      iy = baseIY + (py ? 1 : 0);
      ix = baseIX + (px ? 1 : 0);
    }
    const bool ok =
        ((unsigned)iy < (unsigned)IH) && ((unsigned)ix < (unsigned)IH);
    float v[8] = {0.f, 0.f, 0.f, 0.f, 0.f, 0.f, 0.f, 0.f};
    if (ok) {
      if constexpr (INBF) {
        const ushort* xp =
            (const ushort*)X + ((size_t)baseNB + iy * IH + ix) * CIN + skg;
        const short8 raw = *(const short8*)xp;
#pragma unroll
        for (int u = 0; u < 8; ++u) v[u] = bf2f((ushort)raw[u]);
      } else {
        const float* xp = &X[((size_t)baseNB + iy * IH + ix) * CIN + skg];
        const float4 va = *(const float4*)xp, vb = *(const float4*)(xp + 4);
        v[0] = va.x; v[1] = va.y; v[2] = va.z; v[3] = va.w;
        v[4] = vb.x; v[5] = vb.y; v[6] = vb.z; v[7] = vb.w;
      }
      if (HASN) {
#pragma unroll
        for (int u = 0; u < 8; ++u)
          v[u] = fmaf(v[u], nrm0[skg + u], -nrm1[skg + u]);
      }
    }
    short8 o;
#pragma unroll
    for (int u = 0; u < 8; ++u) o[u] = (short)f2bf(v[u]);
    *(short8*)&As[0][sm][skg] = o;
    if (tid < TN * 4)
      *(short8*)&Bs[0][bn][bkg] =
          *(const short8*)&W[(size_t)(gxTN + bn) * K + bkg];
  }
  __syncthreads();

  for (int kk = 0; kk < nsteps; ++kk) {
    const int cur = kk & 1, nxt = cur ^ 1;

    // ---- issue next step's global loads into regs ----
    bool okN = false;
    int ci0N = 0;
    short8 rawN;
    float4 vaN, vbN;
    short8 rawBN;
    const bool hasNext = (kk + 1 < nsteps);
    if (hasNext) {
      const int k0n = (kk + 1) * 32;
      const int t = k0n / CIN;
      ci0N = k0n - t * CIN;
      int iy, ix;
      if (MODE == 0) {
        iy = baseIY + t / 3;
        ix = baseIX + (t - (t / 3) * 3);
      } else {
        const int kyi = t / nx, kxi = t - (t / nx) * nx;
        iy = baseIY + ((py && kyi == 0) ? 1 : 0);
        ix = baseIX + ((px && kxi == 0) ? 1 : 0);
      }
      okN = ((unsigned)iy < (unsigned)IH) && ((unsigned)ix < (unsigned)IH);
      if (okN) {
        if constexpr (INBF) {
          const ushort* xp = (const ushort*)X +
                             ((size_t)baseNB + iy * IH + ix) * CIN + ci0N + skg;
          rawN = *(const short8*)xp;
        } else {
          const float* xp =
              &X[((size_t)baseNB + iy * IH + ix) * CIN + ci0N + skg];
          vaN = *(const float4*)xp;
          vbN = *(const float4*)(xp + 4);
        }
      }
      if (tid < TN * 4)
        rawBN = *(const short8*)&W[(size_t)(gxTN + bn) * K + k0n + bkg];
    }

    // ---- MFMAs on buf[cur] ----
    const short8 a = *(const short8*)&As[cur][wv * 16 + ln15][quad * 8];
#pragma unroll
    for (int f = 0; f < NF; ++f) {
      const short8 b = *(const short8*)&Bs[cur][f * 16 + ln15][quad * 8];
      acc[f] = __builtin_amdgcn_mfma_f32_16x16x32_bf16(a, b, acc[f], 0, 0, 0);
    }

    // ---- convert + write next step into buf[nxt] ----
    if (hasNext) {
      float v[8] = {0.f, 0.f, 0.f, 0.f, 0.f, 0.f, 0.f, 0.f};
      if (okN) {
        if constexpr (INBF) {
#pragma unroll
          for (int u = 0; u < 8; ++u) v[u] = bf2f((ushort)rawN[u]);
        } else {
          v[0] = vaN.x; v[1] = vaN.y; v[2] = vaN.z; v[3] = vaN.w;
          v[4] = vbN.x; v[5] = vbN.y; v[6] = vbN.z; v[7] = vbN.w;
        }
        if (HASN) {
          const int c = ci0N + skg;
#pragma unroll
          for (int u = 0; u < 8; ++u)
            v[u] = fmaf(v[u], nrm0[c + u], -nrm1[c + u]);
        }
      }
      short8 o;
#pragma unroll
      for (int u = 0; u < 8; ++u) o[u] = (short)f2bf(v[u]);
      *(short8*)&As[nxt][sm][skg] = o;
      if (tid < TN * 4) *(short8*)&Bs[nxt][bn][bkg] = rawBN;
    }
    __syncthreads();
  }

  size_t maddr[4];
#pragma unroll
  for (int r = 0; r < 4; ++r) {
    const int m = gyTM + wv * 16 + quad * 4 + r;
    if (MODE == 0) {
      const int ni = m / (OH * OH), rr = m % (OH * OH);
      maddr[r] = (((size_t)ni * OH + rr / OH) * OH + rr % OH) * COUT;
    } else {
      const int ni = m / (IH * IH), rr = m % (IH * IH);
      const int oy = 2 * (rr / IH) + py, ox = 2 * (rr % IH) + px;
      maddr[r] = (((size_t)ni * OH + oy) * OH + ox) * COUT;
    }
  }
  if constexpr (OUTBF) {
    // lane owns channels ch0..ch0+3 (slot f*16+l = channel 4l+f)
    const int ch0 = gxTN + 4 * ln15;
    const float b0 = bias[ch0 + 0], b1 = bias[ch0 + 1];
    const float b2 = bias[ch0 + 2], b3 = bias[ch0 + 3];
    ushort* Yb = (ushort*)Y;
    float cS[4] = {0.f, 0.f, 0.f, 0.f}, cQ[4] = {0.f, 0.f, 0.f, 0.f};
#pragma unroll
    for (int r = 0; r < 4; ++r) {
      const float o0 = lrelu(acc[0][r] + b0);
      const float o1 = lrelu(acc[1][r] + b1);
      const float o2 = lrelu(acc[2][r] + b2);
      const float o3 = lrelu(acc[3][r] + b3);
      cS[0] += o0; cQ[0] += o0 * o0;
      cS[1] += o1; cQ[1] += o1 * o1;
      cS[2] += o2; cQ[2] += o2 * o2;
      cS[3] += o3; cQ[3] += o3 * o3;
      uint2 pk;
      pk.x = (unsigned)f2bf(o0) | ((unsigned)f2bf(o1) << 16);
      pk.y = (unsigned)f2bf(o2) | ((unsigned)f2bf(o3) << 16);
      *(uint2*)&Yb[maddr[r] + ch0] = pk;
    }
#pragma unroll
    for (int f = 0; f < 4; ++f) {
      float s_ = cS[f], q_ = cQ[f];
      s_ += __shfl_down(s_, 32); s_ += __shfl_down(s_, 16);
      q_ += __shfl_down(q_, 32); q_ += __shfl_down(q_, 16);
      if (lane < 16) { redS[wv][f * 16 + ln15] = s_; redQ[wv][f * 16 + ln15] = q_; }
    }
    __syncthreads();
    if (tid < TN) {
      float S = redS[0][tid] + redS[1][tid] + redS[2][tid] + redS[3][tid];
      float Q = redQ[0][tid] + redQ[1][tid] + redQ[2][tid] + redQ[3][tid];
      const int ch = gxTN + 4 * (tid & 15) + (tid >> 4);
      atomicAdd(&stOut[ch], S);
      atomicAdd(&stOut[256 + ch], Q);
    }
  } else {
#pragma unroll
    for (int f = 0; f < NF; ++f) {
      const int col = gxTN + f * 16 + ln15;
      const float bv = bias[col];
      float cS = 0.f, cQ = 0.f;
#pragma unroll
      for (int r = 0; r < 4; ++r) {
        const float o = lrelu(acc[f][r] + bv);
        cS += o;
        cQ += o * o;
        Y[maddr[r] + col] = o;
      }
      cS += __shfl_down(cS, 32); cS += __shfl_down(cS, 16);
      cQ += __shfl_down(cQ, 32); cQ += __shfl_down(cQ, 16);
      if (lane < 16) { redS[wv][f * 16 + ln15] = cS; redQ[wv][f * 16 + ln15] = cQ; }
    }
    __syncthreads();
    if (tid < TN) {
      float S = redS[0][tid] + redS[1][tid] + redS[2][tid] + redS[3][tid];
      float Q = redQ[0][tid] + redQ[1][tid] + redQ[2][tid] + redQ[3][tid];
      atomicAdd(&stOut[gxTN + tid], S);
      atomicAdd(&stOut[256 + gxTN + tid], Q);
    }
  }
}

// ======================= bf16 MFMA dense GEMM: C = alpha*(A.B^T) + bias ====
__global__ __launch_bounds__(256) void gemm_bf_abt(
    const float* __restrict__ A, const float* __restrict__ B,
    const float* __restrict__ bias, float* __restrict__ C, int K, int N,
    float alpha) {
  __shared__ short As[2][64][40];
  __shared__ short Bs[2][64][40];
  const int tid = threadIdx.x;
  const int wv = tid >> 6, lane = tid & 63;
  const int quad = lane >> 4, ln15 = lane & 15;
  const int gm0 = blockIdx.y * 64, gn0 = blockIdx.x * 64;
  const int sm = tid & 63, skg = (tid >> 6) * 8;
  const int bn = tid >> 2, bkg = (tid & 3) * 8;
  const float* Ap = A + (size_t)(gm0 + sm) * K + skg;
  const float* Bp = B + (size_t)(gn0 + bn) * K + bkg;
  f32x4 acc[4];
#pragma unroll
  for (int f = 0; f < 4; ++f) acc[f] = (f32x4){0.f, 0.f, 0.f, 0.f};
  const int nsteps = K / 32;

  {
    const float4 va = *(const float4*)Ap, vb = *(const float4*)(Ap + 4);
    short8 o;
    o[0] = (short)f2bf(va.x); o[1] = (short)f2bf(va.y);
    o[2] = (short)f2bf(va.z); o[3] = (short)f2bf(va.w);
    o[4] = (short)f2bf(vb.x); o[5] = (short)f2bf(vb.y);
    o[6] = (short)f2bf(vb.z); o[7] = (short)f2bf(vb.w);
    *(short8*)&As[0][sm][skg] = o;
    const float4 wa = *(const float4*)Bp, wb = *(const float4*)(Bp + 4);
    short8 p;
    p[0] = (short)f2bf(wa.x); p[1] = (short)f2bf(wa.y);
    p[2] = (short)f2bf(wa.z); p[3] = (short)f2bf(wa.w);
    p[4] = (short)f2bf(wb.x); p[5] = (short)f2bf(wb.y);
    p[6] = (short)f2bf(wb.z); p[7] = (short)f2bf(wb.w);
    *(short8*)&Bs[0][bn][bkg] = p;
  }
  __syncthreads();

  for (int kk = 0; kk < nsteps; ++kk) {
    const int cur = kk & 1, nxt = cur ^ 1;
    const bool hasNext = (kk + 1 < nsteps);
    float4 vaN, vbN, waN, wbN;
    if (hasNext) {
      const int k0n = (kk + 1) * 32;
      vaN = *(const float4*)(Ap + k0n);
      vbN = *(const float4*)(Ap + k0n + 4);
      waN = *(const float4*)(Bp + k0n);
      wbN = *(const float4*)(Bp + k0n + 4);
    }

    const short8 a = *(const short8*)&As[cur][wv * 16 + ln15][quad * 8];
#pragma unroll
    for (int f = 0; f < 4; ++f) {
      const short8 b = *(const short8*)&Bs[cur][f * 16 + ln15][quad * 8];
      acc[f] = __builtin_amdgcn_mfma_f32_16x16x32_bf16(a, b, acc[f], 0, 0, 0);
    }

    if (hasNext) {
      short8 o;
      o[0] = (short)f2bf(vaN.x); o[1] = (short)f2bf(vaN.y);
      o[2] = (short)f2bf(vaN.z); o[3] = (short)f2bf(vaN.w);
      o[4] = (short)f2bf(vbN.x); o[5] = (short)f2bf(vbN.y);
      o[6] = (short)f2bf(vbN.z); o[7] = (short)f2bf(vbN.w);
      *(short8*)&As[nxt][sm][skg] = o;
      short8 p;
      p[0] = (short)f2bf(waN.x); p[1] = (short)f2bf(waN.y);
      p[2] = (short)f2bf(waN.z); p[3] = (short)f2bf(waN.w);
      p[4] = (short)f2bf(wbN.x); p[5] = (short)f2bf(wbN.y);
      p[6] = (short)f2bf(wbN.z); p[7] = (short)f2bf(wbN.w);
      *(short8*)&Bs[nxt][bn][bkg] = p;
    }
    __syncthreads();
  }

#pragma unroll
  for (int f = 0; f < 4; ++f) {
    const int col = gn0 + f * 16 + ln15;
    const float bv = bias[col];
#pragma unroll
    for (int r = 0; r < 4; ++r) {
      const int row = gm0 + wv * 16 + quad * 4 + r;
      C[(size_t)row * N + col] = fmaf(alpha, acc[f][r], bv);
    }
  }
}

// ======================= halo-tile merged convT (COUT=32, CIN<=64) =========
template <int IH, int CIN, bool HASN, bool INBF, int NSTRIP>
__global__ __launch_bounds__(256) void convt_mfma(
    const float* __restrict__ X, const ushort* __restrict__ WT,
    const float* __restrict__ bias, const float* __restrict__ st, float invN,
    float* __restrict__ Y, float* __restrict__ stOut) {
  constexpr int OH = 2 * IH;
  constexpr int L = (IH == 32) ? 5 : 4;
  constexpr int RSPAN = 64 / IH;
  constexpr int NP = (RSPAN + 1) * (IH + 1);
  constexpr int LK = CIN + 8;
  constexpr int TI = NP * (CIN / 8);
  constexpr int ITER = (TI + 255) / 256;
  __shared__ short As[2][NP][LK];
  __shared__ short Ws[9 * 32][LK];
  __shared__ float nrm0[HASN ? CIN : 4], nrm1[HASN ? CIN : 4];
  __shared__ float redS[4][32], redQ[4][32];
  const int tid = threadIdx.x;
  const int wv = tid >> 6, lane = tid & 63;
  const int quad = lane >> 4, ln15 = lane & 15;
  if (HASN) {
    for (int c = tid; c < CIN; c += 256) {
      float m = st[c] * invN;
      float var = st[256 + c] * invN - m * m;
      float s = rsqrtf(var + EPS_BN);
      nrm0[c] = s;
      nrm1[c] = m * s;
    }
  }
  for (int i = tid; i < 9 * 32 * (CIN / 8); i += 256) {
    const int row = i / (CIN / 8), kg = (i % (CIN / 8)) * 8;
    *(short8*)&Ws[row][kg] = *(const short8*)&WT[(size_t)row * CIN + kg];
  }
  __syncthreads();

  const int strip0 = blockIdx.x * NSTRIP;
  const int n = (strip0 * 64) / (IH * IH);
  const int iy0base = (strip0 * 64 - n * (IH * IH)) >> L;

#pragma unroll
  for (int it = 0; it < ITER; ++it) {
    const int i = tid + it * 256;
    if (i < TI) {
      const int slot = i / (CIN / 8), kg = (i % (CIN / 8)) * 8;
      const int ty = slot / (IH + 1), tx = slot - ty * (IH + 1);
      const int iy = iy0base + ty;
      short8 o = {0, 0, 0, 0, 0, 0, 0, 0};
      if (iy < IH && tx < IH) {
        float v[8];
        if constexpr (INBF) {
          const ushort* xp =
              (const ushort*)X + (((size_t)n * IH + iy) * IH + tx) * CIN + kg;
          const short8 raw = *(const short8*)xp;
#pragma unroll
          for (int u = 0; u < 8; ++u) v[u] = bf2f((ushort)raw[u]);
        } else {
          const float* xp = &X[(((size_t)n * IH + iy) * IH + tx) * CIN + kg];
          const float4 va = *(const float4*)xp, vb = *(const float4*)(xp + 4);
          v[0] = va.x; v[1] = va.y; v[2] = va.z; v[3] = va.w;
          v[4] = vb.x; v[5] = vb.y; v[6] = vb.z; v[7] = vb.w;
        }
        if (HASN) {
#pragma unroll
          for (int u = 0; u < 8; ++u)
            v[u] = fmaf(v[u], nrm0[kg + u], -nrm1[kg + u]);
        }
#pragma unroll
        for (int u = 0; u < 8; ++u) o[u] = (short)f2bf(v[u]);
      }
      *(short8*)&As[0][slot][kg] = o;
    }
  }
  __syncthreads();

  const int rA = wv * 16 + ln15;
  const int baseIdx = (rA >> L) * (IH + 1) + (rA & (IH - 1));
  constexpr int NT[4] = {4, 2, 2, 1};
  constexpr int TT[4][4] = {{4, 5, 7, 8}, {3, 6, 0, 0}, {1, 2, 0, 0}, {0, 0, 0, 0}};
  const float bv0 = bias[2 * ln15], bv1 = bias[2 * ln15 + 1];
  unsigned* Yp = (unsigned*)Y;
  float cS[2] = {0.f, 0.f}, cQ[2] = {0.f, 0.f};

#pragma unroll
  for (int s = 0; s < NSTRIP; ++s) {
    const int cur = s & 1, nxt = cur ^ 1;
    const int iy0 = iy0base + s * RSPAN;

    short8 rbf[ITER];
    float4 rva[ITER], rvb[ITER];
    bool vld[ITER];
    if (s + 1 < NSTRIP) {
      const int iyN0 = iy0 + RSPAN;
#pragma unroll
      for (int it = 0; it < ITER; ++it) {
        vld[it] = false;
        const int i = tid + it * 256;
        if (i < TI) {
          const int slot = i / (CIN / 8), kg = (i % (CIN / 8)) * 8;
          const int ty = slot / (IH + 1), tx = slot - ty * (IH + 1);
          const int iy = iyN0 + ty;
          if (iy < IH && tx < IH) {
            vld[it] = true;
            if constexpr (INBF) {
              const ushort* xp = (const ushort*)X +
                                 (((size_t)n * IH + iy) * IH + tx) * CIN + kg;
              rbf[it] = *(const short8*)xp;
            } else {
              const float* xp =
                  &X[(((size_t)n * IH + iy) * IH + tx) * CIN + kg];
              rva[it] = *(const float4*)xp;
              rvb[it] = *(const float4*)(xp + 4);
            }
          }
        }
      }
    }

    f32x4 acc[4][2];
#pragma unroll
    for (int p = 0; p < 4; ++p)
#pragma unroll
      for (int f = 0; f < 2; ++f) acc[p][f] = (f32x4){0.f, 0.f, 0.f, 0.f};
#pragma unroll
    for (int sh = 0; sh < 4; ++sh) {
      const int off = (sh >> 1) * (IH + 1) + (sh & 1);
#pragma unroll
      for (int j = 0; j < NT[sh]; ++j) {
        const int t = TT[sh][j];
        const int ky = t / 3, kx = t - ky * 3;
        const int par = ((ky == 1) ? 0 : 2) + ((kx == 1) ? 0 : 1);
#pragma unroll
        for (int ks = 0; ks < CIN / 32; ++ks) {
          const short8 a =
              *(const short8*)&As[cur][baseIdx + off][ks * 32 + quad * 8];
#pragma unroll
          for (int f = 0; f < 2; ++f) {
            const short8 b =
                *(const short8*)&Ws[t * 32 + f * 16 + ln15][ks * 32 + quad * 8];
            acc[par][f] = __builtin_amdgcn_mfma_f32_16x16x32_bf16(
                a, b, acc[par][f], 0, 0, 0);
          }
        }
      }
    }

#pragma unroll
    for (int i = 0; i < 4; ++i) {
      const int rD = wv * 16 + quad * 4 + i;
      const int ry = rD >> L, rx = rD & (IH - 1);
      const int iy = iy0 + ry;
#pragma unroll
      for (int p = 0; p < 4; ++p) {
        const int a = p >> 1, b = p & 1;
        const size_t base =
            (((size_t)n * OH + 2 * iy + a) * OH + 2 * rx + b) * 32;
        const float o0 = lrelu(acc[p][0][i] + bv0);
        const float o1 = lrelu(acc[p][1][i] + bv1);
        cS[0] += o0; cQ[0] += o0 * o0;
        cS[1] += o1; cQ[1] += o1 * o1;
        Yp[(base >> 1) + ln15] = (unsigned)f2bf(o0) | ((unsigned)f2bf(o1) << 16);
      }
    }

    if (s + 1 < NSTRIP) {
#pragma unroll
      for (int it = 0; it < ITER; ++it) {
        const int i = tid + it * 256;
        if (i < TI) {
          const int slot = i / (CIN / 8), kg = (i % (CIN / 8)) * 8;
          short8 o = {0, 0, 0, 0, 0, 0, 0, 0};
          if (vld[it]) {
            float v[8];
            if constexpr (INBF) {
#pragma unroll
              for (int u = 0; u < 8; ++u) v[u] = bf2f((ushort)rbf[it][u]);
            } else {
              v[0] = rva[it].x; v[1] = rva[it].y;
              v[2] = rva[it].z; v[3] = rva[it].w;
              v[4] = rvb[it].x; v[5] = rvb[it].y;
              v[6] = rvb[it].z; v[7] = rvb[it].w;
            }
            if (HASN) {
#pragma unroll
              for (int u = 0; u < 8; ++u)
                v[u] = fmaf(v[u], nrm0[kg + u], -nrm1[kg + u]);
            }
#pragma unroll
            for (int u = 0; u < 8; ++u) o[u] = (short)f2bf(v[u]);
          }
          *(short8*)&As[nxt][slot][kg] = o;
        }
      }
    }
    __syncthreads();
  }

#pragma unroll
  for (int f = 0; f < 2; ++f) {
    float s_ = cS[f], q_ = cQ[f];
    s_ += __shfl_down(s_, 32); s_ += __shfl_down(s_, 16);
    q_ += __shfl_down(q_, 32); q_ += __shfl_down(q_, 16);
    if (lane < 16) { redS[wv][f * 16 + ln15] = s_; redQ[wv][f * 16 + ln15] = q_; }
  }
  __syncthreads();
  if (tid < 32) {
    float S = redS[0][tid] + redS[1][tid] + redS[2][tid] + redS[3][tid];
    float Q = redQ[0][tid] + redQ[1][tid] + redQ[2][tid] + redQ[3][tid];
    const int ch = ((tid & 15) << 1) | (tid >> 4);
    atomicAdd(&stOut[ch], S);
    atomicAdd(&stOut[256 + ch], Q);
  }
}

// ======================= conv1 via MFMA im2col =============================
__global__ __launch_bounds__(256) void conv1_mfma(
    const float* __restrict__ x, const ushort* __restrict__ WT,
    const float* __restrict__ bias, ushort* __restrict__ y,
    float* __restrict__ st) {
  __shared__ float xin[3][17][67];
  __shared__ float redS[4][32], redQ[4][32];
  const int tid = threadIdx.x;
  const int wv = tid >> 6, lane = tid & 63;
  const int quad = lane >> 4, ln15 = lane & 15;
  const short8 bf0 = *(const short8*)&WT[(size_t)lane * 8];
  const short8 bf1 = *(const short8*)&WT[(size_t)(64 + lane) * 8];
  const int n = blockIdx.x >> 2;
  const int oy0 = (blockIdx.x & 3) * 8;
  const int iy0 = 2 * oy0 - 1;
  if (tid < 51) {
    const int ci = tid / 17, r = tid - ci * 17;
    xin[ci][r][0] = 0.f;
  }
  for (int i = tid; i < 816; i += 256) {
    const int ci = i / 272;
    const int r = (i - ci * 272) >> 4;
    const int c4 = (i & 15) << 2;
    const int iy = iy0 + r;
    float4 v = make_float4(0.f, 0.f, 0.f, 0.f);
    if ((unsigned)iy < 64u)
      v = *(const float4*)&x[((size_t)(n * 3 + ci) * 64 + iy) * 64 + c4];
    xin[ci][r][1 + c4] = v.x;
    xin[ci][r][2 + c4] = v.y;
    xin[ci][r][3 + c4] = v.z;
    xin[ci][r][4 + c4] = v.w;
  }
  __syncthreads();

  const float bv0 = bias[2 * ln15], bv1 = bias[2 * ln15 + 1];
  unsigned* Yp = (unsigned*)y;
  float cS[2] = {0.f, 0.f}, cQ[2] = {0.f, 0.f};
#pragma unroll
  for (int rr = 0; rr < 2; ++rr) {
    const int row = 2 * wv + rr;
#pragma unroll
    for (int h = 0; h < 2; ++h) {
      short8 a;
#pragma unroll
      for (int j = 0; j < 8; ++j) {
        const int k = quad * 8 + j;
        float val = 0.f;
        if (k < 27) {
          const int ci = k / 9, r2 = k - ci * 9;
          const int ky = r2 / 3, kx = r2 - ky * 3;
          val = xin[ci][2 * row + ky][2 * (h * 16 + ln15) + kx];
        }
        a[j] = (short)f2bf(val);
      }
      f32x4 acc0 = (f32x4){0.f, 0.f, 0.f, 0.f};
      f32x4 acc1 = (f32x4){0.f, 0.f, 0.f, 0.f};
      acc0 = __builtin_amdgcn_mfma_f32_16x16x32_bf16(a, bf0, acc0, 0, 0, 0);
      acc1 = __builtin_amdgcn_mfma_f32_16x16x32_bf16(a, bf1, acc1, 0, 0, 0);
#pragma unroll
      for (int r = 0; r < 4; ++r) {
        const int px = h * 16 + quad * 4 + r;
        const float o0 = lrelu(acc0[r] + bv0);
        const float o1 = lrelu(acc1[r] + bv1);
        cS[0] += o0; cQ[0] += o0 * o0;
        cS[1] += o1; cQ[1] += o1 * o1;
        Yp[((size_t)n * 1024 + (oy0 + row) * 32 + px) * 16 + ln15] =
            (unsigned)f2bf(o0) | ((unsigned)f2bf(o1) << 16);
      }
    }
  }
#pragma unroll
  for (int f = 0; f < 2; ++f) {
    float s_ = cS[f], q_ = cQ[f];
    s_ += __shfl_down(s_, 32); s_ += __shfl_down(s_, 16);
    q_ += __shfl_down(q_, 32); q_ += __shfl_down(q_, 16);
    if (lane < 16) { redS[wv][f * 16 + ln15] = s_; redQ[wv][f * 16 + ln15] = q_; }
  }
  __syncthreads();
  if (tid < 32) {
    float S = redS[0][tid] + redS[1][tid] + redS[2][tid] + redS[3][tid];
    float Q = redQ[0][tid] + redQ[1][tid] + redQ[2][tid] + redQ[3][tid];
    const int ch = ((tid & 15) << 1) | (tid >> 4);
    atomicAdd(&st[ch], S);
    atomicAdd(&st[256 + ch], Q);
  }
}

// ======================= final convT via MFMA + 4-row LDS ring =============
__global__ __launch_bounds__(256) void convt4_mfma(
    const float* __restrict__ X, const ushort* __restrict__ WT,
    const float* __restrict__ bias, const float* __restrict__ st, float invN,
    float* __restrict__ out) {
  __shared__ short ring[4][66][32];
  __shared__ float s0[32], s1[32];
  const int tid = threadIdx.x;
  const int wv = tid >> 6, lane = tid & 63;
  const int quad = lane >> 4, ln15 = lane & 15;
  if (tid < 32) {
    float m = st[tid] * invN;
    float var = st[256 + tid] * invN - m * m;
    float s = rsqrtf(var + EPS_BN);
    s0[tid] = s;
    s1[tid] = m * s;
  }
  if (tid >= 32 && tid < 64) {
    const int t = tid - 32;
    const int slot = t >> 3, h = (t >> 2) & 1, kg = (t & 3) * 8;
    short8 z = {0, 0, 0, 0, 0, 0, 0, 0};
    *(short8*)&ring[slot][h ? 65 : 0][kg] = z;
  }
  short8 bfrag[9];
#pragma unroll
  for (int s = 0; s < 9; ++s)
    bfrag[s] = *(const short8*)&WT[((size_t)s * 64 + lane) * 8];
  __syncthreads();

  const int n = blockIdx.x >> 2;
  const int y0 = (blockIdx.x & 3) * 16;
  const ushort* xn = (const ushort*)X + (size_t)n * 131072;
  const int spx = tid >> 2, skg = (tid & 3) * 8;

#pragma unroll
  for (int pr = 0; pr < 3; ++pr) {
    const int Y = y0 - 1 + pr;
    short8 o = {0, 0, 0, 0, 0, 0, 0, 0};
    if ((unsigned)Y < 64u) {
      const short8 raw = *(const short8*)&xn[((size_t)Y * 64 + spx) * 32 + skg];
#pragma unroll
      for (int u = 0; u < 8; ++u)
        o[u] = (short)f2bf(fmaf(bf2f((ushort)raw[u]), s0[skg + u], -s1[skg + u]));
    }
    *(short8*)&ring[Y & 3][spx + 1][skg] = o;
  }
  __syncthreads();

  const int x0 = wv * 16;
  const float bv = (ln15 < 3) ? bias[ln15] : 0.f;
  float* op = out + (size_t)n * 3 * 4096;

  for (int y = y0; y < y0 + 16; ++y) {
    const int Ypf = y + 2;
    const bool pre = (Ypf <= y0 + 16);
    short8 raw;
    bool vld = false;
    if (pre && (unsigned)Ypf < 64u) {
      raw = *(const short8*)&xn[((size_t)Ypf * 64 + spx) * 32 + skg];
      vld = true;
    }

    f32x4 acc0 = (f32x4){0.f, 0.f, 0.f, 0.f};
    f32x4 acc1 = (f32x4){0.f, 0.f, 0.f, 0.f};
#pragma unroll
    for (int ty = 0; ty < 3; ++ty) {
      const short* rp = &ring[(y - 1 + ty) & 3][0][0];
#pragma unroll
      for (int tx = 0; tx < 3; ++tx) {
        const short8 a = *(const short8*)&rp[(x0 + ln15 + tx) * 32 + quad * 8];
        const int s = ty * 3 + tx;
        if (s & 1)
          acc1 = __builtin_amdgcn_mfma_f32_16x16x32_bf16(a, bfrag[s], acc1, 0, 0, 0);
        else
          acc0 = __builtin_amdgcn_mfma_f32_16x16x32_bf16(a, bfrag[s], acc0, 0, 0, 0);
      }
    }

    if (ln15 < 3) {
      float4 o;
      float v;
      v = acc0[0] + acc1[0] + bv; o.x = 1.f / (1.f + __expf(-2.f * v));
      v = acc0[1] + acc1[1] + bv; o.y = 1.f / (1.f + __expf(-2.f * v));
      v = acc0[2] + acc1[2] + bv; o.z = 1.f / (1.f + __expf(-2.f * v));
      v = acc0[3] + acc1[3] + bv; o.w = 1.f / (1.f + __expf(-2.f * v));
      *(float4*)&op[(size_t)ln15 * 4096 + y * 64 + x0 + quad * 4] = o;
    }

    if (pre) {
      short8 o = {0, 0, 0, 0, 0, 0, 0, 0};
      if (vld) {
#pragma unroll
        for (int u = 0; u < 8; ++u)
          o[u] = (short)f2bf(
              fmaf(bf2f((ushort)raw[u]), s0[skg + u], -s1[skg + u]));
      }
      *(short8*)&ring[Ypf & 3][spx + 1][skg] = o;
    }
    __syncthreads();
  }
}

// ======================= dense GEMM (encoder FC), fp32 =====================
__global__ __launch_bounds__(256) void gemm_abt(
    const float* __restrict__ A, const float* __restrict__ B,
    const float* __restrict__ bias, const float* __restrict__ stA, float invN,
    float* __restrict__ C, float* __restrict__ P, int K, int ldc, int col0,
    float alpha, int act) {
  __shared__ float As[16][68];
  __shared__ float Bsh[16][68];
  __shared__ float nrm[2][256];
  const int tid = threadIdx.x;
  if (stA) {
    const int c = tid;
    float m = stA[c] * invN;
    float var = stA[256 + c] * invN - m * m;
    float s = rsqrtf(var + EPS_BN);
    nrm[0][c] = s;
    nrm[1][c] = m * s;
    __syncthreads();
  }
  const int lm = tid >> 2, lk = (tid & 3) << 2;
  const int KS = gridDim.z;
  const int kChunk = K / KS;
  const int kStart = blockIdx.z * kChunk;
  const float* Arow = A + (size_t)(blockIdx.y * 64 + lm) * K + lk;
  const float* Brow = B + (size_t)(blockIdx.x * 64 + lm) * K + lk;
  float acc[4][4] = {};
  const int m0 = (tid >> 4) << 2, n0 = (tid & 15) << 2;

  for (int k0 = kStart; k0 < kStart + kChunk; k0 += 16) {
    float4 av = *(const float4*)(Arow + k0);
    float4 bv = *(const float4*)(Brow + k0);
    if (stA) {
      const int ch = (k0 + lk) >> 4;
      const float s = nrm[0][ch], ms = nrm[1][ch];
      av.x = fmaf(av.x, s, -ms);
      av.y = fmaf(av.y, s, -ms);
      av.z = fmaf(av.z, s, -ms);
      av.w = fmaf(av.w, s, -ms);
    }
    As[lk + 0][lm] = av.x; As[lk + 1][lm] = av.y;
    As[lk + 2][lm] = av.z; As[lk + 3][lm] = av.w;
    Bsh[lk + 0][lm] = bv.x; Bsh[lk + 1][lm] = bv.y;
    Bsh[lk + 2][lm] = bv.z; Bsh[lk + 3][lm] = bv.w;
    __syncthreads();
#pragma unroll
    for (int kk = 0; kk < 16; ++kk) {
      const float4 a = *(const float4*)&As[kk][m0];
      const float4 b = *(const float4*)&Bsh[kk][n0];
      acc[0][0] = fmaf(a.x, b.x, acc[0][0]); acc[0][1] = fmaf(a.x, b.y, acc[0][1]);
      acc[0][2] = fmaf(a.x, b.z, acc[0][2]); acc[0][3] = fmaf(a.x, b.w, acc[0][3]);
      acc[1][0] = fmaf(a.y, b.x, acc[1][0]); acc[1][1] = fmaf(a.y, b.y, acc[1][1]);
      acc[1][2] = fmaf(a.y, b.z, acc[1][2]); acc[1][3] = fmaf(a.y, b.w, acc[1][3]);
      acc[2][0] = fmaf(a.z, b.x, acc[2][0]); acc[2][1] = fmaf(a.z, b.y, acc[2][1]);
      acc[2][2] = fmaf(a.z, b.z, acc[2][2]); acc[2][3] = fmaf(a.z, b.w, acc[2][3]);
      acc[3][0] = fmaf(a.w, b.x, acc[3][0]); acc[3][1] = fmaf(a.w, b.y, acc[3][1]);
      acc[3][2] = fmaf(a.w, b.z, acc[3][2]); acc[3][3] = fmaf(a.w, b.w, acc[3][3]);
    }
    __syncthreads();
  }

  const int gm = blockIdx.y * 64 + m0;
  const int gn = blockIdx.x * 64 + n0;
  if (KS == 1) {
#pragma unroll
    for (int i = 0; i < 4; ++i) {
      float4 o;
      o.x = alpha * acc[i][0] + bias[gn + 0];
      o.y = alpha * acc[i][1] + bias[gn + 1];
      o.z = alpha * acc[i][2] + bias[gn + 2];
      o.w = alpha * acc[i][3] + bias[gn + 3];
      if (act == 1) {
        o.x = fmaxf(o.x, 0.f); o.y = fmaxf(o.y, 0.f);
        o.z = fmaxf(o.z, 0.f); o.w = fmaxf(o.w, 0.f);
      }
      *(float4*)&C[(size_t)(gm + i) * ldc + col0 + gn] = o;
    }
  } else {
    const int M = gridDim.y * 64, N = gridDim.x * 64;
#pragma unroll
    for (int i = 0; i < 4; ++i)
      *(float4*)&P[((size_t)blockIdx.z * M + gm + i) * N + gn] =
          make_float4(acc[i][0], acc[i][1], acc[i][2], acc[i][3]);
  }
}

__global__ __launch_bounds__(256) void gemm_reduce(
    const float* __restrict__ P, float* __restrict__ C,
    const float* __restrict__ bias, int M, int N, int ldc, int col0,
    float alpha, int act, int KS) {
  const int idx = blockIdx.x * 256 + threadIdx.x;
  if (idx >= M * N) return;
  const int m = idx / N, n = idx % N;
  float s = 0.f;
  for (int z = 0; z < KS; ++z) s += P[((size_t)z * M + m) * N + n];
  float v = alpha * s + bias[n];
  if (act == 1) v = fmaxf(v, 0.f);
  C[(size_t)m * ldc + col0 + n] = v;
}

// ======================= VQ =================================================
__global__ __launch_bounds__(256) void rowsq(const float* __restrict__ cb,
                                             float* __restrict__ csq) {
  const int row = blockIdx.x * 4 + (threadIdx.x >> 6);
  const int ln = threadIdx.x & 63;
  const float4 v = ((const float4*)(cb + (size_t)row * 256))[ln];
  float s = v.x * v.x + v.y * v.y + v.z * v.z + v.w * v.w;
#pragma unroll
  for (int off = 32; off > 0; off >>= 1) s += __shfl_down(s, off);
  if (ln == 0) csq[row] = s;
}

__global__ __launch_bounds__(256) void argmin_d2(const float* __restrict__ d2,
                                                 int* __restrict__ idx) {
  const int b = blockIdx.x, t = threadIdx.x;
  const float* row = d2 + (size_t)b * 8192;
  float best = 3.4e38f;
  int bi = 0x7fffffff;
  for (int k = t; k < 8192; k += 256) {
    const float v = row[k];
    if (v < best) { best = v; bi = k; }
  }
  __shared__ float bval[256];
  __shared__ int bidx[256];
  bval[t] = best;
  bidx[t] = bi;
  __syncthreads();
  for (int s = 128; s > 0; s >>= 1) {
    if (t < s) {
      const float ov = bval[t + s];
      const int oi = bidx[t + s];
      if (ov < bval[t] || (ov == bval[t] && oi < bidx[t])) {
        bval[t] = ov;
        bidx[t] = oi;
      }
    }
    __syncthreads();
  }
  if (t == 0) idx[b] = bidx[0];
}

__global__ __launch_bounds__(256) void vq_gather_loss(
    const float* __restrict__ ze, const float* __restrict__ cb,
    const int* __restrict__ idx, float* __restrict__ zq,
    float* __restrict__ lossacc) {
  const int b = blockIdx.x, d = threadIdx.x;
  const int i = b * 256 + d;
  const float q = cb[(size_t)idx[b] * 256 + d];
  zq[i] = q;
  const float df = ze[i] - q;
  float v = df * df;
  __shared__ float sh[256];
  sh[d] = v;
  __syncthreads();
  for (int s = 128; s > 0; s >>= 1) {
    if (d < s) sh[d] += sh[d + s];
    __syncthreads();
  }
  if (d == 0) atomicAdd(lossacc, sh[0]);
}

__global__ void write_loss(const float* __restrict__ lossacc,
                           float* __restrict__ out) {
  out[0] = 2.f * lossacc[0];
}

// ---------------------------------------------------------------------------
extern "C" void kernel_launch(void* const* d_in, const int* in_sizes, int n_in,
                              void* d_out, int out_size, void* d_ws,
                              size_t ws_size, hipStream_t stream) {
  const float* x = (const float*)d_in[0];
  const float* ew1 = (const float*)d_in[1];
  const float* eb1 = (const float*)d_in[2];
  const float* ew2 = (const float*)d_in[3];
  const float* eb2 = (const float*)d_in[4];
  const float* ew3 = (const float*)d_in[5];
  const float* eb3 = (const float*)d_in[6];
  const float* ew4 = (const float*)d_in[7];
  const float* eb4 = (const float*)d_in[8];
  const float* wmu = (const float*)d_in[9];
  const float* bmu = (const float*)d_in[10];
  const float* wcov = (const float*)d_in[11];
  const float* bcov = (const float*)d_in[12];
  const float* cb = (const float*)d_in[13];
  const float* wfc = (const float*)d_in[14];
  const float* bfc = (const float*)d_in[15];
  const float* wt1 = (const float*)d_in[16];
  const float* bt1 = (const float*)d_in[17];
  const float* wt2 = (const float*)d_in[18];
  const float* bt2 = (const float*)d_in[19];
  const float* wt3 = (const float*)d_in[20];
  const float* bt3 = (const float*)d_in[21];
  const float* wt31 = (const float*)d_in[22];
  const float* bt31 = (const float*)d_in[23];
  const float* wt4 = (const float*)d_in[24];
  const float* bt4 = (const float*)d_in[25];

  float* ws = (float*)d_ws;
  float* a1 = ws;               // NHWC [256,32,32,32] bf16 (reused as g3, bf16)
  float* a2 = a1 + 8388608;     // NHWC [256,16,16,64] bf16 (reused as g2, bf16)
  float* a3 = a2 + 4194304;     // NHWC [256,8,8,128] bf16  (reused as g1, bf16)
  float* a4 = a3 + 2097152;     // NHWC [256,4,4,256] fp32  (reused as g0, fp32)
  float* g31 = a4 + 1048576;    // NHWC [256,64,64,32] bf16 (region 33554432 f)
  float* d2 = g31;              // [256,8192]
  float* P = g31 + 2097152;     // 262144
  float* csq = g31 + 2359296;   // 8192
  float* a4n = g31 + 2367488;   // NCHW a4 copy
  float* wfcT = g31 + 3416064;  // 1048576
  float* bfcT = g31 + 4464640;  // 4096
  ushort* wTc2 = (ushort*)(g31 + 4468736);  // 18432 bf16
  ushort* wTc3 = (ushort*)(g31 + 4487168);  // 73728 bf16
  ushort* wTc4 = (ushort*)(g31 + 4560896);  // 294912 bf16
  float* ze = g31 + 33554432;   // [256,256]
  float* zq = ze + 65536;
  float* stats = zq + 65536;    // 8 layers x 512
  float* lossacc = stats + 4096;
  int* idx = (int*)(lossacc + 4);
  ushort* wTt1 = (ushort*)(lossacc + 4 + 256);  // 294912 bf16 (parity,perm)
  ushort* wTt2 = wTt1 + 294912;                 // 73728 bf16 (parity,perm)
  ushort* wTt3 = wTt2 + 73728;                  // 18432 bf16 (tap-major,perm)
  ushort* wTt31 = wTt3 + 18432;                 // 9216 bf16 (tap-major,perm)
  ushort* wT4 = wTt31 + 9216;                   // 4608 bf16 (convt4 B frags)
  ushort* wb1 = wT4 + 4608;                     // 1024 bf16 (conv1 B frags)
  float* g3 = a1;   // bf16 content
  float* g2 = a2;   // bf16 content
  float* g1 = a3;   // bf16 content
  float* g0 = a4;   // fp32

  float* st0 = stats + 0 * 512;
  float* st1 = stats + 1 * 512;
  float* st2 = stats + 2 * 512;
  float* st3 = stats + 3 * 512;
  float* st4 = stats + 4 * 512;
  float* st5 = stats + 5 * 512;
  float* st6 = stats + 6 * 512;
  float* st7 = stats + 7 * 512;

  hipMemsetAsync(stats, 0, (4096 + 8) * sizeof(float), stream);

  // ---- weight transposes (bf16) ----
  tr_convw_bf<<<72, 256, 0, stream>>>(ew2, wTc2, 32, 64, 18432, 1);
  tr_convw_bf<<<288, 256, 0, stream>>>(ew3, wTc3, 64, 128, 73728, 1);
  tr_convw_bf<<<1152, 256, 0, stream>>>(ew4, wTc4, 128, 256, 294912, 0);
  tr_convtw_bf<<<1152, 256, 0, stream>>>(wt1, wTt1, 256, 128, 294912);
  tr_convtw_bf<<<288, 256, 0, stream>>>(wt2, wTt2, 128, 64, 73728);
  tr_convtw_tc<<<72, 256, 0, stream>>>(wt3, wTt3, 64, 32, 18432);
  tr_convtw_tc<<<36, 256, 0, stream>>>(wt31, wTt31, 32, 32, 9216);
  tr_w4<<<18, 256, 0, stream>>>(wt4, wT4);
  tr_w1b<<<4, 256, 0, stream>>>(ew1, wb1);
  tr_fcdec<<<4096, 256, 0, stream>>>(wfc, bfc, wfcT, bfcT);
  rowsq<<<2048, 256, 0, stream>>>(cb, csq);

  // ---- encoder ----
  conv1_mfma<<<1024, 256, 0, stream>>>(x, wb1, eb1, (ushort*)a1, st0);
  mfmaconv<64, 0, 32, 32, 64, true, true, true>
      <<<dim3(1, 1024), 256, 0, stream>>>(a1, wTc2, eb2, st0,
                                          1.f / (256.f * 1024.f), a2, st1);
  mfmaconv<64, 0, 16, 64, 128, true, true, true>
      <<<dim3(2, 256), 256, 0, stream>>>(a2, wTc3, eb3, st1,
                                         1.f / (256.f * 256.f), a3, st2);
  mfmaconv<64, 0, 8, 128, 256, true, true, false>
      <<<dim3(4, 64), 256, 0, stream>>>(a3, wTc4, eb4, st2,
                                        1.f / (256.f * 64.f), a4, st3);
  tr_a4<<<4096, 256, 0, stream>>>(a4, a4n);

  // ---- encoder FC (fp32, split-K) ----
  gemm_abt<<<dim3(2, 4, 8), 256, 0, stream>>>(a4n, wmu, nullptr, st3,
                                              1.f / 4096.f, nullptr, P, 4096,
                                              0, 0, 1.f, 0);
  gemm_reduce<<<128, 256, 0, stream>>>(P, ze, bmu, 256, 128, 256, 0, 1.f, 0, 8);
  gemm_abt<<<dim3(2, 4, 8), 256, 0, stream>>>(a4n, wcov, nullptr, st3,
                                              1.f / 4096.f, nullptr, P, 4096,
                                              0, 0, 1.f, 0);
  gemm_reduce<<<128, 256, 0, stream>>>(P, ze, bcov, 256, 128, 256, 128, 1.f, 1, 8);

  // ---- VQ: d2 = csq[n] - 2*ze.cb (|ze|^2 dropped, argmin-invariant) ----
  gemm_bf_abt<<<dim3(128, 4), 256, 0, stream>>>(ze, cb, csq, d2, 256, 8192,
                                                -2.f);
  argmin_d2<<<256, 256, 0, stream>>>(d2, idx);
  vq_gather_loss<<<256, 256, 0, stream>>>(ze, cb, idx, zq, lossacc);

  // ---- decoder FC (bf16 MFMA) ----
  gemm_bf_abt<<<dim3(64, 4), 256, 0, stream>>>(zq, wfcT, bfcT, g0, 256, 4096,
                                               1.f);

  // ---- decoder ----
  mfmaconv<64, 1, 4, 256, 128, false, false, true>
      <<<dim3(2, 64, 4), 256, 0, stream>>>(g0, wTt1, bt1, nullptr, 0.f, g1,
                                           st4);
  mfmaconv<64, 1, 8, 128, 64, true, true, true>
      <<<dim3(1, 256, 4), 256, 0, stream>>>(g1, wTt2, bt2, st4,
                                            1.f / (256.f * 64.f), g2, st5);
  convt_mfma<16, 64, true, true, 2><<<512, 256, 0, stream>>>(
      g2, wTt3, bt3, st5, 1.f / (256.f * 256.f), g3, st6);
  convt_mfma<32, 32, true, true, 4><<<1024, 256, 0, stream>>>(
      g3, wTt31, bt31, st6, 1.f / (256.f * 1024.f), g31, st7);

  convt4_mfma<<<1024, 256, 0, stream>>>(g31, wT4, bt4, st7,
                                        1.f / (256.f * 4096.f), (float*)d_out);
  write_loss<<<1, 1, 0, stream>>>(lossacc, (float*)d_out + 3145728);
}

// Round 12
// 471.443 us; speedup vs baseline: 1.4033x; 1.0553x over previous
//
#include <hip/hip_runtime.h>
#include <cmath>

// ---------------------------------------------------------------------------
// VQ-VAE forward. B=256, C=3, HW=64, D=256, K=8192, LAT=128
// R18: (a) all 11 weight-prep kernels fused into ONE fused_pre megakernel
// (block-range dispatch, 9226 blocks) -> 10 fewer serialized launches;
// (b) conv4 stores NCHW directly (OUTNCHW template flag) -> tr_a4 kernel
// and its 8.4MB round-trip eliminated. Rest identical to R17 (497.5us):
// OUTBF packed-bf16 a2/a3/g1/g2, R15 gemm_bf_abt, R14 pipelined k-loop,
// R13 conv1_mfma, R11 convt4 ring, R10 multi-strip (NSTRIP 2/4), R9 tail.
// ---------------------------------------------------------------------------

#define EPS_BN 1e-5f
typedef unsigned short ushort;
typedef short short8 __attribute__((ext_vector_type(8)));
typedef ushort us4 __attribute__((ext_vector_type(4)));
typedef float f32x4 __attribute__((ext_vector_type(4)));

__device__ __forceinline__ float lrelu(float v) { return v >= 0.f ? v : 0.01f * v; }
__device__ __forceinline__ ushort f2bf(float f) {
  unsigned u = __float_as_uint(f);
  return (ushort)((u + 0x7FFF + ((u >> 16) & 1)) >> 16);
}
__device__ __forceinline__ float bf2f(ushort u) {
  return __uint_as_float(((unsigned)u) << 16);
}

// ======================= fused weight-prep megakernel ======================
__device__ __forceinline__ void d_convw(const float* __restrict__ w,
                                        ushort* __restrict__ wT, int CIN,
                                        int COUT, int total, int perm, int vb,
                                        int tid) {
  int i = vb * 256 + tid;
  if (i >= total) return;
  int co = i / (9 * CIN);
  int r = i - co * 9 * CIN;
  int t = r / CIN, ci = r - t * CIN;
  int co_s = co;
  if (perm) {
    const int cr = co & 63;
    co_s = (co - cr) + ((cr & 3) << 4) + (cr >> 2);
  }
  wT[(size_t)co_s * 9 * CIN + r] = f2bf(w[((size_t)co * CIN + ci) * 9 + t]);
}

__device__ __forceinline__ void d_convtw(const float* __restrict__ w,
                                         ushort* __restrict__ wT, int CIN,
                                         int COUT, int total, int vb, int tid) {
  int i = vb * 256 + tid;
  if (i >= total) return;
  const int cc = CIN * COUT;
  int p, base, Kp;
  if (i < cc) { p = 0; base = 0; Kp = CIN; }
  else if (i < 3 * cc) { p = 1; base = cc; Kp = 2 * CIN; }
  else if (i < 5 * cc) { p = 2; base = 3 * cc; Kp = 2 * CIN; }
  else { p = 3; base = 5 * cc; Kp = 4 * CIN; }
  const int r = i - base;
  const int co = r / Kp;
  const int q = r - co * Kp;
  const int tix = q / CIN, ci = q - (q / CIN) * CIN;
  const int py = p >> 1, px = p & 1;
  const int nx = px ? 2 : 1;
  const int kyi = tix / nx, kxi = tix - kyi * nx;
  const int ky = py ? (kyi == 0 ? 0 : 2) : 1;
  const int kx = px ? (kxi == 0 ? 0 : 2) : 1;
  const int cr = co & 63;
  const int co_s = (co - cr) + ((cr & 3) << 4) + (cr >> 2);
  wT[base + (size_t)co_s * Kp + q] =
      f2bf(w[((size_t)ci * COUT + co) * 9 + ky * 3 + kx]);
}

__device__ __forceinline__ void d_convtw_tc(const float* __restrict__ w,
                                            ushort* __restrict__ wT, int CIN,
                                            int COUT, int total, int vb,
                                            int tid) {
  int i = vb * 256 + tid;
  if (i >= total) return;
  int ci = i % CIN;
  int tmp = i / CIN;
  int co = tmp % COUT;
  int t = tmp / COUT;
  const int co_slot = ((co & 1) << 4) | (co >> 1);
  wT[((size_t)t * COUT + co_slot) * CIN + ci] =
      f2bf(w[((size_t)ci * COUT + co) * 9 + t]);
}

__device__ __forceinline__ void d_w4(const float* __restrict__ w,
                                     ushort* __restrict__ wT, int vb, int tid) {
  int i = vb * 256 + tid;
  if (i >= 4608) return;
  const int s = i >> 9;
  const int l = (i >> 3) & 63;
  const int j = i & 7;
  const int nn = l & 15;
  const int ci = ((l >> 4) << 3) + j;
  const int ty = s / 3, tx = s - ty * 3;
  ushort v = 0;
  if (nn < 3)
    v = f2bf(w[((size_t)ci * 3 + nn) * 9 + (2 - ty) * 3 + (2 - tx)]);
  wT[i] = v;
}

__device__ __forceinline__ void d_w1b(const float* __restrict__ w,
                                      ushort* __restrict__ wT, int vb,
                                      int tid) {
  int i = vb * 256 + tid;
  if (i >= 1024) return;
  const int j = i & 7, l = (i >> 3) & 63, f = i >> 9;
  const int c = 2 * (l & 15) + f;
  const int k = ((l >> 4) << 3) + j;
  ushort v = 0;
  if (k < 27) {
    const int ci = k / 9, r = k - ci * 9;
    v = f2bf(w[((size_t)c * 3 + ci) * 9 + r]);
  }
  wT[i] = v;
}

__device__ __forceinline__ void d_fcdec(const float* __restrict__ in,
                                        const float* __restrict__ bin,
                                        float* __restrict__ out,
                                        float* __restrict__ bout, int vb,
                                        int tid) {
  int i = vb * 256 + tid;
  int k = i >> 8, d = i & 255;
  int kp = (k & 15) * 256 + (k >> 4);
  out[(size_t)kp * 256 + d] = in[i];
  if (d == 0) bout[kp] = bin[k];
}

__device__ __forceinline__ void d_rowsq(const float* __restrict__ cb,
                                        float* __restrict__ csq, int vb,
                                        int tid) {
  const int row = vb * 4 + (tid >> 6);
  const int ln = tid & 63;
  const float4 v = ((const float4*)(cb + (size_t)row * 256))[ln];
  float s = v.x * v.x + v.y * v.y + v.z * v.z + v.w * v.w;
#pragma unroll
  for (int off = 32; off > 0; off >>= 1) s += __shfl_down(s, off);
  if (ln == 0) csq[row] = s;
}

// block ranges: 72|288|1152|1152|288|72|36|18|4|4096|2048 = 9226
__global__ __launch_bounds__(256) void fused_pre(
    const float* __restrict__ ew2, ushort* __restrict__ wTc2,
    const float* __restrict__ ew3, ushort* __restrict__ wTc3,
    const float* __restrict__ ew4, ushort* __restrict__ wTc4,
    const float* __restrict__ wt1, ushort* __restrict__ wTt1,
    const float* __restrict__ wt2, ushort* __restrict__ wTt2,
    const float* __restrict__ wt3, ushort* __restrict__ wTt3,
    const float* __restrict__ wt31, ushort* __restrict__ wTt31,
    const float* __restrict__ wt4, ushort* __restrict__ wT4,
    const float* __restrict__ ew1, ushort* __restrict__ wb1,
    const float* __restrict__ wfc, const float* __restrict__ bfc,
    float* __restrict__ wfcT, float* __restrict__ bfcT,
    const float* __restrict__ cb, float* __restrict__ csq) {
  const int tid = threadIdx.x;
  int b = blockIdx.x;
  if (b < 72) { d_convw(ew2, wTc2, 32, 64, 18432, 1, b, tid); return; }
  b -= 72;
  if (b < 288) { d_convw(ew3, wTc3, 64, 128, 73728, 1, b, tid); return; }
  b -= 288;
  if (b < 1152) { d_convw(ew4, wTc4, 128, 256, 294912, 0, b, tid); return; }
  b -= 1152;
  if (b < 1152) { d_convtw(wt1, wTt1, 256, 128, 294912, b, tid); return; }
  b -= 1152;
  if (b < 288) { d_convtw(wt2, wTt2, 128, 64, 73728, b, tid); return; }
  b -= 288;
  if (b < 72) { d_convtw_tc(wt3, wTt3, 64, 32, 18432, b, tid); return; }
  b -= 72;
  if (b < 36) { d_convtw_tc(wt31, wTt31, 32, 32, 9216, b, tid); return; }
  b -= 36;
  if (b < 18) { d_w4(wt4, wT4, b, tid); return; }
  b -= 18;
  if (b < 4) { d_w1b(ew1, wb1, b, tid); return; }
  b -= 4;
  if (b < 4096) { d_fcdec(wfc, bfc, wfcT, bfcT, b, tid); return; }
  b -= 4096;
  d_rowsq(cb, csq, b, tid);
}

// ======================= bf16 MFMA implicit-GEMM conv / convT ==============
// R14 pipeline. OUTBF: packed-bf16 output, slot f*16+l = channel 4l+f.
// OUTNCHW (MODE 0 only): scalar fp32 stores directly in NCHW [n][c][px].
template <int TN, int MODE, int IH, int CIN, int COUT, bool HASN, bool INBF,
          bool OUTBF, bool OUTNCHW>
__global__ __launch_bounds__(256) void mfmaconv(
    const float* __restrict__ X, const ushort* __restrict__ WT,
    const float* __restrict__ bias, const float* __restrict__ st, float invN,
    float* __restrict__ Y, float* __restrict__ stOut) {
  constexpr int OH = (MODE == 0) ? IH / 2 : 2 * IH;
  constexpr int NF = TN / 16;
  static_assert(!OUTBF || NF == 4, "OUTBF requires NF==4");
  __shared__ short As[2][64][40];
  __shared__ short Bs[2][TN][40];
  __shared__ float nrm0[HASN ? CIN : 4], nrm1[HASN ? CIN : 4];
  __shared__ float redS[4][TN], redQ[4][TN];
  const int tid = threadIdx.x;
  const int wv = tid >> 6, lane = tid & 63;
  const int quad = lane >> 4, ln15 = tid & 15;
  if (HASN) {
    for (int c = tid; c < CIN; c += 256) {
      float m = st[c] * invN;
      float var = st[256 + c] * invN - m * m;
      float s = rsqrtf(var + EPS_BN);
      nrm0[c] = s;
      nrm1[c] = m * s;
    }
    __syncthreads();
  }
  int py = 0, px = 0, nx = 1, K = 9 * CIN;
  const ushort* W = WT;
  if (MODE == 1) {
    const int pz = blockIdx.z;
    py = pz >> 1;
    px = pz & 1;
    nx = px ? 2 : 1;
    const int ny = py ? 2 : 1;
    K = ny * nx * CIN;
    const int pre[4] = {0, 1, 3, 5};
    W = WT + (size_t)pre[pz] * CIN * COUT;
  }
  const int gyTM = blockIdx.y * 64;
  const int gxTN = blockIdx.x * TN;

  const int sm = tid & 63, skg = (tid >> 6) * 8;
  const int bn = tid >> 2, bkg = (tid & 3) * 8;
  int baseNB, baseIY, baseIX;
  {
    const int gm = gyTM + sm;
    if (MODE == 0) {
      const int ni = gm / (OH * OH), r = gm % (OH * OH);
      baseNB = ni * IH * IH;
      baseIY = 2 * (r / OH) - 1;
      baseIX = 2 * (r % OH) - 1;
    } else {
      const int ni = gm / (IH * IH), r = gm % (IH * IH);
      baseNB = ni * IH * IH;
      baseIY = r / IH;
      baseIX = r % IH;
    }
  }
  f32x4 acc[NF];
#pragma unroll
  for (int f = 0; f < NF; ++f) acc[f] = (f32x4){0.f, 0.f, 0.f, 0.f};

  const int nsteps = K / 32;

  // ---- prologue: stage step 0 into buf 0 ----
  {
    int iy, ix;
    if (MODE == 0) {
      iy = baseIY;
      ix = baseIX;
    } else {
      iy = baseIY + (py ? 1 : 0);
      ix = baseIX + (px ? 1 : 0);
    }
    const bool ok =
        ((unsigned)iy < (unsigned)IH) && ((unsigned)ix < (unsigned)IH);
    float v[8] = {0.f, 0.f, 0.f, 0.f, 0.f, 0.f, 0.f, 0.f};
    if (ok) {
      if constexpr (INBF) {
        const ushort* xp =
            (const ushort*)X + ((size_t)baseNB + iy * IH + ix) * CIN + skg;
        const short8 raw = *(const short8*)xp;
#pragma unroll
        for (int u = 0; u < 8; ++u) v[u] = bf2f((ushort)raw[u]);
      } else {
        const float* xp = &X[((size_t)baseNB + iy * IH + ix) * CIN + skg];
        const float4 va = *(const float4*)xp, vb = *(const float4*)(xp + 4);
        v[0] = va.x; v[1] = va.y; v[2] = va.z; v[3] = va.w;
        v[4] = vb.x; v[5] = vb.y; v[6] = vb.z; v[7] = vb.w;
      }
      if (HASN) {
#pragma unroll
        for (int u = 0; u < 8; ++u)
          v[u] = fmaf(v[u], nrm0[skg + u], -nrm1[skg + u]);
      }
    }
    short8 o;
#pragma unroll
    for (int u = 0; u < 8; ++u) o[u] = (short)f2bf(v[u]);
    *(short8*)&As[0][sm][skg] = o;
    if (tid < TN * 4)
      *(short8*)&Bs[0][bn][bkg] =
          *(const short8*)&W[(size_t)(gxTN + bn) * K + bkg];
  }
  __syncthreads();

  for (int kk = 0; kk < nsteps; ++kk) {
    const int cur = kk & 1, nxt = cur ^ 1;

    // ---- issue next step's global loads into regs ----
    bool okN = false;
    int ci0N = 0;
    short8 rawN;
    float4 vaN, vbN;
    short8 rawBN;
    const bool hasNext = (kk + 1 < nsteps);
    if (hasNext) {
      const int k0n = (kk + 1) * 32;
      const int t = k0n / CIN;
      ci0N = k0n - t * CIN;
      int iy, ix;
      if (MODE == 0) {
        iy = baseIY + t / 3;
        ix = baseIX + (t - (t / 3) * 3);
      } else {
        const int kyi = t / nx, kxi = t - (t / nx) * nx;
        iy = baseIY + ((py && kyi == 0) ? 1 : 0);
        ix = baseIX + ((px && kxi == 0) ? 1 : 0);
      }
      okN = ((unsigned)iy < (unsigned)IH) && ((unsigned)ix < (unsigned)IH);
      if (okN) {
        if constexpr (INBF) {
          const ushort* xp = (const ushort*)X +
                             ((size_t)baseNB + iy * IH + ix) * CIN + ci0N + skg;
          rawN = *(const short8*)xp;
        } else {
          const float* xp =
              &X[((size_t)baseNB + iy * IH + ix) * CIN + ci0N + skg];
          vaN = *(const float4*)xp;
          vbN = *(const float4*)(xp + 4);
        }
      }
      if (tid < TN * 4)
        rawBN = *(const short8*)&W[(size_t)(gxTN + bn) * K + k0n + bkg];
    }

    // ---- MFMAs on buf[cur] ----
    const short8 a = *(const short8*)&As[cur][wv * 16 + ln15][quad * 8];
#pragma unroll
    for (int f = 0; f < NF; ++f) {
      const short8 b = *(const short8*)&Bs[cur][f * 16 + ln15][quad * 8];
      acc[f] = __builtin_amdgcn_mfma_f32_16x16x32_bf16(a, b, acc[f], 0, 0, 0);
    }

    // ---- convert + write next step into buf[nxt] ----
    if (hasNext) {
      float v[8] = {0.f, 0.f, 0.f, 0.f, 0.f, 0.f, 0.f, 0.f};
      if (okN) {
        if constexpr (INBF) {
#pragma unroll
          for (int u = 0; u < 8; ++u) v[u] = bf2f((ushort)rawN[u]);
        } else {
          v[0] = vaN.x; v[1] = vaN.y; v[2] = vaN.z; v[3] = vaN.w;
          v[4] = vbN.x; v[5] = vbN.y; v[6] = vbN.z; v[7] = vbN.w;
        }
        if (HASN) {
          const int c = ci0N + skg;
#pragma unroll
          for (int u = 0; u < 8; ++u)
            v[u] = fmaf(v[u], nrm0[c + u], -nrm1[c + u]);
        }
      }
      short8 o;
#pragma unroll
      for (int u = 0; u < 8; ++u) o[u] = (short)f2bf(v[u]);
      *(short8*)&As[nxt][sm][skg] = o;
      if (tid < TN * 4) *(short8*)&Bs[nxt][bn][bkg] = rawBN;
    }
    __syncthreads();
  }

  size_t maddr[4];
#pragma unroll
  for (int r = 0; r < 4; ++r) {
    const int m = gyTM + wv * 16 + quad * 4 + r;
    if (MODE == 0) {
      const int ni = m / (OH * OH), rr = m % (OH * OH);
      if constexpr (OUTNCHW)
        maddr[r] = (size_t)ni * COUT * (OH * OH) + rr;
      else
        maddr[r] = (((size_t)ni * OH + rr / OH) * OH + rr % OH) * COUT;
    } else {
      const int ni = m / (IH * IH), rr = m % (IH * IH);
      const int oy = 2 * (rr / IH) + py, ox = 2 * (rr % IH) + px;
      maddr[r] = (((size_t)ni * OH + oy) * OH + ox) * COUT;
    }
  }
  if constexpr (OUTBF) {
    // lane owns channels ch0..ch0+3 (slot f*16+l = channel 4l+f)
    const int ch0 = gxTN + 4 * ln15;
    const float b0 = bias[ch0 + 0], b1 = bias[ch0 + 1];
    const float b2 = bias[ch0 + 2], b3 = bias[ch0 + 3];
    ushort* Yb = (ushort*)Y;
    float cS[4] = {0.f, 0.f, 0.f, 0.f}, cQ[4] = {0.f, 0.f, 0.f, 0.f};
#pragma unroll
    for (int r = 0; r < 4; ++r) {
      const float o0 = lrelu(acc[0][r] + b0);
      const float o1 = lrelu(acc[1][r] + b1);
      const float o2 = lrelu(acc[2][r] + b2);
      const float o3 = lrelu(acc[3][r] + b3);
      cS[0] += o0; cQ[0] += o0 * o0;
      cS[1] += o1; cQ[1] += o1 * o1;
      cS[2] += o2; cQ[2] += o2 * o2;
      cS[3] += o3; cQ[3] += o3 * o3;
      uint2 pk;
      pk.x = (unsigned)f2bf(o0) | ((unsigned)f2bf(o1) << 16);
      pk.y = (unsigned)f2bf(o2) | ((unsigned)f2bf(o3) << 16);
      *(uint2*)&Yb[maddr[r] + ch0] = pk;
    }
#pragma unroll
    for (int f = 0; f < 4; ++f) {
      float s_ = cS[f], q_ = cQ[f];
      s_ += __shfl_down(s_, 32); s_ += __shfl_down(s_, 16);
      q_ += __shfl_down(q_, 32); q_ += __shfl_down(q_, 16);
      if (lane < 16) { redS[wv][f * 16 + ln15] = s_; redQ[wv][f * 16 + ln15] = q_; }
    }
    __syncthreads();
    if (tid < TN) {
      float S = redS[0][tid] + redS[1][tid] + redS[2][tid] + redS[3][tid];
      float Q = redQ[0][tid] + redQ[1][tid] + redQ[2][tid] + redQ[3][tid];
      const int ch = gxTN + 4 * (tid & 15) + (tid >> 4);
      atomicAdd(&stOut[ch], S);
      atomicAdd(&stOut[256 + ch], Q);
    }
  } else {
#pragma unroll
    for (int f = 0; f < NF; ++f) {
      const int col = gxTN + f * 16 + ln15;
      const float bv = bias[col];
      float cS = 0.f, cQ = 0.f;
#pragma unroll
      for (int r = 0; r < 4; ++r) {
        const float o = lrelu(acc[f][r] + bv);
        cS += o;
        cQ += o * o;
        if constexpr (OUTNCHW)
          Y[maddr[r] + (size_t)col * (OH * OH)] = o;
        else
          Y[maddr[r] + col] = o;
      }
      cS += __shfl_down(cS, 32); cS += __shfl_down(cS, 16);
      cQ += __shfl_down(cQ, 32); cQ += __shfl_down(cQ, 16);
      if (lane < 16) { redS[wv][f * 16 + ln15] = cS; redQ[wv][f * 16 + ln15] = cQ; }
    }
    __syncthreads();
    if (tid < TN) {
      float S = redS[0][tid] + redS[1][tid] + redS[2][tid] + redS[3][tid];
      float Q = redQ[0][tid] + redQ[1][tid] + redQ[2][tid] + redQ[3][tid];
      atomicAdd(&stOut[gxTN + tid], S);
      atomicAdd(&stOut[256 + gxTN + tid], Q);
    }
  }
}

// ======================= bf16 MFMA dense GEMM: C = alpha*(A.B^T) + bias ====
__global__ __launch_bounds__(256) void gemm_bf_abt(
    const float* __restrict__ A, const float* __restrict__ B,
    const float* __restrict__ bias, float* __restrict__ C, int K, int N,
    float alpha) {
  __shared__ short As[2][64][40];
  __shared__ short Bs[2][64][40];
  const int tid = threadIdx.x;
  const int wv = tid >> 6, lane = tid & 63;
  const int quad = lane >> 4, ln15 = lane & 15;
  const int gm0 = blockIdx.y * 64, gn0 = blockIdx.x * 64;
  const int sm = tid & 63, skg = (tid >> 6) * 8;
  const int bn = tid >> 2, bkg = (tid & 3) * 8;
  const float* Ap = A + (size_t)(gm0 + sm) * K + skg;
  const float* Bp = B + (size_t)(gn0 + bn) * K + bkg;
  f32x4 acc[4];
#pragma unroll
  for (int f = 0; f < 4; ++f) acc[f] = (f32x4){0.f, 0.f, 0.f, 0.f};
  const int nsteps = K / 32;

  {
    const float4 va = *(const float4*)Ap, vb = *(const float4*)(Ap + 4);
    short8 o;
    o[0] = (short)f2bf(va.x); o[1] = (short)f2bf(va.y);
    o[2] = (short)f2bf(va.z); o[3] = (short)f2bf(va.w);
    o[4] = (short)f2bf(vb.x); o[5] = (short)f2bf(vb.y);
    o[6] = (short)f2bf(vb.z); o[7] = (short)f2bf(vb.w);
    *(short8*)&As[0][sm][skg] = o;
    const float4 wa = *(const float4*)Bp, wb = *(const float4*)(Bp + 4);
    short8 p;
    p[0] = (short)f2bf(wa.x); p[1] = (short)f2bf(wa.y);
    p[2] = (short)f2bf(wa.z); p[3] = (short)f2bf(wa.w);
    p[4] = (short)f2bf(wb.x); p[5] = (short)f2bf(wb.y);
    p[6] = (short)f2bf(wb.z); p[7] = (short)f2bf(wb.w);
    *(short8*)&Bs[0][bn][bkg] = p;
  }
  __syncthreads();

  for (int kk = 0; kk < nsteps; ++kk) {
    const int cur = kk & 1, nxt = cur ^ 1;
    const bool hasNext = (kk + 1 < nsteps);
    float4 vaN, vbN, waN, wbN;
    if (hasNext) {
      const int k0n = (kk + 1) * 32;
      vaN = *(const float4*)(Ap + k0n);
      vbN = *(const float4*)(Ap + k0n + 4);
      waN = *(const float4*)(Bp + k0n);
      wbN = *(const float4*)(Bp + k0n + 4);
    }

    const short8 a = *(const short8*)&As[cur][wv * 16 + ln15][quad * 8];
#pragma unroll
    for (int f = 0; f < 4; ++f) {
      const short8 b = *(const short8*)&Bs[cur][f * 16 + ln15][quad * 8];
      acc[f] = __builtin_amdgcn_mfma_f32_16x16x32_bf16(a, b, acc[f], 0, 0, 0);
    }

    if (hasNext) {
      short8 o;
      o[0] = (short)f2bf(vaN.x); o[1] = (short)f2bf(vaN.y);
      o[2] = (short)f2bf(vaN.z); o[3] = (short)f2bf(vaN.w);
      o[4] = (short)f2bf(vbN.x); o[5] = (short)f2bf(vbN.y);
      o[6] = (short)f2bf(vbN.z); o[7] = (short)f2bf(vbN.w);
      *(short8*)&As[nxt][sm][skg] = o;
      short8 p;
      p[0] = (short)f2bf(waN.x); p[1] = (short)f2bf(waN.y);
      p[2] = (short)f2bf(waN.z); p[3] = (short)f2bf(waN.w);
      p[4] = (short)f2bf(wbN.x); p[5] = (short)f2bf(wbN.y);
      p[6] = (short)f2bf(wbN.z); p[7] = (short)f2bf(wbN.w);
      *(short8*)&Bs[nxt][bn][bkg] = p;
    }
    __syncthreads();
  }

#pragma unroll
  for (int f = 0; f < 4; ++f) {
    const int col = gn0 + f * 16 + ln15;
    const float bv = bias[col];
#pragma unroll
    for (int r = 0; r < 4; ++r) {
      const int row = gm0 + wv * 16 + quad * 4 + r;
      C[(size_t)row * N + col] = fmaf(alpha, acc[f][r], bv);
    }
  }
}

// ======================= halo-tile merged convT (COUT=32, CIN<=64) =========
template <int IH, int CIN, bool HASN, bool INBF, int NSTRIP>
__global__ __launch_bounds__(256) void convt_mfma(
    const float* __restrict__ X, const ushort* __restrict__ WT,
    const float* __restrict__ bias, const float* __restrict__ st, float invN,
    float* __restrict__ Y, float* __restrict__ stOut) {
  constexpr int OH = 2 * IH;
  constexpr int L = (IH == 32) ? 5 : 4;
  constexpr int RSPAN = 64 / IH;
  constexpr int NP = (RSPAN + 1) * (IH + 1);
  constexpr int LK = CIN + 8;
  constexpr int TI = NP * (CIN / 8);
  constexpr int ITER = (TI + 255) / 256;
  __shared__ short As[2][NP][LK];
  __shared__ short Ws[9 * 32][LK];
  __shared__ float nrm0[HASN ? CIN : 4], nrm1[HASN ? CIN : 4];
  __shared__ float redS[4][32], redQ[4][32];
  const int tid = threadIdx.x;
  const int wv = tid >> 6, lane = tid & 63;
  const int quad = lane >> 4, ln15 = lane & 15;
  if (HASN) {
    for (int c = tid; c < CIN; c += 256) {
      float m = st[c] * invN;
      float var = st[256 + c] * invN - m * m;
      float s = rsqrtf(var + EPS_BN);
      nrm0[c] = s;
      nrm1[c] = m * s;
    }
  }
  for (int i = tid; i < 9 * 32 * (CIN / 8); i += 256) {
    const int row = i / (CIN / 8), kg = (i % (CIN / 8)) * 8;
    *(short8*)&Ws[row][kg] = *(const short8*)&WT[(size_t)row * CIN + kg];
  }
  __syncthreads();

  const int strip0 = blockIdx.x * NSTRIP;
  const int n = (strip0 * 64) / (IH * IH);
  const int iy0base = (strip0 * 64 - n * (IH * IH)) >> L;

#pragma unroll
  for (int it = 0; it < ITER; ++it) {
    const int i = tid + it * 256;
    if (i < TI) {
      const int slot = i / (CIN / 8), kg = (i % (CIN / 8)) * 8;
      const int ty = slot / (IH + 1), tx = slot - ty * (IH + 1);
      const int iy = iy0base + ty;
      short8 o = {0, 0, 0, 0, 0, 0, 0, 0};
      if (iy < IH && tx < IH) {
        float v[8];
        if constexpr (INBF) {
          const ushort* xp =
              (const ushort*)X + (((size_t)n * IH + iy) * IH + tx) * CIN + kg;
          const short8 raw = *(const short8*)xp;
#pragma unroll
          for (int u = 0; u < 8; ++u) v[u] = bf2f((ushort)raw[u]);
        } else {
          const float* xp = &X[(((size_t)n * IH + iy) * IH + tx) * CIN + kg];
          const float4 va = *(const float4*)xp, vb = *(const float4*)(xp + 4);
          v[0] = va.x; v[1] = va.y; v[2] = va.z; v[3] = va.w;
          v[4] = vb.x; v[5] = vb.y; v[6] = vb.z; v[7] = vb.w;
        }
        if (HASN) {
#pragma unroll
          for (int u = 0; u < 8; ++u)
            v[u] = fmaf(v[u], nrm0[kg + u], -nrm1[kg + u]);
        }
#pragma unroll
        for (int u = 0; u < 8; ++u) o[u] = (short)f2bf(v[u]);
      }
      *(short8*)&As[0][slot][kg] = o;
    }
  }
  __syncthreads();

  const int rA = wv * 16 + ln15;
  const int baseIdx = (rA >> L) * (IH + 1) + (rA & (IH - 1));
  constexpr int NT[4] = {4, 2, 2, 1};
  constexpr int TT[4][4] = {{4, 5, 7, 8}, {3, 6, 0, 0}, {1, 2, 0, 0}, {0, 0, 0, 0}};
  const float bv0 = bias[2 * ln15], bv1 = bias[2 * ln15 + 1];
  unsigned* Yp = (unsigned*)Y;
  float cS[2] = {0.f, 0.f}, cQ[2] = {0.f, 0.f};

#pragma unroll
  for (int s = 0; s < NSTRIP; ++s) {
    const int cur = s & 1, nxt = cur ^ 1;
    const int iy0 = iy0base + s * RSPAN;

    short8 rbf[ITER];
    float4 rva[ITER], rvb[ITER];
    bool vld[ITER];
    if (s + 1 < NSTRIP) {
      const int iyN0 = iy0 + RSPAN;
#pragma unroll
      for (int it = 0; it < ITER; ++it) {
        vld[it] = false;
        const int i = tid + it * 256;
        if (i < TI) {
          const int slot = i / (CIN / 8), kg = (i % (CIN / 8)) * 8;
          const int ty = slot / (IH + 1), tx = slot - ty * (IH + 1);
          const int iy = iyN0 + ty;
          if (iy < IH && tx < IH) {
            vld[it] = true;
            if constexpr (INBF) {
              const ushort* xp = (const ushort*)X +
                                 (((size_t)n * IH + iy) * IH + tx) * CIN + kg;
              rbf[it] = *(const short8*)xp;
            } else {
              const float* xp =
                  &X[(((size_t)n * IH + iy) * IH + tx) * CIN + kg];
              rva[it] = *(const float4*)xp;
              rvb[it] = *(const float4*)(xp + 4);
            }
          }
        }
      }
    }

    f32x4 acc[4][2];
#pragma unroll
    for (int p = 0; p < 4; ++p)
#pragma unroll
      for (int f = 0; f < 2; ++f) acc[p][f] = (f32x4){0.f, 0.f, 0.f, 0.f};
#pragma unroll
    for (int sh = 0; sh < 4; ++sh) {
      const int off = (sh >> 1) * (IH + 1) + (sh & 1);
#pragma unroll
      for (int j = 0; j < NT[sh]; ++j) {
        const int t = TT[sh][j];
        const int ky = t / 3, kx = t - ky * 3;
        const int par = ((ky == 1) ? 0 : 2) + ((kx == 1) ? 0 : 1);
#pragma unroll
        for (int ks = 0; ks < CIN / 32; ++ks) {
          const short8 a =
              *(const short8*)&As[cur][baseIdx + off][ks * 32 + quad * 8];
#pragma unroll
          for (int f = 0; f < 2; ++f) {
            const short8 b =
                *(const short8*)&Ws[t * 32 + f * 16 + ln15][ks * 32 + quad * 8];
            acc[par][f] = __builtin_amdgcn_mfma_f32_16x16x32_bf16(
                a, b, acc[par][f], 0, 0, 0);
          }
        }
      }
    }

#pragma unroll
    for (int i = 0; i < 4; ++i) {
      const int rD = wv * 16 + quad * 4 + i;
      const int ry = rD >> L, rx = rD & (IH - 1);
      const int iy = iy0 + ry;
#pragma unroll
      for (int p = 0; p < 4; ++p) {
        const int a = p >> 1, b = p & 1;
        const size_t base =
            (((size_t)n * OH + 2 * iy + a) * OH + 2 * rx + b) * 32;
        const float o0 = lrelu(acc[p][0][i] + bv0);
        const float o1 = lrelu(acc[p][1][i] + bv1);
        cS[0] += o0; cQ[0] += o0 * o0;
        cS[1] += o1; cQ[1] += o1 * o1;
        Yp[(base >> 1) + ln15] = (unsigned)f2bf(o0) | ((unsigned)f2bf(o1) << 16);
      }
    }

    if (s + 1 < NSTRIP) {
#pragma unroll
      for (int it = 0; it < ITER; ++it) {
        const int i = tid + it * 256;
        if (i < TI) {
          const int slot = i / (CIN / 8), kg = (i % (CIN / 8)) * 8;
          short8 o = {0, 0, 0, 0, 0, 0, 0, 0};
          if (vld[it]) {
            float v[8];
            if constexpr (INBF) {
#pragma unroll
              for (int u = 0; u < 8; ++u) v[u] = bf2f((ushort)rbf[it][u]);
            } else {
              v[0] = rva[it].x; v[1] = rva[it].y;
              v[2] = rva[it].z; v[3] = rva[it].w;
              v[4] = rvb[it].x; v[5] = rvb[it].y;
              v[6] = rvb[it].z; v[7] = rvb[it].w;
            }
            if (HASN) {
#pragma unroll
              for (int u = 0; u < 8; ++u)
                v[u] = fmaf(v[u], nrm0[kg + u], -nrm1[kg + u]);
            }
#pragma unroll
            for (int u = 0; u < 8; ++u) o[u] = (short)f2bf(v[u]);
          }
          *(short8*)&As[nxt][slot][kg] = o;
        }
      }
    }
    __syncthreads();
  }

#pragma unroll
  for (int f = 0; f < 2; ++f) {
    float s_ = cS[f], q_ = cQ[f];
    s_ += __shfl_down(s_, 32); s_ += __shfl_down(s_, 16);
    q_ += __shfl_down(q_, 32); q_ += __shfl_down(q_, 16);
    if (lane < 16) { redS[wv][f * 16 + ln15] = s_; redQ[wv][f * 16 + ln15] = q_; }
  }
  __syncthreads();
  if (tid < 32) {
    float S = redS[0][tid] + redS[1][tid] + redS[2][tid] + redS[3][tid];
    float Q = redQ[0][tid] + redQ[1][tid] + redQ[2][tid] + redQ[3][tid];
    const int ch = ((tid & 15) << 1) | (tid >> 4);
    atomicAdd(&stOut[ch], S);
    atomicAdd(&stOut[256 + ch], Q);
  }
}

// ======================= conv1 via MFMA im2col =============================
__global__ __launch_bounds__(256) void conv1_mfma(
    const float* __restrict__ x, const ushort* __restrict__ WT,
    const float* __restrict__ bias, ushort* __restrict__ y,
    float* __restrict__ st) {
  __shared__ float xin[3][17][67];
  __shared__ float redS[4][32], redQ[4][32];
  const int tid = threadIdx.x;
  const int wv = tid >> 6, lane = tid & 63;
  const int quad = lane >> 4, ln15 = lane & 15;
  const short8 bf0 = *(const short8*)&WT[(size_t)lane * 8];
  const short8 bf1 = *(const short8*)&WT[(size_t)(64 + lane) * 8];
  const int n = blockIdx.x >> 2;
  const int oy0 = (blockIdx.x & 3) * 8;
  const int iy0 = 2 * oy0 - 1;
  if (tid < 51) {
    const int ci = tid / 17, r = tid - ci * 17;
    xin[ci][r][0] = 0.f;
  }
  for (int i = tid; i < 816; i += 256) {
    const int ci = i / 272;
    const int r = (i - ci * 272) >> 4;
    const int c4 = (i & 15) << 2;
    const int iy = iy0 + r;
    float4 v = make_float4(0.f, 0.f, 0.f, 0.f);
    if ((unsigned)iy < 64u)
      v = *(const float4*)&x[((size_t)(n * 3 + ci) * 64 + iy) * 64 + c4];
    xin[ci][r][1 + c4] = v.x;
    xin[ci][r][2 + c4] = v.y;
    xin[ci][r][3 + c4] = v.z;
    xin[ci][r][4 + c4] = v.w;
  }
  __syncthreads();

  const float bv0 = bias[2 * ln15], bv1 = bias[2 * ln15 + 1];
  unsigned* Yp = (unsigned*)y;
  float cS[2] = {0.f, 0.f}, cQ[2] = {0.f, 0.f};
#pragma unroll
  for (int rr = 0; rr < 2; ++rr) {
    const int row = 2 * wv + rr;
#pragma unroll
    for (int h = 0; h < 2; ++h) {
      short8 a;
#pragma unroll
      for (int j = 0; j < 8; ++j) {
        const int k = quad * 8 + j;
        float val = 0.f;
        if (k < 27) {
          const int ci = k / 9, r2 = k - ci * 9;
          const int ky = r2 / 3, kx = r2 - ky * 3;
          val = xin[ci][2 * row + ky][2 * (h * 16 + ln15) + kx];
        }
        a[j] = (short)f2bf(val);
      }
      f32x4 acc0 = (f32x4){0.f, 0.f, 0.f, 0.f};
      f32x4 acc1 = (f32x4){0.f, 0.f, 0.f, 0.f};
      acc0 = __builtin_amdgcn_mfma_f32_16x16x32_bf16(a, bf0, acc0, 0, 0, 0);
      acc1 = __builtin_amdgcn_mfma_f32_16x16x32_bf16(a, bf1, acc1, 0, 0, 0);
#pragma unroll
      for (int r = 0; r < 4; ++r) {
        const int px = h * 16 + quad * 4 + r;
        const float o0 = lrelu(acc0[r] + bv0);
        const float o1 = lrelu(acc1[r] + bv1);
        cS[0] += o0; cQ[0] += o0 * o0;
        cS[1] += o1; cQ[1] += o1 * o1;
        Yp[((size_t)n * 1024 + (oy0 + row) * 32 + px) * 16 + ln15] =
            (unsigned)f2bf(o0) | ((unsigned)f2bf(o1) << 16);
      }
    }
  }
#pragma unroll
  for (int f = 0; f < 2; ++f) {
    float s_ = cS[f], q_ = cQ[f];
    s_ += __shfl_down(s_, 32); s_ += __shfl_down(s_, 16);
    q_ += __shfl_down(q_, 32); q_ += __shfl_down(q_, 16);
    if (lane < 16) { redS[wv][f * 16 + ln15] = s_; redQ[wv][f * 16 + ln15] = q_; }
  }
  __syncthreads();
  if (tid < 32) {
    float S = redS[0][tid] + redS[1][tid] + redS[2][tid] + redS[3][tid];
    float Q = redQ[0][tid] + redQ[1][tid] + redQ[2][tid] + redQ[3][tid];
    const int ch = ((tid & 15) << 1) | (tid >> 4);
    atomicAdd(&st[ch], S);
    atomicAdd(&st[256 + ch], Q);
  }
}

// ======================= final convT via MFMA + 4-row LDS ring =============
__global__ __launch_bounds__(256) void convt4_mfma(
    const float* __restrict__ X, const ushort* __restrict__ WT,
    const float* __restrict__ bias, const float* __restrict__ st, float invN,
    float* __restrict__ out) {
  __shared__ short ring[4][66][32];
  __shared__ float s0[32], s1[32];
  const int tid = threadIdx.x;
  const int wv = tid >> 6, lane = tid & 63;
  const int quad = lane >> 4, ln15 = lane & 15;
  if (tid < 32) {
    float m = st[tid] * invN;
    float var = st[256 + tid] * invN - m * m;
    float s = rsqrtf(var + EPS_BN);
    s0[tid] = s;
    s1[tid] = m * s;
  }
  if (tid >= 32 && tid < 64) {
    const int t = tid - 32;
    const int slot = t >> 3, h = (t >> 2) & 1, kg = (t & 3) * 8;
    short8 z = {0, 0, 0, 0, 0, 0, 0, 0};
    *(short8*)&ring[slot][h ? 65 : 0][kg] = z;
  }
  short8 bfrag[9];
#pragma unroll
  for (int s = 0; s < 9; ++s)
    bfrag[s] = *(const short8*)&WT[((size_t)s * 64 + lane) * 8];
  __syncthreads();

  const int n = blockIdx.x >> 2;
  const int y0 = (blockIdx.x & 3) * 16;
  const ushort* xn = (const ushort*)X + (size_t)n * 131072;
  const int spx = tid >> 2, skg = (tid & 3) * 8;

#pragma unroll
  for (int pr = 0; pr < 3; ++pr) {
    const int Y = y0 - 1 + pr;
    short8 o = {0, 0, 0, 0, 0, 0, 0, 0};
    if ((unsigned)Y < 64u) {
      const short8 raw = *(const short8*)&xn[((size_t)Y * 64 + spx) * 32 + skg];
#pragma unroll
      for (int u = 0; u < 8; ++u)
        o[u] = (short)f2bf(fmaf(bf2f((ushort)raw[u]), s0[skg + u], -s1[skg + u]));
    }
    *(short8*)&ring[Y & 3][spx + 1][skg] = o;
  }
  __syncthreads();

  const int x0 = wv * 16;
  const float bv = (ln15 < 3) ? bias[ln15] : 0.f;
  float* op = out + (size_t)n * 3 * 4096;

  for (int y = y0; y < y0 + 16; ++y) {
    const int Ypf = y + 2;
    const bool pre = (Ypf <= y0 + 16);
    short8 raw;
    bool vld = false;
    if (pre && (unsigned)Ypf < 64u) {
      raw = *(const short8*)&xn[((size_t)Ypf * 64 + spx) * 32 + skg];
      vld = true;
    }

    f32x4 acc0 = (f32x4){0.f, 0.f, 0.f, 0.f};
    f32x4 acc1 = (f32x4){0.f, 0.f, 0.f, 0.f};
#pragma unroll
    for (int ty = 0; ty < 3; ++ty) {
      const short* rp = &ring[(y - 1 + ty) & 3][0][0];
#pragma unroll
      for (int tx = 0; tx < 3; ++tx) {
        const short8 a = *(const short8*)&rp[(x0 + ln15 + tx) * 32 + quad * 8];
        const int s = ty * 3 + tx;
        if (s & 1)
          acc1 = __builtin_amdgcn_mfma_f32_16x16x32_bf16(a, bfrag[s], acc1, 0, 0, 0);
        else
          acc0 = __builtin_amdgcn_mfma_f32_16x16x32_bf16(a, bfrag[s], acc0, 0, 0, 0);
      }
    }

    if (ln15 < 3) {
      float4 o;
      float v;
      v = acc0[0] + acc1[0] + bv; o.x = 1.f / (1.f + __expf(-2.f * v));
      v = acc0[1] + acc1[1] + bv; o.y = 1.f / (1.f + __expf(-2.f * v));
      v = acc0[2] + acc1[2] + bv; o.z = 1.f / (1.f + __expf(-2.f * v));
      v = acc0[3] + acc1[3] + bv; o.w = 1.f / (1.f + __expf(-2.f * v));
      *(float4*)&op[(size_t)ln15 * 4096 + y * 64 + x0 + quad * 4] = o;
    }

    if (pre) {
      short8 o = {0, 0, 0, 0, 0, 0, 0, 0};
      if (vld) {
#pragma unroll
        for (int u = 0; u < 8; ++u)
          o[u] = (short)f2bf(
              fmaf(bf2f((ushort)raw[u]), s0[skg + u], -s1[skg + u]));
      }
      *(short8*)&ring[Ypf & 3][spx + 1][skg] = o;
    }
    __syncthreads();
  }
}

// ======================= dense GEMM (encoder FC), fp32 =====================
__global__ __launch_bounds__(256) void gemm_abt(
    const float* __restrict__ A, const float* __restrict__ B,
    const float* __restrict__ bias, const float* __restrict__ stA, float invN,
    float* __restrict__ C, float* __restrict__ P, int K, int ldc, int col0,
    float alpha, int act) {
  __shared__ float As[16][68];
  __shared__ float Bsh[16][68];
  __shared__ float nrm[2][256];
  const int tid = threadIdx.x;
  if (stA) {
    const int c = tid;
    float m = stA[c] * invN;
    float var = stA[256 + c] * invN - m * m;
    float s = rsqrtf(var + EPS_BN);
    nrm[0][c] = s;
    nrm[1][c] = m * s;
    __syncthreads();
  }
  const int lm = tid >> 2, lk = (tid & 3) << 2;
  const int KS = gridDim.z;
  const int kChunk = K / KS;
  const int kStart = blockIdx.z * kChunk;
  const float* Arow = A + (size_t)(blockIdx.y * 64 + lm) * K + lk;
  const float* Brow = B + (size_t)(blockIdx.x * 64 + lm) * K + lk;
  float acc[4][4] = {};
  const int m0 = (tid >> 4) << 2, n0 = (tid & 15) << 2;

  for (int k0 = kStart; k0 < kStart + kChunk; k0 += 16) {
    float4 av = *(const float4*)(Arow + k0);
    float4 bv = *(const float4*)(Brow + k0);
    if (stA) {
      const int ch = (k0 + lk) >> 4;
      const float s = nrm[0][ch], ms = nrm[1][ch];
      av.x = fmaf(av.x, s, -ms);
      av.y = fmaf(av.y, s, -ms);
      av.z = fmaf(av.z, s, -ms);
      av.w = fmaf(av.w, s, -ms);
    }
    As[lk + 0][lm] = av.x; As[lk + 1][lm] = av.y;
    As[lk + 2][lm] = av.z; As[lk + 3][lm] = av.w;
    Bsh[lk + 0][lm] = bv.x; Bsh[lk + 1][lm] = bv.y;
    Bsh[lk + 2][lm] = bv.z; Bsh[lk + 3][lm] = bv.w;
    __syncthreads();
#pragma unroll
    for (int kk = 0; kk < 16; ++kk) {
      const float4 a = *(const float4*)&As[kk][m0];
      const float4 b = *(const float4*)&Bsh[kk][n0];
      acc[0][0] = fmaf(a.x, b.x, acc[0][0]); acc[0][1] = fmaf(a.x, b.y, acc[0][1]);
      acc[0][2] = fmaf(a.x, b.z, acc[0][2]); acc[0][3] = fmaf(a.x, b.w, acc[0][3]);
      acc[1][0] = fmaf(a.y, b.x, acc[1][0]); acc[1][1] = fmaf(a.y, b.y, acc[1][1]);
      acc[1][2] = fmaf(a.y, b.z, acc[1][2]); acc[1][3] = fmaf(a.y, b.w, acc[1][3]);
      acc[2][0] = fmaf(a.z, b.x, acc[2][0]); acc[2][1] = fmaf(a.z, b.y, acc[2][1]);
      acc[2][2] = fmaf(a.z, b.z, acc[2][2]); acc[2][3] = fmaf(a.z, b.w, acc[2][3]);
      acc[3][0] = fmaf(a.w, b.x, acc[3][0]); acc[3][1] = fmaf(a.w, b.y, acc[3][1]);
      acc[3][2] = fmaf(a.w, b.z, acc[3][2]); acc[3][3] = fmaf(a.w, b.w, acc[3][3]);
    }
    __syncthreads();
  }

  const int gm = blockIdx.y * 64 + m0;
  const int gn = blockIdx.x * 64 + n0;
  if (KS == 1) {
#pragma unroll
    for (int i = 0; i < 4; ++i) {
      float4 o;
      o.x = alpha * acc[i][0] + bias[gn + 0];
      o.y = alpha * acc[i][1] + bias[gn + 1];
      o.z = alpha * acc[i][2] + bias[gn + 2];
      o.w = alpha * acc[i][3] + bias[gn + 3];
      if (act == 1) {
        o.x = fmaxf(o.x, 0.f); o.y = fmaxf(o.y, 0.f);
        o.z = fmaxf(o.z, 0.f); o.w = fmaxf(o.w, 0.f);
      }
      *(float4*)&C[(size_t)(gm + i) * ldc + col0 + gn] = o;
    }
  } else {
    const int M = gridDim.y * 64, N = gridDim.x * 64;
#pragma unroll
    for (int i = 0; i < 4; ++i)
      *(float4*)&P[((size_t)blockIdx.z * M + gm + i) * N + gn] =
          make_float4(acc[i][0], acc[i][1], acc[i][2], acc[i][3]);
  }
}

__global__ __launch_bounds__(256) void gemm_reduce(
    const float* __restrict__ P, float* __restrict__ C,
    const float* __restrict__ bias, int M, int N, int ldc, int col0,
    float alpha, int act, int KS) {
  const int idx = blockIdx.x * 256 + threadIdx.x;
  if (idx >= M * N) return;
  const int m = idx / N, n = idx % N;
  float s = 0.f;
  for (int z = 0; z < KS; ++z) s += P[((size_t)z * M + m) * N + n];
  float v = alpha * s + bias[n];
  if (act == 1) v = fmaxf(v, 0.f);
  C[(size_t)m * ldc + col0 + n] = v;
}

// ======================= VQ =================================================
__global__ __launch_bounds__(256) void argmin_d2(const float* __restrict__ d2,
                                                 int* __restrict__ idx) {
  const int b = blockIdx.x, t = threadIdx.x;
  const float* row = d2 + (size_t)b * 8192;
  float best = 3.4e38f;
  int bi = 0x7fffffff;
  for (int k = t; k < 8192; k += 256) {
    const float v = row[k];
    if (v < best) { best = v; bi = k; }
  }
  __shared__ float bval[256];
  __shared__ int bidx[256];
  bval[t] = best;
  bidx[t] = bi;
  __syncthreads();
  for (int s = 128; s > 0; s >>= 1) {
    if (t < s) {
      const float ov = bval[t + s];
      const int oi = bidx[t + s];
      if (ov < bval[t] || (ov == bval[t] && oi < bidx[t])) {
        bval[t] = ov;
        bidx[t] = oi;
      }
    }
    __syncthreads();
  }
  if (t == 0) idx[b] = bidx[0];
}

__global__ __launch_bounds__(256) void vq_gather_loss(
    const float* __restrict__ ze, const float* __restrict__ cb,
    const int* __restrict__ idx, float* __restrict__ zq,
    float* __restrict__ lossacc) {
  const int b = blockIdx.x, d = threadIdx.x;
  const int i = b * 256 + d;
  const float q = cb[(size_t)idx[b] * 256 + d];
  zq[i] = q;
  const float df = ze[i] - q;
  float v = df * df;
  __shared__ float sh[256];
  sh[d] = v;
  __syncthreads();
  for (int s = 128; s > 0; s >>= 1) {
    if (d < s) sh[d] += sh[d + s];
    __syncthreads();
  }
  if (d == 0) atomicAdd(lossacc, sh[0]);
}

__global__ void write_loss(const float* __restrict__ lossacc,
                           float* __restrict__ out) {
  out[0] = 2.f * lossacc[0];
}

// ---------------------------------------------------------------------------
extern "C" void kernel_launch(void* const* d_in, const int* in_sizes, int n_in,
                              void* d_out, int out_size, void* d_ws,
                              size_t ws_size, hipStream_t stream) {
  const float* x = (const float*)d_in[0];
  const float* ew1 = (const float*)d_in[1];
  const float* eb1 = (const float*)d_in[2];
  const float* ew2 = (const float*)d_in[3];
  const float* eb2 = (const float*)d_in[4];
  const float* ew3 = (const float*)d_in[5];
  const float* eb3 = (const float*)d_in[6];
  const float* ew4 = (const float*)d_in[7];
  const float* eb4 = (const float*)d_in[8];
  const float* wmu = (const float*)d_in[9];
  const float* bmu = (const float*)d_in[10];
  const float* wcov = (const float*)d_in[11];
  const float* bcov = (const float*)d_in[12];
  const float* cb = (const float*)d_in[13];
  const float* wfc = (const float*)d_in[14];
  const float* bfc = (const float*)d_in[15];
  const float* wt1 = (const float*)d_in[16];
  const float* bt1 = (const float*)d_in[17];
  const float* wt2 = (const float*)d_in[18];
  const float* bt2 = (const float*)d_in[19];
  const float* wt3 = (const float*)d_in[20];
  const float* bt3 = (const float*)d_in[21];
  const float* wt31 = (const float*)d_in[22];
  const float* bt31 = (const float*)d_in[23];
  const float* wt4 = (const float*)d_in[24];
  const float* bt4 = (const float*)d_in[25];

  float* ws = (float*)d_ws;
  float* a1 = ws;               // NHWC [256,32,32,32] bf16 (reused as g3, bf16)
  float* a2 = a1 + 8388608;     // NHWC [256,16,16,64] bf16 (reused as g2, bf16)
  float* a3 = a2 + 4194304;     // NHWC [256,8,8,128] bf16  (reused as g1, bf16)
  float* a4 = a3 + 2097152;     // [256,256,4,4] region     (reused as g0, fp32)
  float* g31 = a4 + 1048576;    // NHWC [256,64,64,32] bf16 (region 33554432 f)
  float* d2 = g31;              // [256,8192]
  float* P = g31 + 2097152;     // 262144
  float* csq = g31 + 2359296;   // 8192
  float* a4n = g31 + 2367488;   // NCHW a4 (written directly by conv4)
  float* wfcT = g31 + 3416064;  // 1048576
  float* bfcT = g31 + 4464640;  // 4096
  ushort* wTc2 = (ushort*)(g31 + 4468736);  // 18432 bf16
  ushort* wTc3 = (ushort*)(g31 + 4487168);  // 73728 bf16
  ushort* wTc4 = (ushort*)(g31 + 4560896);  // 294912 bf16
  float* ze = g31 + 33554432;   // [256,256]
  float* zq = ze + 65536;
  float* stats = zq + 65536;    // 8 layers x 512
  float* lossacc = stats + 4096;
  int* idx = (int*)(lossacc + 4);
  ushort* wTt1 = (ushort*)(lossacc + 4 + 256);  // 294912 bf16 (parity,perm)
  ushort* wTt2 = wTt1 + 294912;                 // 73728 bf16 (parity,perm)
  ushort* wTt3 = wTt2 + 73728;                  // 18432 bf16 (tap-major,perm)
  ushort* wTt31 = wTt3 + 18432;                 // 9216 bf16 (tap-major,perm)
  ushort* wT4 = wTt31 + 9216;                   // 4608 bf16 (convt4 B frags)
  ushort* wb1 = wT4 + 4608;                     // 1024 bf16 (conv1 B frags)
  float* g3 = a1;   // bf16 content
  float* g2 = a2;   // bf16 content
  float* g1 = a3;   // bf16 content
  float* g0 = a4;   // fp32

  float* st0 = stats + 0 * 512;
  float* st1 = stats + 1 * 512;
  float* st2 = stats + 2 * 512;
  float* st3 = stats + 3 * 512;
  float* st4 = stats + 4 * 512;
  float* st5 = stats + 5 * 512;
  float* st6 = stats + 6 * 512;
  float* st7 = stats + 7 * 512;

  hipMemsetAsync(stats, 0, (4096 + 8) * sizeof(float), stream);

  // ---- fused weight prep (11 kernels -> 1) ----
  fused_pre<<<9226, 256, 0, stream>>>(ew2, wTc2, ew3, wTc3, ew4, wTc4, wt1,
                                      wTt1, wt2, wTt2, wt3, wTt3, wt31, wTt31,
                                      wt4, wT4, ew1, wb1, wfc, bfc, wfcT, bfcT,
                                      cb, csq);

  // ---- encoder ----
  conv1_mfma<<<1024, 256, 0, stream>>>(x, wb1, eb1, (ushort*)a1, st0);
  mfmaconv<64, 0, 32, 32, 64, true, true, true, false>
      <<<dim3(1, 1024), 256, 0, stream>>>(a1, wTc2, eb2, st0,
                                          1.f / (256.f * 1024.f), a2, st1);
  mfmaconv<64, 0, 16, 64, 128, true, true, true, false>
      <<<dim3(2, 256), 256, 0, stream>>>(a2, wTc3, eb3, st1,
                                         1.f / (256.f * 256.f), a3, st2);
  mfmaconv<64, 0, 8, 128, 256, true, true, false, true>
      <<<dim3(4, 64), 256, 0, stream>>>(a3, wTc4, eb4, st2,
                                        1.f / (256.f * 64.f), a4n, st3);

  // ---- encoder FC (fp32, split-K) ----
  gemm_abt<<<dim3(2, 4, 8), 256, 0, stream>>>(a4n, wmu, nullptr, st3,
                                              1.f / 4096.f, nullptr, P, 4096,
                                              0, 0, 1.f, 0);
  gemm_reduce<<<128, 256, 0, stream>>>(P, ze, bmu, 256, 128, 256, 0, 1.f, 0, 8);
  gemm_abt<<<dim3(2, 4, 8), 256, 0, stream>>>(a4n, wcov, nullptr, st3,
                                              1.f / 4096.f, nullptr, P, 4096,
                                              0, 0, 1.f, 0);
  gemm_reduce<<<128, 256, 0, stream>>>(P, ze, bcov, 256, 128, 256, 128, 1.f, 1, 8);

  // ---- VQ: d2 = csq[n] - 2*ze.cb (|ze|^2 dropped, argmin-invariant) ----
  gemm_bf_abt<<<dim3(128, 4), 256, 0, stream>>>(ze, cb, csq, d2, 256, 8192,
                                                -2.f);
  argmin_d2<<<256, 256, 0, stream>>>(d2, idx);
  vq_gather_loss<<<256, 256, 0, stream>>>(ze, cb, idx, zq, lossacc);

  // ---- decoder FC (bf16 MFMA) ----
  gemm_bf_abt<<<dim3(64, 4), 256, 0, stream>>>(zq, wfcT, bfcT, g0, 256, 4096,
                                               1.f);

  // ---- decoder ----
  mfmaconv<64, 1, 4, 256, 128, false, false, true, false>
      <<<dim3(2, 64, 4), 256, 0, stream>>>(g0, wTt1, bt1, nullptr, 0.f, g1,
                                           st4);
  mfmaconv<64, 1, 8, 128, 64, true, true, true, false>
      <<<dim3(1, 256, 4), 256, 0, stream>>>(g1, wTt2, bt2, st4,
                                            1.f / (256.f * 64.f), g2, st5);
  convt_mfma<16, 64, true, true, 2><<<512, 256, 0, stream>>>(
      g2, wTt3, bt3, st5, 1.f / (256.f * 256.f), g3, st6);
  convt_mfma<32, 32, true, true, 4><<<1024, 256, 0, stream>>>(
      g3, wTt31, bt31, st6, 1.f / (256.f * 1024.f), g31, st7);

  convt4_mfma<<<1024, 256, 0, stream>>>(g31, wT4, bt4, st7,
                                        1.f / (256.f * 4096.f), (float*)d_out);
  write_loss<<<1, 1, 0, stream>>>(lossacc, (float*)d_out + 3145728);
}

// Round 13
// 430.940 us; speedup vs baseline: 1.5352x; 1.0940x over previous
//
#include <hip/hip_runtime.h>
#include <cmath>

// ---------------------------------------------------------------------------
// VQ-VAE forward. B=256, C=3, HW=64, D=256, K=8192, LAT=128
// R19: (a) encoder FC mu+cov fused into ONE split-K gemm (gemm_enc, B-ptr
// selected per block column; 4 launches -> 2; P widened, moved to dead
// region g31+8388608); (b) argmin+gather+loss fused (vq_argmin_gather, idx
// buffer dropped). Rest identical to R18 (471.4us): fused_pre, OUTNCHW
// conv4, OUTBF a2/a3/g1/g2, gemm_bf_abt, R14 pipelined k-loop, conv1_mfma,
// convt4 ring, multi-strip convt (NSTRIP 2/4), packed-bf16 tail.
// ---------------------------------------------------------------------------

#define EPS_BN 1e-5f
typedef unsigned short ushort;
typedef short short8 __attribute__((ext_vector_type(8)));
typedef ushort us4 __attribute__((ext_vector_type(4)));
typedef float f32x4 __attribute__((ext_vector_type(4)));

__device__ __forceinline__ float lrelu(float v) { return v >= 0.f ? v : 0.01f * v; }
__device__ __forceinline__ ushort f2bf(float f) {
  unsigned u = __float_as_uint(f);
  return (ushort)((u + 0x7FFF + ((u >> 16) & 1)) >> 16);
}
__device__ __forceinline__ float bf2f(ushort u) {
  return __uint_as_float(((unsigned)u) << 16);
}

// ======================= fused weight-prep megakernel ======================
__device__ __forceinline__ void d_convw(const float* __restrict__ w,
                                        ushort* __restrict__ wT, int CIN,
                                        int COUT, int total, int perm, int vb,
                                        int tid) {
  int i = vb * 256 + tid;
  if (i >= total) return;
  int co = i / (9 * CIN);
  int r = i - co * 9 * CIN;
  int t = r / CIN, ci = r - t * CIN;
  int co_s = co;
  if (perm) {
    const int cr = co & 63;
    co_s = (co - cr) + ((cr & 3) << 4) + (cr >> 2);
  }
  wT[(size_t)co_s * 9 * CIN + r] = f2bf(w[((size_t)co * CIN + ci) * 9 + t]);
}

__device__ __forceinline__ void d_convtw(const float* __restrict__ w,
                                         ushort* __restrict__ wT, int CIN,
                                         int COUT, int total, int vb, int tid) {
  int i = vb * 256 + tid;
  if (i >= total) return;
  const int cc = CIN * COUT;
  int p, base, Kp;
  if (i < cc) { p = 0; base = 0; Kp = CIN; }
  else if (i < 3 * cc) { p = 1; base = cc; Kp = 2 * CIN; }
  else if (i < 5 * cc) { p = 2; base = 3 * cc; Kp = 2 * CIN; }
  else { p = 3; base = 5 * cc; Kp = 4 * CIN; }
  const int r = i - base;
  const int co = r / Kp;
  const int q = r - co * Kp;
  const int tix = q / CIN, ci = q - (q / CIN) * CIN;
  const int py = p >> 1, px = p & 1;
  const int nx = px ? 2 : 1;
  const int kyi = tix / nx, kxi = tix - kyi * nx;
  const int ky = py ? (kyi == 0 ? 0 : 2) : 1;
  const int kx = px ? (kxi == 0 ? 0 : 2) : 1;
  const int cr = co & 63;
  const int co_s = (co - cr) + ((cr & 3) << 4) + (cr >> 2);
  wT[base + (size_t)co_s * Kp + q] =
      f2bf(w[((size_t)ci * COUT + co) * 9 + ky * 3 + kx]);
}

__device__ __forceinline__ void d_convtw_tc(const float* __restrict__ w,
                                            ushort* __restrict__ wT, int CIN,
                                            int COUT, int total, int vb,
                                            int tid) {
  int i = vb * 256 + tid;
  if (i >= total) return;
  int ci = i % CIN;
  int tmp = i / CIN;
  int co = tmp % COUT;
  int t = tmp / COUT;
  const int co_slot = ((co & 1) << 4) | (co >> 1);
  wT[((size_t)t * COUT + co_slot) * CIN + ci] =
      f2bf(w[((size_t)ci * COUT + co) * 9 + t]);
}

__device__ __forceinline__ void d_w4(const float* __restrict__ w,
                                     ushort* __restrict__ wT, int vb, int tid) {
  int i = vb * 256 + tid;
  if (i >= 4608) return;
  const int s = i >> 9;
  const int l = (i >> 3) & 63;
  const int j = i & 7;
  const int nn = l & 15;
  const int ci = ((l >> 4) << 3) + j;
  const int ty = s / 3, tx = s - ty * 3;
  ushort v = 0;
  if (nn < 3)
    v = f2bf(w[((size_t)ci * 3 + nn) * 9 + (2 - ty) * 3 + (2 - tx)]);
  wT[i] = v;
}

__device__ __forceinline__ void d_w1b(const float* __restrict__ w,
                                      ushort* __restrict__ wT, int vb,
                                      int tid) {
  int i = vb * 256 + tid;
  if (i >= 1024) return;
  const int j = i & 7, l = (i >> 3) & 63, f = i >> 9;
  const int c = 2 * (l & 15) + f;
  const int k = ((l >> 4) << 3) + j;
  ushort v = 0;
  if (k < 27) {
    const int ci = k / 9, r = k - ci * 9;
    v = f2bf(w[((size_t)c * 3 + ci) * 9 + r]);
  }
  wT[i] = v;
}

__device__ __forceinline__ void d_fcdec(const float* __restrict__ in,
                                        const float* __restrict__ bin,
                                        float* __restrict__ out,
                                        float* __restrict__ bout, int vb,
                                        int tid) {
  int i = vb * 256 + tid;
  int k = i >> 8, d = i & 255;
  int kp = (k & 15) * 256 + (k >> 4);
  out[(size_t)kp * 256 + d] = in[i];
  if (d == 0) bout[kp] = bin[k];
}

__device__ __forceinline__ void d_rowsq(const float* __restrict__ cb,
                                        float* __restrict__ csq, int vb,
                                        int tid) {
  const int row = vb * 4 + (tid >> 6);
  const int ln = tid & 63;
  const float4 v = ((const float4*)(cb + (size_t)row * 256))[ln];
  float s = v.x * v.x + v.y * v.y + v.z * v.z + v.w * v.w;
#pragma unroll
  for (int off = 32; off > 0; off >>= 1) s += __shfl_down(s, off);
  if (ln == 0) csq[row] = s;
}

// block ranges: 72|288|1152|1152|288|72|36|18|4|4096|2048|1 = 9227
__global__ __launch_bounds__(256) void fused_pre(
    const float* __restrict__ ew2, ushort* __restrict__ wTc2,
    const float* __restrict__ ew3, ushort* __restrict__ wTc3,
    const float* __restrict__ ew4, ushort* __restrict__ wTc4,
    const float* __restrict__ wt1, ushort* __restrict__ wTt1,
    const float* __restrict__ wt2, ushort* __restrict__ wTt2,
    const float* __restrict__ wt3, ushort* __restrict__ wTt3,
    const float* __restrict__ wt31, ushort* __restrict__ wTt31,
    const float* __restrict__ wt4, ushort* __restrict__ wT4,
    const float* __restrict__ ew1, ushort* __restrict__ wb1,
    const float* __restrict__ wfc, const float* __restrict__ bfc,
    float* __restrict__ wfcT, float* __restrict__ bfcT,
    const float* __restrict__ cb, float* __restrict__ csq,
    const float* __restrict__ bmu, const float* __restrict__ bcov,
    float* __restrict__ bcat) {
  const int tid = threadIdx.x;
  int b = blockIdx.x;
  if (b < 72) { d_convw(ew2, wTc2, 32, 64, 18432, 1, b, tid); return; }
  b -= 72;
  if (b < 288) { d_convw(ew3, wTc3, 64, 128, 73728, 1, b, tid); return; }
  b -= 288;
  if (b < 1152) { d_convw(ew4, wTc4, 128, 256, 294912, 0, b, tid); return; }
  b -= 1152;
  if (b < 1152) { d_convtw(wt1, wTt1, 256, 128, 294912, b, tid); return; }
  b -= 1152;
  if (b < 288) { d_convtw(wt2, wTt2, 128, 64, 73728, b, tid); return; }
  b -= 288;
  if (b < 72) { d_convtw_tc(wt3, wTt3, 64, 32, 18432, b, tid); return; }
  b -= 72;
  if (b < 36) { d_convtw_tc(wt31, wTt31, 32, 32, 9216, b, tid); return; }
  b -= 36;
  if (b < 18) { d_w4(wt4, wT4, b, tid); return; }
  b -= 18;
  if (b < 4) { d_w1b(ew1, wb1, b, tid); return; }
  b -= 4;
  if (b < 4096) { d_fcdec(wfc, bfc, wfcT, bfcT, b, tid); return; }
  b -= 4096;
  if (b < 2048) { d_rowsq(cb, csq, b, tid); return; }
  // bcat concat (1 block)
  bcat[tid] = (tid < 128) ? bmu[tid] : bcov[tid - 128];
}

// ======================= bf16 MFMA implicit-GEMM conv / convT ==============
// R14 pipeline. OUTBF: packed-bf16 output, slot f*16+l = channel 4l+f.
// OUTNCHW (MODE 0 only): scalar fp32 stores directly in NCHW [n][c][px].
template <int TN, int MODE, int IH, int CIN, int COUT, bool HASN, bool INBF,
          bool OUTBF, bool OUTNCHW>
__global__ __launch_bounds__(256) void mfmaconv(
    const float* __restrict__ X, const ushort* __restrict__ WT,
    const float* __restrict__ bias, const float* __restrict__ st, float invN,
    float* __restrict__ Y, float* __restrict__ stOut) {
  constexpr int OH = (MODE == 0) ? IH / 2 : 2 * IH;
  constexpr int NF = TN / 16;
  static_assert(!OUTBF || NF == 4, "OUTBF requires NF==4");
  __shared__ short As[2][64][40];
  __shared__ short Bs[2][TN][40];
  __shared__ float nrm0[HASN ? CIN : 4], nrm1[HASN ? CIN : 4];
  __shared__ float redS[4][TN], redQ[4][TN];
  const int tid = threadIdx.x;
  const int wv = tid >> 6, lane = tid & 63;
  const int quad = lane >> 4, ln15 = tid & 15;
  if (HASN) {
    for (int c = tid; c < CIN; c += 256) {
      float m = st[c] * invN;
      float var = st[256 + c] * invN - m * m;
      float s = rsqrtf(var + EPS_BN);
      nrm0[c] = s;
      nrm1[c] = m * s;
    }
    __syncthreads();
  }
  int py = 0, px = 0, nx = 1, K = 9 * CIN;
  const ushort* W = WT;
  if (MODE == 1) {
    const int pz = blockIdx.z;
    py = pz >> 1;
    px = pz & 1;
    nx = px ? 2 : 1;
    const int ny = py ? 2 : 1;
    K = ny * nx * CIN;
    const int pre[4] = {0, 1, 3, 5};
    W = WT + (size_t)pre[pz] * CIN * COUT;
  }
  const int gyTM = blockIdx.y * 64;
  const int gxTN = blockIdx.x * TN;

  const int sm = tid & 63, skg = (tid >> 6) * 8;
  const int bn = tid >> 2, bkg = (tid & 3) * 8;
  int baseNB, baseIY, baseIX;
  {
    const int gm = gyTM + sm;
    if (MODE == 0) {
      const int ni = gm / (OH * OH), r = gm % (OH * OH);
      baseNB = ni * IH * IH;
      baseIY = 2 * (r / OH) - 1;
      baseIX = 2 * (r % OH) - 1;
    } else {
      const int ni = gm / (IH * IH), r = gm % (IH * IH);
      baseNB = ni * IH * IH;
      baseIY = r / IH;
      baseIX = r % IH;
    }
  }
  f32x4 acc[NF];
#pragma unroll
  for (int f = 0; f < NF; ++f) acc[f] = (f32x4){0.f, 0.f, 0.f, 0.f};

  const int nsteps = K / 32;

  // ---- prologue: stage step 0 into buf 0 ----
  {
    int iy, ix;
    if (MODE == 0) {
      iy = baseIY;
      ix = baseIX;
    } else {
      iy = baseIY + (py ? 1 : 0);
      ix = baseIX + (px ? 1 : 0);
    }
    const bool ok =
        ((unsigned)iy < (unsigned)IH) && ((unsigned)ix < (unsigned)IH);
    float v[8] = {0.f, 0.f, 0.f, 0.f, 0.f, 0.f, 0.f, 0.f};
    if (ok) {
      if constexpr (INBF) {
        const ushort* xp =
            (const ushort*)X + ((size_t)baseNB + iy * IH + ix) * CIN + skg;
        const short8 raw = *(const short8*)xp;
#pragma unroll
        for (int u = 0; u < 8; ++u) v[u] = bf2f((ushort)raw[u]);
      } else {
        const float* xp = &X[((size_t)baseNB + iy * IH + ix) * CIN + skg];
        const float4 va = *(const float4*)xp, vb = *(const float4*)(xp + 4);
        v[0] = va.x; v[1] = va.y; v[2] = va.z; v[3] = va.w;
        v[4] = vb.x; v[5] = vb.y; v[6] = vb.z; v[7] = vb.w;
      }
      if (HASN) {
#pragma unroll
        for (int u = 0; u < 8; ++u)
          v[u] = fmaf(v[u], nrm0[skg + u], -nrm1[skg + u]);
      }
    }
    short8 o;
#pragma unroll
    for (int u = 0; u < 8; ++u) o[u] = (short)f2bf(v[u]);
    *(short8*)&As[0][sm][skg] = o;
    if (tid < TN * 4)
      *(short8*)&Bs[0][bn][bkg] =
          *(const short8*)&W[(size_t)(gxTN + bn) * K + bkg];
  }
  __syncthreads();

  for (int kk = 0; kk < nsteps; ++kk) {
    const int cur = kk & 1, nxt = cur ^ 1;

    bool okN = false;
    int ci0N = 0;
    short8 rawN;
    float4 vaN, vbN;
    short8 rawBN;
    const bool hasNext = (kk + 1 < nsteps);
    if (hasNext) {
      const int k0n = (kk + 1) * 32;
      const int t = k0n / CIN;
      ci0N = k0n - t * CIN;
      int iy, ix;
      if (MODE == 0) {
        iy = baseIY + t / 3;
        ix = baseIX + (t - (t / 3) * 3);
      } else {
        const int kyi = t / nx, kxi = t - (t / nx) * nx;
        iy = baseIY + ((py && kyi == 0) ? 1 : 0);
        ix = baseIX + ((px && kxi == 0) ? 1 : 0);
      }
      okN = ((unsigned)iy < (unsigned)IH) && ((unsigned)ix < (unsigned)IH);
      if (okN) {
        if constexpr (INBF) {
          const ushort* xp = (const ushort*)X +
                             ((size_t)baseNB + iy * IH + ix) * CIN + ci0N + skg;
          rawN = *(const short8*)xp;
        } else {
          const float* xp =
              &X[((size_t)baseNB + iy * IH + ix) * CIN + ci0N + skg];
          vaN = *(const float4*)xp;
          vbN = *(const float4*)(xp + 4);
        }
      }
      if (tid < TN * 4)
        rawBN = *(const short8*)&W[(size_t)(gxTN + bn) * K + k0n + bkg];
    }

    const short8 a = *(const short8*)&As[cur][wv * 16 + ln15][quad * 8];
#pragma unroll
    for (int f = 0; f < NF; ++f) {
      const short8 b = *(const short8*)&Bs[cur][f * 16 + ln15][quad * 8];
      acc[f] = __builtin_amdgcn_mfma_f32_16x16x32_bf16(a, b, acc[f], 0, 0, 0);
    }

    if (hasNext) {
      float v[8] = {0.f, 0.f, 0.f, 0.f, 0.f, 0.f, 0.f, 0.f};
      if (okN) {
        if constexpr (INBF) {
#pragma unroll
          for (int u = 0; u < 8; ++u) v[u] = bf2f((ushort)rawN[u]);
        } else {
          v[0] = vaN.x; v[1] = vaN.y; v[2] = vaN.z; v[3] = vaN.w;
          v[4] = vbN.x; v[5] = vbN.y; v[6] = vbN.z; v[7] = vbN.w;
        }
        if (HASN) {
          const int c = ci0N + skg;
#pragma unroll
          for (int u = 0; u < 8; ++u)
            v[u] = fmaf(v[u], nrm0[c + u], -nrm1[c + u]);
        }
      }
      short8 o;
#pragma unroll
      for (int u = 0; u < 8; ++u) o[u] = (short)f2bf(v[u]);
      *(short8*)&As[nxt][sm][skg] = o;
      if (tid < TN * 4) *(short8*)&Bs[nxt][bn][bkg] = rawBN;
    }
    __syncthreads();
  }

  size_t maddr[4];
#pragma unroll
  for (int r = 0; r < 4; ++r) {
    const int m = gyTM + wv * 16 + quad * 4 + r;
    if (MODE == 0) {
      const int ni = m / (OH * OH), rr = m % (OH * OH);
      if constexpr (OUTNCHW)
        maddr[r] = (size_t)ni * COUT * (OH * OH) + rr;
      else
        maddr[r] = (((size_t)ni * OH + rr / OH) * OH + rr % OH) * COUT;
    } else {
      const int ni = m / (IH * IH), rr = m % (IH * IH);
      const int oy = 2 * (rr / IH) + py, ox = 2 * (rr % IH) + px;
      maddr[r] = (((size_t)ni * OH + oy) * OH + ox) * COUT;
    }
  }
  if constexpr (OUTBF) {
    const int ch0 = gxTN + 4 * ln15;
    const float b0 = bias[ch0 + 0], b1 = bias[ch0 + 1];
    const float b2 = bias[ch0 + 2], b3 = bias[ch0 + 3];
    ushort* Yb = (ushort*)Y;
    float cS[4] = {0.f, 0.f, 0.f, 0.f}, cQ[4] = {0.f, 0.f, 0.f, 0.f};
#pragma unroll
    for (int r = 0; r < 4; ++r) {
      const float o0 = lrelu(acc[0][r] + b0);
      const float o1 = lrelu(acc[1][r] + b1);
      const float o2 = lrelu(acc[2][r] + b2);
      const float o3 = lrelu(acc[3][r] + b3);
      cS[0] += o0; cQ[0] += o0 * o0;
      cS[1] += o1; cQ[1] += o1 * o1;
      cS[2] += o2; cQ[2] += o2 * o2;
      cS[3] += o3; cQ[3] += o3 * o3;
      uint2 pk;
      pk.x = (unsigned)f2bf(o0) | ((unsigned)f2bf(o1) << 16);
      pk.y = (unsigned)f2bf(o2) | ((unsigned)f2bf(o3) << 16);
      *(uint2*)&Yb[maddr[r] + ch0] = pk;
    }
#pragma unroll
    for (int f = 0; f < 4; ++f) {
      float s_ = cS[f], q_ = cQ[f];
      s_ += __shfl_down(s_, 32); s_ += __shfl_down(s_, 16);
      q_ += __shfl_down(q_, 32); q_ += __shfl_down(q_, 16);
      if (lane < 16) { redS[wv][f * 16 + ln15] = s_; redQ[wv][f * 16 + ln15] = q_; }
    }
    __syncthreads();
    if (tid < TN) {
      float S = redS[0][tid] + redS[1][tid] + redS[2][tid] + redS[3][tid];
      float Q = redQ[0][tid] + redQ[1][tid] + redQ[2][tid] + redQ[3][tid];
      const int ch = gxTN + 4 * (tid & 15) + (tid >> 4);
      atomicAdd(&stOut[ch], S);
      atomicAdd(&stOut[256 + ch], Q);
    }
  } else {
#pragma unroll
    for (int f = 0; f < NF; ++f) {
      const int col = gxTN + f * 16 + ln15;
      const float bv = bias[col];
      float cS = 0.f, cQ = 0.f;
#pragma unroll
      for (int r = 0; r < 4; ++r) {
        const float o = lrelu(acc[f][r] + bv);
        cS += o;
        cQ += o * o;
        if constexpr (OUTNCHW)
          Y[maddr[r] + (size_t)col * (OH * OH)] = o;
        else
          Y[maddr[r] + col] = o;
      }
      cS += __shfl_down(cS, 32); cS += __shfl_down(cS, 16);
      cQ += __shfl_down(cQ, 32); cQ += __shfl_down(cQ, 16);
      if (lane < 16) { redS[wv][f * 16 + ln15] = cS; redQ[wv][f * 16 + ln15] = cQ; }
    }
    __syncthreads();
    if (tid < TN) {
      float S = redS[0][tid] + redS[1][tid] + redS[2][tid] + redS[3][tid];
      float Q = redQ[0][tid] + redQ[1][tid] + redQ[2][tid] + redQ[3][tid];
      atomicAdd(&stOut[gxTN + tid], S);
      atomicAdd(&stOut[256 + gxTN + tid], Q);
    }
  }
}

// ======================= bf16 MFMA dense GEMM: C = alpha*(A.B^T) + bias ====
__global__ __launch_bounds__(256) void gemm_bf_abt(
    const float* __restrict__ A, const float* __restrict__ B,
    const float* __restrict__ bias, float* __restrict__ C, int K, int N,
    float alpha) {
  __shared__ short As[2][64][40];
  __shared__ short Bs[2][64][40];
  const int tid = threadIdx.x;
  const int wv = tid >> 6, lane = tid & 63;
  const int quad = lane >> 4, ln15 = lane & 15;
  const int gm0 = blockIdx.y * 64, gn0 = blockIdx.x * 64;
  const int sm = tid & 63, skg = (tid >> 6) * 8;
  const int bn = tid >> 2, bkg = (tid & 3) * 8;
  const float* Ap = A + (size_t)(gm0 + sm) * K + skg;
  const float* Bp = B + (size_t)(gn0 + bn) * K + bkg;
  f32x4 acc[4];
#pragma unroll
  for (int f = 0; f < 4; ++f) acc[f] = (f32x4){0.f, 0.f, 0.f, 0.f};
  const int nsteps = K / 32;

  {
    const float4 va = *(const float4*)Ap, vb = *(const float4*)(Ap + 4);
    short8 o;
    o[0] = (short)f2bf(va.x); o[1] = (short)f2bf(va.y);
    o[2] = (short)f2bf(va.z); o[3] = (short)f2bf(va.w);
    o[4] = (short)f2bf(vb.x); o[5] = (short)f2bf(vb.y);
    o[6] = (short)f2bf(vb.z); o[7] = (short)f2bf(vb.w);
    *(short8*)&As[0][sm][skg] = o;
    const float4 wa = *(const float4*)Bp, wb = *(const float4*)(Bp + 4);
    short8 p;
    p[0] = (short)f2bf(wa.x); p[1] = (short)f2bf(wa.y);
    p[2] = (short)f2bf(wa.z); p[3] = (short)f2bf(wa.w);
    p[4] = (short)f2bf(wb.x); p[5] = (short)f2bf(wb.y);
    p[6] = (short)f2bf(wb.z); p[7] = (short)f2bf(wb.w);
    *(short8*)&Bs[0][bn][bkg] = p;
  }
  __syncthreads();

  for (int kk = 0; kk < nsteps; ++kk) {
    const int cur = kk & 1, nxt = cur ^ 1;
    const bool hasNext = (kk + 1 < nsteps);
    float4 vaN, vbN, waN, wbN;
    if (hasNext) {
      const int k0n = (kk + 1) * 32;
      vaN = *(const float4*)(Ap + k0n);
      vbN = *(const float4*)(Ap + k0n + 4);
      waN = *(const float4*)(Bp + k0n);
      wbN = *(const float4*)(Bp + k0n + 4);
    }

    const short8 a = *(const short8*)&As[cur][wv * 16 + ln15][quad * 8];
#pragma unroll
    for (int f = 0; f < 4; ++f) {
      const short8 b = *(const short8*)&Bs[cur][f * 16 + ln15][quad * 8];
      acc[f] = __builtin_amdgcn_mfma_f32_16x16x32_bf16(a, b, acc[f], 0, 0, 0);
    }

    if (hasNext) {
      short8 o;
      o[0] = (short)f2bf(vaN.x); o[1] = (short)f2bf(vaN.y);
      o[2] = (short)f2bf(vaN.z); o[3] = (short)f2bf(vaN.w);
      o[4] = (short)f2bf(vbN.x); o[5] = (short)f2bf(vbN.y);
      o[6] = (short)f2bf(vbN.z); o[7] = (short)f2bf(vbN.w);
      *(short8*)&As[nxt][sm][skg] = o;
      short8 p;
      p[0] = (short)f2bf(waN.x); p[1] = (short)f2bf(waN.y);
      p[2] = (short)f2bf(waN.z); p[3] = (short)f2bf(waN.w);
      p[4] = (short)f2bf(wbN.x); p[5] = (short)f2bf(wbN.y);
      p[6] = (short)f2bf(wbN.z); p[7] = (short)f2bf(wbN.w);
      *(short8*)&Bs[nxt][bn][bkg] = p;
    }
    __syncthreads();
  }

#pragma unroll
  for (int f = 0; f < 4; ++f) {
    const int col = gn0 + f * 16 + ln15;
    const float bv = bias[col];
#pragma unroll
    for (int r = 0; r < 4; ++r) {
      const int row = gm0 + wv * 16 + quad * 4 + r;
      C[(size_t)row * N + col] = fmaf(alpha, acc[f][r], bv);
    }
  }
}

// ======================= halo-tile merged convT (COUT=32, CIN<=64) =========
template <int IH, int CIN, bool HASN, bool INBF, int NSTRIP>
__global__ __launch_bounds__(256) void convt_mfma(
    const float* __restrict__ X, const ushort* __restrict__ WT,
    const float* __restrict__ bias, const float* __restrict__ st, float invN,
    float* __restrict__ Y, float* __restrict__ stOut) {
  constexpr int OH = 2 * IH;
  constexpr int L = (IH == 32) ? 5 : 4;
  constexpr int RSPAN = 64 / IH;
  constexpr int NP = (RSPAN + 1) * (IH + 1);
  constexpr int LK = CIN + 8;
  constexpr int TI = NP * (CIN / 8);
  constexpr int ITER = (TI + 255) / 256;
  __shared__ short As[2][NP][LK];
  __shared__ short Ws[9 * 32][LK];
  __shared__ float nrm0[HASN ? CIN : 4], nrm1[HASN ? CIN : 4];
  __shared__ float redS[4][32], redQ[4][32];
  const int tid = threadIdx.x;
  const int wv = tid >> 6, lane = tid & 63;
  const int quad = lane >> 4, ln15 = lane & 15;
  if (HASN) {
    for (int c = tid; c < CIN; c += 256) {
      float m = st[c] * invN;
      float var = st[256 + c] * invN - m * m;
      float s = rsqrtf(var + EPS_BN);
      nrm0[c] = s;
      nrm1[c] = m * s;
    }
  }
  for (int i = tid; i < 9 * 32 * (CIN / 8); i += 256) {
    const int row = i / (CIN / 8), kg = (i % (CIN / 8)) * 8;
    *(short8*)&Ws[row][kg] = *(const short8*)&WT[(size_t)row * CIN + kg];
  }
  __syncthreads();

  const int strip0 = blockIdx.x * NSTRIP;
  const int n = (strip0 * 64) / (IH * IH);
  const int iy0base = (strip0 * 64 - n * (IH * IH)) >> L;

#pragma unroll
  for (int it = 0; it < ITER; ++it) {
    const int i = tid + it * 256;
    if (i < TI) {
      const int slot = i / (CIN / 8), kg = (i % (CIN / 8)) * 8;
      const int ty = slot / (IH + 1), tx = slot - ty * (IH + 1);
      const int iy = iy0base + ty;
      short8 o = {0, 0, 0, 0, 0, 0, 0, 0};
      if (iy < IH && tx < IH) {
        float v[8];
        if constexpr (INBF) {
          const ushort* xp =
              (const ushort*)X + (((size_t)n * IH + iy) * IH + tx) * CIN + kg;
          const short8 raw = *(const short8*)xp;
#pragma unroll
          for (int u = 0; u < 8; ++u) v[u] = bf2f((ushort)raw[u]);
        } else {
          const float* xp = &X[(((size_t)n * IH + iy) * IH + tx) * CIN + kg];
          const float4 va = *(const float4*)xp, vb = *(const float4*)(xp + 4);
          v[0] = va.x; v[1] = va.y; v[2] = va.z; v[3] = va.w;
          v[4] = vb.x; v[5] = vb.y; v[6] = vb.z; v[7] = vb.w;
        }
        if (HASN) {
#pragma unroll
          for (int u = 0; u < 8; ++u)
            v[u] = fmaf(v[u], nrm0[kg + u], -nrm1[kg + u]);
        }
#pragma unroll
        for (int u = 0; u < 8; ++u) o[u] = (short)f2bf(v[u]);
      }
      *(short8*)&As[0][slot][kg] = o;
    }
  }
  __syncthreads();

  const int rA = wv * 16 + ln15;
  const int baseIdx = (rA >> L) * (IH + 1) + (rA & (IH - 1));
  constexpr int NT[4] = {4, 2, 2, 1};
  constexpr int TT[4][4] = {{4, 5, 7, 8}, {3, 6, 0, 0}, {1, 2, 0, 0}, {0, 0, 0, 0}};
  const float bv0 = bias[2 * ln15], bv1 = bias[2 * ln15 + 1];
  unsigned* Yp = (unsigned*)Y;
  float cS[2] = {0.f, 0.f}, cQ[2] = {0.f, 0.f};

#pragma unroll
  for (int s = 0; s < NSTRIP; ++s) {
    const int cur = s & 1, nxt = cur ^ 1;
    const int iy0 = iy0base + s * RSPAN;

    short8 rbf[ITER];
    float4 rva[ITER], rvb[ITER];
    bool vld[ITER];
    if (s + 1 < NSTRIP) {
      const int iyN0 = iy0 + RSPAN;
#pragma unroll
      for (int it = 0; it < ITER; ++it) {
        vld[it] = false;
        const int i = tid + it * 256;
        if (i < TI) {
          const int slot = i / (CIN / 8), kg = (i % (CIN / 8)) * 8;
          const int ty = slot / (IH + 1), tx = slot - ty * (IH + 1);
          const int iy = iyN0 + ty;
          if (iy < IH && tx < IH) {
            vld[it] = true;
            if constexpr (INBF) {
              const ushort* xp = (const ushort*)X +
                                 (((size_t)n * IH + iy) * IH + tx) * CIN + kg;
              rbf[it] = *(const short8*)xp;
            } else {
              const float* xp =
                  &X[(((size_t)n * IH + iy) * IH + tx) * CIN + kg];
              rva[it] = *(const float4*)xp;
              rvb[it] = *(const float4*)(xp + 4);
            }
          }
        }
      }
    }

    f32x4 acc[4][2];
#pragma unroll
    for (int p = 0; p < 4; ++p)
#pragma unroll
      for (int f = 0; f < 2; ++f) acc[p][f] = (f32x4){0.f, 0.f, 0.f, 0.f};
#pragma unroll
    for (int sh = 0; sh < 4; ++sh) {
      const int off = (sh >> 1) * (IH + 1) + (sh & 1);
#pragma unroll
      for (int j = 0; j < NT[sh]; ++j) {
        const int t = TT[sh][j];
        const int ky = t / 3, kx = t - ky * 3;
        const int par = ((ky == 1) ? 0 : 2) + ((kx == 1) ? 0 : 1);
#pragma unroll
        for (int ks = 0; ks < CIN / 32; ++ks) {
          const short8 a =
              *(const short8*)&As[cur][baseIdx + off][ks * 32 + quad * 8];
#pragma unroll
          for (int f = 0; f < 2; ++f) {
            const short8 b =
                *(const short8*)&Ws[t * 32 + f * 16 + ln15][ks * 32 + quad * 8];
            acc[par][f] = __builtin_amdgcn_mfma_f32_16x16x32_bf16(
                a, b, acc[par][f], 0, 0, 0);
          }
        }
      }
    }

#pragma unroll
    for (int i = 0; i < 4; ++i) {
      const int rD = wv * 16 + quad * 4 + i;
      const int ry = rD >> L, rx = rD & (IH - 1);
      const int iy = iy0 + ry;
#pragma unroll
      for (int p = 0; p < 4; ++p) {
        const int a = p >> 1, b = p & 1;
        const size_t base =
            (((size_t)n * OH + 2 * iy + a) * OH + 2 * rx + b) * 32;
        const float o0 = lrelu(acc[p][0][i] + bv0);
        const float o1 = lrelu(acc[p][1][i] + bv1);
        cS[0] += o0; cQ[0] += o0 * o0;
        cS[1] += o1; cQ[1] += o1 * o1;
        Yp[(base >> 1) + ln15] = (unsigned)f2bf(o0) | ((unsigned)f2bf(o1) << 16);
      }
    }

    if (s + 1 < NSTRIP) {
#pragma unroll
      for (int it = 0; it < ITER; ++it) {
        const int i = tid + it * 256;
        if (i < TI) {
          const int slot = i / (CIN / 8), kg = (i % (CIN / 8)) * 8;
          short8 o = {0, 0, 0, 0, 0, 0, 0, 0};
          if (vld[it]) {
            float v[8];
            if constexpr (INBF) {
#pragma unroll
              for (int u = 0; u < 8; ++u) v[u] = bf2f((ushort)rbf[it][u]);
            } else {
              v[0] = rva[it].x; v[1] = rva[it].y;
              v[2] = rva[it].z; v[3] = rva[it].w;
              v[4] = rvb[it].x; v[5] = rvb[it].y;
              v[6] = rvb[it].z; v[7] = rvb[it].w;
            }
            if (HASN) {
#pragma unroll
              for (int u = 0; u < 8; ++u)
                v[u] = fmaf(v[u], nrm0[kg + u], -nrm1[kg + u]);
            }
#pragma unroll
            for (int u = 0; u < 8; ++u) o[u] = (short)f2bf(v[u]);
          }
          *(short8*)&As[nxt][slot][kg] = o;
        }
      }
    }
    __syncthreads();
  }

#pragma unroll
  for (int f = 0; f < 2; ++f) {
    float s_ = cS[f], q_ = cQ[f];
    s_ += __shfl_down(s_, 32); s_ += __shfl_down(s_, 16);
    q_ += __shfl_down(q_, 32); q_ += __shfl_down(q_, 16);
    if (lane < 16) { redS[wv][f * 16 + ln15] = s_; redQ[wv][f * 16 + ln15] = q_; }
  }
  __syncthreads();
  if (tid < 32) {
    float S = redS[0][tid] + redS[1][tid] + redS[2][tid] + redS[3][tid];
    float Q = redQ[0][tid] + redQ[1][tid] + redQ[2][tid] + redQ[3][tid];
    const int ch = ((tid & 15) << 1) | (tid >> 4);
    atomicAdd(&stOut[ch], S);
    atomicAdd(&stOut[256 + ch], Q);
  }
}

// ======================= conv1 via MFMA im2col =============================
__global__ __launch_bounds__(256) void conv1_mfma(
    const float* __restrict__ x, const ushort* __restrict__ WT,
    const float* __restrict__ bias, ushort* __restrict__ y,
    float* __restrict__ st) {
  __shared__ float xin[3][17][67];
  __shared__ float redS[4][32], redQ[4][32];
  const int tid = threadIdx.x;
  const int wv = tid >> 6, lane = tid & 63;
  const int quad = lane >> 4, ln15 = lane & 15;
  const short8 bf0 = *(const short8*)&WT[(size_t)lane * 8];
  const short8 bf1 = *(const short8*)&WT[(size_t)(64 + lane) * 8];
  const int n = blockIdx.x >> 2;
  const int oy0 = (blockIdx.x & 3) * 8;
  const int iy0 = 2 * oy0 - 1;
  if (tid < 51) {
    const int ci = tid / 17, r = tid - ci * 17;
    xin[ci][r][0] = 0.f;
  }
  for (int i = tid; i < 816; i += 256) {
    const int ci = i / 272;
    const int r = (i - ci * 272) >> 4;
    const int c4 = (i & 15) << 2;
    const int iy = iy0 + r;
    float4 v = make_float4(0.f, 0.f, 0.f, 0.f);
    if ((unsigned)iy < 64u)
      v = *(const float4*)&x[((size_t)(n * 3 + ci) * 64 + iy) * 64 + c4];
    xin[ci][r][1 + c4] = v.x;
    xin[ci][r][2 + c4] = v.y;
    xin[ci][r][3 + c4] = v.z;
    xin[ci][r][4 + c4] = v.w;
  }
  __syncthreads();

  const float bv0 = bias[2 * ln15], bv1 = bias[2 * ln15 + 1];
  unsigned* Yp = (unsigned*)y;
  float cS[2] = {0.f, 0.f}, cQ[2] = {0.f, 0.f};
#pragma unroll
  for (int rr = 0; rr < 2; ++rr) {
    const int row = 2 * wv + rr;
#pragma unroll
    for (int h = 0; h < 2; ++h) {
      short8 a;
#pragma unroll
      for (int j = 0; j < 8; ++j) {
        const int k = quad * 8 + j;
        float val = 0.f;
        if (k < 27) {
          const int ci = k / 9, r2 = k - ci * 9;
          const int ky = r2 / 3, kx = r2 - ky * 3;
          val = xin[ci][2 * row + ky][2 * (h * 16 + ln15) + kx];
        }
        a[j] = (short)f2bf(val);
      }
      f32x4 acc0 = (f32x4){0.f, 0.f, 0.f, 0.f};
      f32x4 acc1 = (f32x4){0.f, 0.f, 0.f, 0.f};
      acc0 = __builtin_amdgcn_mfma_f32_16x16x32_bf16(a, bf0, acc0, 0, 0, 0);
      acc1 = __builtin_amdgcn_mfma_f32_16x16x32_bf16(a, bf1, acc1, 0, 0, 0);
#pragma unroll
      for (int r = 0; r < 4; ++r) {
        const int px = h * 16 + quad * 4 + r;
        const float o0 = lrelu(acc0[r] + bv0);
        const float o1 = lrelu(acc1[r] + bv1);
        cS[0] += o0; cQ[0] += o0 * o0;
        cS[1] += o1; cQ[1] += o1 * o1;
        Yp[((size_t)n * 1024 + (oy0 + row) * 32 + px) * 16 + ln15] =
            (unsigned)f2bf(o0) | ((unsigned)f2bf(o1) << 16);
      }
    }
  }
#pragma unroll
  for (int f = 0; f < 2; ++f) {
    float s_ = cS[f], q_ = cQ[f];
    s_ += __shfl_down(s_, 32); s_ += __shfl_down(s_, 16);
    q_ += __shfl_down(q_, 32); q_ += __shfl_down(q_, 16);
    if (lane < 16) { redS[wv][f * 16 + ln15] = s_; redQ[wv][f * 16 + ln15] = q_; }
  }
  __syncthreads();
  if (tid < 32) {
    float S = redS[0][tid] + redS[1][tid] + redS[2][tid] + redS[3][tid];
    float Q = redQ[0][tid] + redQ[1][tid] + redQ[2][tid] + redQ[3][tid];
    const int ch = ((tid & 15) << 1) | (tid >> 4);
    atomicAdd(&st[ch], S);
    atomicAdd(&st[256 + ch], Q);
  }
}

// ======================= final convT via MFMA + 4-row LDS ring =============
__global__ __launch_bounds__(256) void convt4_mfma(
    const float* __restrict__ X, const ushort* __restrict__ WT,
    const float* __restrict__ bias, const float* __restrict__ st, float invN,
    float* __restrict__ out) {
  __shared__ short ring[4][66][32];
  __shared__ float s0[32], s1[32];
  const int tid = threadIdx.x;
  const int wv = tid >> 6, lane = tid & 63;
  const int quad = lane >> 4, ln15 = lane & 15;
  if (tid < 32) {
    float m = st[tid] * invN;
    float var = st[256 + tid] * invN - m * m;
    float s = rsqrtf(var + EPS_BN);
    s0[tid] = s;
    s1[tid] = m * s;
  }
  if (tid >= 32 && tid < 64) {
    const int t = tid - 32;
    const int slot = t >> 3, h = (t >> 2) & 1, kg = (t & 3) * 8;
    short8 z = {0, 0, 0, 0, 0, 0, 0, 0};
    *(short8*)&ring[slot][h ? 65 : 0][kg] = z;
  }
  short8 bfrag[9];
#pragma unroll
  for (int s = 0; s < 9; ++s)
    bfrag[s] = *(const short8*)&WT[((size_t)s * 64 + lane) * 8];
  __syncthreads();

  const int n = blockIdx.x >> 2;
  const int y0 = (blockIdx.x & 3) * 16;
  const ushort* xn = (const ushort*)X + (size_t)n * 131072;
  const int spx = tid >> 2, skg = (tid & 3) * 8;

#pragma unroll
  for (int pr = 0; pr < 3; ++pr) {
    const int Y = y0 - 1 + pr;
    short8 o = {0, 0, 0, 0, 0, 0, 0, 0};
    if ((unsigned)Y < 64u) {
      const short8 raw = *(const short8*)&xn[((size_t)Y * 64 + spx) * 32 + skg];
#pragma unroll
      for (int u = 0; u < 8; ++u)
        o[u] = (short)f2bf(fmaf(bf2f((ushort)raw[u]), s0[skg + u], -s1[skg + u]));
    }
    *(short8*)&ring[Y & 3][spx + 1][skg] = o;
  }
  __syncthreads();

  const int x0 = wv * 16;
  const float bv = (ln15 < 3) ? bias[ln15] : 0.f;
  float* op = out + (size_t)n * 3 * 4096;

  for (int y = y0; y < y0 + 16; ++y) {
    const int Ypf = y + 2;
    const bool pre = (Ypf <= y0 + 16);
    short8 raw;
    bool vld = false;
    if (pre && (unsigned)Ypf < 64u) {
      raw = *(const short8*)&xn[((size_t)Ypf * 64 + spx) * 32 + skg];
      vld = true;
    }

    f32x4 acc0 = (f32x4){0.f, 0.f, 0.f, 0.f};
    f32x4 acc1 = (f32x4){0.f, 0.f, 0.f, 0.f};
#pragma unroll
    for (int ty = 0; ty < 3; ++ty) {
      const short* rp = &ring[(y - 1 + ty) & 3][0][0];
#pragma unroll
      for (int tx = 0; tx < 3; ++tx) {
        const short8 a = *(const short8*)&rp[(x0 + ln15 + tx) * 32 + quad * 8];
        const int s = ty * 3 + tx;
        if (s & 1)
          acc1 = __builtin_amdgcn_mfma_f32_16x16x32_bf16(a, bfrag[s], acc1, 0, 0, 0);
        else
          acc0 = __builtin_amdgcn_mfma_f32_16x16x32_bf16(a, bfrag[s], acc0, 0, 0, 0);
      }
    }

    if (ln15 < 3) {
      float4 o;
      float v;
      v = acc0[0] + acc1[0] + bv; o.x = 1.f / (1.f + __expf(-2.f * v));
      v = acc0[1] + acc1[1] + bv; o.y = 1.f / (1.f + __expf(-2.f * v));
      v = acc0[2] + acc1[2] + bv; o.z = 1.f / (1.f + __expf(-2.f * v));
      v = acc0[3] + acc1[3] + bv; o.w = 1.f / (1.f + __expf(-2.f * v));
      *(float4*)&op[(size_t)ln15 * 4096 + y * 64 + x0 + quad * 4] = o;
    }

    if (pre) {
      short8 o = {0, 0, 0, 0, 0, 0, 0, 0};
      if (vld) {
#pragma unroll
        for (int u = 0; u < 8; ++u)
          o[u] = (short)f2bf(
              fmaf(bf2f((ushort)raw[u]), s0[skg + u], -s1[skg + u]));
      }
      *(short8*)&ring[Ypf & 3][spx + 1][skg] = o;
    }
    __syncthreads();
  }
}

// ======================= encoder FC: fused mu||cov split-K fp32 ============
// grid dim3(4,4,8). Rows 0-127 of combined B = wmu, 128-255 = wcov (block-
// column aligned: bx<2 -> wmu, bx>=2 -> wcov). P[z][256][256].
__global__ __launch_bounds__(256) void gemm_enc(
    const float* __restrict__ A, const float* __restrict__ B1,
    const float* __restrict__ B2, const float* __restrict__ stA, float invN,
    float* __restrict__ P, int K) {
  __shared__ float As[16][68];
  __shared__ float Bsh[16][68];
  __shared__ float nrm[2][256];
  const int tid = threadIdx.x;
  {
    const int c = tid;
    float m = stA[c] * invN;
    float var = stA[256 + c] * invN - m * m;
    float s = rsqrtf(var + EPS_BN);
    nrm[0][c] = s;
    nrm[1][c] = m * s;
    __syncthreads();
  }
  const int lm = tid >> 2, lk = (tid & 3) << 2;
  const int KS = gridDim.z;
  const int kChunk = K / KS;
  const int kStart = blockIdx.z * kChunk;
  const float* Bbase = (blockIdx.x < 2) ? B1 : B2;
  const int bx = (blockIdx.x < 2) ? blockIdx.x : blockIdx.x - 2;
  const float* Arow = A + (size_t)(blockIdx.y * 64 + lm) * K + lk;
  const float* Brow = Bbase + (size_t)(bx * 64 + lm) * K + lk;
  float acc[4][4] = {};
  const int m0 = (tid >> 4) << 2, n0 = (tid & 15) << 2;

  for (int k0 = kStart; k0 < kStart + kChunk; k0 += 16) {
    float4 av = *(const float4*)(Arow + k0);
    float4 bv = *(const float4*)(Brow + k0);
    {
      const int ch = (k0 + lk) >> 4;
      const float s = nrm[0][ch], ms = nrm[1][ch];
      av.x = fmaf(av.x, s, -ms);
      av.y = fmaf(av.y, s, -ms);
      av.z = fmaf(av.z, s, -ms);
      av.w = fmaf(av.w, s, -ms);
    }
    As[lk + 0][lm] = av.x; As[lk + 1][lm] = av.y;
    As[lk + 2][lm] = av.z; As[lk + 3][lm] = av.w;
    Bsh[lk + 0][lm] = bv.x; Bsh[lk + 1][lm] = bv.y;
    Bsh[lk + 2][lm] = bv.z; Bsh[lk + 3][lm] = bv.w;
    __syncthreads();
#pragma unroll
    for (int kk = 0; kk < 16; ++kk) {
      const float4 a = *(const float4*)&As[kk][m0];
      const float4 b = *(const float4*)&Bsh[kk][n0];
      acc[0][0] = fmaf(a.x, b.x, acc[0][0]); acc[0][1] = fmaf(a.x, b.y, acc[0][1]);
      acc[0][2] = fmaf(a.x, b.z, acc[0][2]); acc[0][3] = fmaf(a.x, b.w, acc[0][3]);
      acc[1][0] = fmaf(a.y, b.x, acc[1][0]); acc[1][1] = fmaf(a.y, b.y, acc[1][1]);
      acc[1][2] = fmaf(a.y, b.z, acc[1][2]); acc[1][3] = fmaf(a.y, b.w, acc[1][3]);
      acc[2][0] = fmaf(a.z, b.x, acc[2][0]); acc[2][1] = fmaf(a.z, b.y, acc[2][1]);
      acc[2][2] = fmaf(a.z, b.z, acc[2][2]); acc[2][3] = fmaf(a.z, b.w, acc[2][3]);
      acc[3][0] = fmaf(a.w, b.x, acc[3][0]); acc[3][1] = fmaf(a.w, b.y, acc[3][1]);
      acc[3][2] = fmaf(a.w, b.z, acc[3][2]); acc[3][3] = fmaf(a.w, b.w, acc[3][3]);
    }
    __syncthreads();
  }

  const int gm = blockIdx.y * 64 + m0;
  const int gn = blockIdx.x * 64 + n0;
#pragma unroll
  for (int i = 0; i < 4; ++i)
    *(float4*)&P[((size_t)blockIdx.z * 256 + gm + i) * 256 + gn] =
        make_float4(acc[i][0], acc[i][1], acc[i][2], acc[i][3]);
}

__global__ __launch_bounds__(256) void gemm_reduce_enc(
    const float* __restrict__ P, float* __restrict__ ze,
    const float* __restrict__ bcat, int KS) {
  const int idx = blockIdx.x * 256 + threadIdx.x;
  const int m = idx >> 8, n = idx & 255;
  float s = 0.f;
  for (int z = 0; z < KS; ++z) s += P[((size_t)z * 256 + m) * 256 + n];
  float v = s + bcat[n];
  if (n >= 128) v = fmaxf(v, 0.f);
  ze[idx] = v;
}

// ======================= VQ: fused argmin + gather + loss ==================
__global__ __launch_bounds__(256) void vq_argmin_gather(
    const float* __restrict__ d2, const float* __restrict__ ze,
    const float* __restrict__ cb, float* __restrict__ zq,
    float* __restrict__ lossacc) {
  const int b = blockIdx.x, t = threadIdx.x;
  const float* row = d2 + (size_t)b * 8192;
  float best = 3.4e38f;
  int bi = 0x7fffffff;
  for (int k = t; k < 8192; k += 256) {
    const float v = row[k];
    if (v < best) { best = v; bi = k; }
  }
  __shared__ float bval[256];
  __shared__ int bidx[256];
  bval[t] = best;
  bidx[t] = bi;
  __syncthreads();
  for (int s = 128; s > 0; s >>= 1) {
    if (t < s) {
      const float ov = bval[t + s];
      const int oi = bidx[t + s];
      if (ov < bval[t] || (ov == bval[t] && oi < bidx[t])) {
        bval[t] = ov;
        bidx[t] = oi;
      }
    }
    __syncthreads();
  }
  const int sel = bidx[0];
  // gather + loss (shared reuse of bval after all reads done)
  const int i = b * 256 + t;
  const float q = cb[(size_t)sel * 256 + t];
  zq[i] = q;
  const float df = ze[i] - q;
  __syncthreads();
  bval[t] = df * df;
  __syncthreads();
  for (int s = 128; s > 0; s >>= 1) {
    if (t < s) bval[t] += bval[t + s];
    __syncthreads();
  }
  if (t == 0) atomicAdd(lossacc, bval[0]);
}

__global__ void write_loss(const float* __restrict__ lossacc,
                           float* __restrict__ out) {
  out[0] = 2.f * lossacc[0];
}

// ---------------------------------------------------------------------------
extern "C" void kernel_launch(void* const* d_in, const int* in_sizes, int n_in,
                              void* d_out, int out_size, void* d_ws,
                              size_t ws_size, hipStream_t stream) {
  const float* x = (const float*)d_in[0];
  const float* ew1 = (const float*)d_in[1];
  const float* eb1 = (const float*)d_in[2];
  const float* ew2 = (const float*)d_in[3];
  const float* eb2 = (const float*)d_in[4];
  const float* ew3 = (const float*)d_in[5];
  const float* eb3 = (const float*)d_in[6];
  const float* ew4 = (const float*)d_in[7];
  const float* eb4 = (const float*)d_in[8];
  const float* wmu = (const float*)d_in[9];
  const float* bmu = (const float*)d_in[10];
  const float* wcov = (const float*)d_in[11];
  const float* bcov = (const float*)d_in[12];
  const float* cb = (const float*)d_in[13];
  const float* wfc = (const float*)d_in[14];
  const float* bfc = (const float*)d_in[15];
  const float* wt1 = (const float*)d_in[16];
  const float* bt1 = (const float*)d_in[17];
  const float* wt2 = (const float*)d_in[18];
  const float* bt2 = (const float*)d_in[19];
  const float* wt3 = (const float*)d_in[20];
  const float* bt3 = (const float*)d_in[21];
  const float* wt31 = (const float*)d_in[22];
  const float* bt31 = (const float*)d_in[23];
  const float* wt4 = (const float*)d_in[24];
  const float* bt4 = (const float*)d_in[25];

  float* ws = (float*)d_ws;
  float* a1 = ws;               // NHWC [256,32,32,32] bf16 (reused as g3, bf16)
  float* a2 = a1 + 8388608;     // NHWC [256,16,16,64] bf16 (reused as g2, bf16)
  float* a3 = a2 + 4194304;     // NHWC [256,8,8,128] bf16  (reused as g1, bf16)
  float* a4 = a3 + 2097152;     // [256,256,4,4] region     (reused as g0, fp32)
  float* g31 = a4 + 1048576;    // NHWC [256,64,64,32] bf16 (region 33554432 f)
  float* d2 = g31;              // [256,8192]
  float* csq = g31 + 2359296;   // 8192
  float* a4n = g31 + 2367488;   // NCHW a4 (written directly by conv4)
  float* wfcT = g31 + 3416064;  // 1048576
  float* bfcT = g31 + 4464640;  // 4096
  ushort* wTc2 = (ushort*)(g31 + 4468736);  // 18432 bf16
  ushort* wTc3 = (ushort*)(g31 + 4487168);  // 73728 bf16
  ushort* wTc4 = (ushort*)(g31 + 4560896);  // 294912 bf16
  float* P = g31 + 8388608;     // [8][256][256] = 524288 (dead before d2/g31)
  float* ze = g31 + 33554432;   // [256,256]
  float* zq = ze + 65536;
  float* stats = zq + 65536;    // 8 layers x 512
  float* lossacc = stats + 4096;
  ushort* wTt1 = (ushort*)(lossacc + 4 + 256);  // 294912 bf16 (parity,perm)
  ushort* wTt2 = wTt1 + 294912;                 // 73728 bf16 (parity,perm)
  ushort* wTt3 = wTt2 + 73728;                  // 18432 bf16 (tap-major,perm)
  ushort* wTt31 = wTt3 + 18432;                 // 9216 bf16 (tap-major,perm)
  ushort* wT4 = wTt31 + 9216;                   // 4608 bf16 (convt4 B frags)
  ushort* wb1 = wT4 + 4608;                     // 1024 bf16 (conv1 B frags)
  float* bcat = (float*)(wb1 + 1024);           // 256 fp32 (bmu||bcov)
  float* g3 = a1;   // bf16 content
  float* g2 = a2;   // bf16 content
  float* g1 = a3;   // bf16 content
  float* g0 = a4;   // fp32

  float* st0 = stats + 0 * 512;
  float* st1 = stats + 1 * 512;
  float* st2 = stats + 2 * 512;
  float* st3 = stats + 3 * 512;
  float* st4 = stats + 4 * 512;
  float* st5 = stats + 5 * 512;
  float* st6 = stats + 6 * 512;
  float* st7 = stats + 7 * 512;

  hipMemsetAsync(stats, 0, (4096 + 8) * sizeof(float), stream);

  // ---- fused weight prep (12 sub-kernels -> 1) ----
  fused_pre<<<9227, 256, 0, stream>>>(ew2, wTc2, ew3, wTc3, ew4, wTc4, wt1,
                                      wTt1, wt2, wTt2, wt3, wTt3, wt31, wTt31,
                                      wt4, wT4, ew1, wb1, wfc, bfc, wfcT, bfcT,
                                      cb, csq, bmu, bcov, bcat);

  // ---- encoder ----
  conv1_mfma<<<1024, 256, 0, stream>>>(x, wb1, eb1, (ushort*)a1, st0);
  mfmaconv<64, 0, 32, 32, 64, true, true, true, false>
      <<<dim3(1, 1024), 256, 0, stream>>>(a1, wTc2, eb2, st0,
                                          1.f / (256.f * 1024.f), a2, st1);
  mfmaconv<64, 0, 16, 64, 128, true, true, true, false>
      <<<dim3(2, 256), 256, 0, stream>>>(a2, wTc3, eb3, st1,
                                         1.f / (256.f * 256.f), a3, st2);
  mfmaconv<64, 0, 8, 128, 256, true, true, false, true>
      <<<dim3(4, 64), 256, 0, stream>>>(a3, wTc4, eb4, st2,
                                        1.f / (256.f * 64.f), a4n, st3);

  // ---- encoder FC (fp32, fused mu||cov, split-K=8) ----
  gemm_enc<<<dim3(4, 4, 8), 256, 0, stream>>>(a4n, wmu, wcov, st3,
                                              1.f / 4096.f, P, 4096);
  gemm_reduce_enc<<<256, 256, 0, stream>>>(P, ze, bcat, 8);

  // ---- VQ: d2 = csq[n] - 2*ze.cb; fused argmin+gather+loss ----
  gemm_bf_abt<<<dim3(128, 4), 256, 0, stream>>>(ze, cb, csq, d2, 256, 8192,
                                                -2.f);
  vq_argmin_gather<<<256, 256, 0, stream>>>(d2, ze, cb, zq, lossacc);

  // ---- decoder FC (bf16 MFMA) ----
  gemm_bf_abt<<<dim3(64, 4), 256, 0, stream>>>(zq, wfcT, bfcT, g0, 256, 4096,
                                               1.f);

  // ---- decoder ----
  mfmaconv<64, 1, 4, 256, 128, false, false, true, false>
      <<<dim3(2, 64, 4), 256, 0, stream>>>(g0, wTt1, bt1, nullptr, 0.f, g1,
                                           st4);
  mfmaconv<64, 1, 8, 128, 64, true, true, true, false>
      <<<dim3(1, 256, 4), 256, 0, stream>>>(g1, wTt2, bt2, st4,
                                            1.f / (256.f * 64.f), g2, st5);
  convt_mfma<16, 64, true, true, 2><<<512, 256, 0, stream>>>(
      g2, wTt3, bt3, st5, 1.f / (256.f * 256.f), g3, st6);
  convt_mfma<32, 32, true, true, 4><<<1024, 256, 0, stream>>>(
      g3, wTt31, bt31, st6, 1.f / (256.f * 1024.f), g31, st7);

  convt4_mfma<<<1024, 256, 0, stream>>>(g31, wT4, bt4, st7,
                                        1.f / (256.f * 4096.f), (float*)d_out);
  write_loss<<<1, 1, 0, stream>>>(lossacc, (float*)d_out + 3145728);
}

// Round 14
// 417.883 us; speedup vs baseline: 1.5832x; 1.0312x over previous
//
#include <hip/hip_runtime.h>
#include <cmath>

// ---------------------------------------------------------------------------
// VQ-VAE forward. B=256, C=3, HW=64, D=256, K=8192, LAT=128
// R20: convt_mfma strip loop forced to #pragma unroll 1 (R16's NSTRIP=8
// register explosion was the UNROLL, not the strip count: VGPR stays at
// single-strip level with a dynamic loop). With that fixed, t31 NSTRIP
// 4->8 (512 blocks): weight staging + barrier overhead per output halves.
// t3 stays NSTRIP=2 (66KB LDS; deeper strips cost occupancy). Rest
// identical to R19 (430.9us): gemm_enc fused mu||cov, vq_argmin_gather,
// fused_pre, OUTNCHW conv4, OUTBF a2/a3/g1/g2, gemm_bf_abt, R14 k-loop.
// ---------------------------------------------------------------------------

#define EPS_BN 1e-5f
typedef unsigned short ushort;
typedef short short8 __attribute__((ext_vector_type(8)));
typedef ushort us4 __attribute__((ext_vector_type(4)));
typedef float f32x4 __attribute__((ext_vector_type(4)));

__device__ __forceinline__ float lrelu(float v) { return v >= 0.f ? v : 0.01f * v; }
__device__ __forceinline__ ushort f2bf(float f) {
  unsigned u = __float_as_uint(f);
  return (ushort)((u + 0x7FFF + ((u >> 16) & 1)) >> 16);
}
__device__ __forceinline__ float bf2f(ushort u) {
  return __uint_as_float(((unsigned)u) << 16);
}

// ======================= fused weight-prep megakernel ======================
__device__ __forceinline__ void d_convw(const float* __restrict__ w,
                                        ushort* __restrict__ wT, int CIN,
                                        int COUT, int total, int perm, int vb,
                                        int tid) {
  int i = vb * 256 + tid;
  if (i >= total) return;
  int co = i / (9 * CIN);
  int r = i - co * 9 * CIN;
  int t = r / CIN, ci = r - t * CIN;
  int co_s = co;
  if (perm) {
    const int cr = co & 63;
    co_s = (co - cr) + ((cr & 3) << 4) + (cr >> 2);
  }
  wT[(size_t)co_s * 9 * CIN + r] = f2bf(w[((size_t)co * CIN + ci) * 9 + t]);
}

__device__ __forceinline__ void d_convtw(const float* __restrict__ w,
                                         ushort* __restrict__ wT, int CIN,
                                         int COUT, int total, int vb, int tid) {
  int i = vb * 256 + tid;
  if (i >= total) return;
  const int cc = CIN * COUT;
  int p, base, Kp;
  if (i < cc) { p = 0; base = 0; Kp = CIN; }
  else if (i < 3 * cc) { p = 1; base = cc; Kp = 2 * CIN; }
  else if (i < 5 * cc) { p = 2; base = 3 * cc; Kp = 2 * CIN; }
  else { p = 3; base = 5 * cc; Kp = 4 * CIN; }
  const int r = i - base;
  const int co = r / Kp;
  const int q = r - co * Kp;
  const int tix = q / CIN, ci = q - (q / CIN) * CIN;
  const int py = p >> 1, px = p & 1;
  const int nx = px ? 2 : 1;
  const int kyi = tix / nx, kxi = tix - kyi * nx;
  const int ky = py ? (kyi == 0 ? 0 : 2) : 1;
  const int kx = px ? (kxi == 0 ? 0 : 2) : 1;
  const int cr = co & 63;
  const int co_s = (co - cr) + ((cr & 3) << 4) + (cr >> 2);
  wT[base + (size_t)co_s * Kp + q] =
      f2bf(w[((size_t)ci * COUT + co) * 9 + ky * 3 + kx]);
}

__device__ __forceinline__ void d_convtw_tc(const float* __restrict__ w,
                                            ushort* __restrict__ wT, int CIN,
                                            int COUT, int total, int vb,
                                            int tid) {
  int i = vb * 256 + tid;
  if (i >= total) return;
  int ci = i % CIN;
  int tmp = i / CIN;
  int co = tmp % COUT;
  int t = tmp / COUT;
  const int co_slot = ((co & 1) << 4) | (co >> 1);
  wT[((size_t)t * COUT + co_slot) * CIN + ci] =
      f2bf(w[((size_t)ci * COUT + co) * 9 + t]);
}

__device__ __forceinline__ void d_w4(const float* __restrict__ w,
                                     ushort* __restrict__ wT, int vb, int tid) {
  int i = vb * 256 + tid;
  if (i >= 4608) return;
  const int s = i >> 9;
  const int l = (i >> 3) & 63;
  const int j = i & 7;
  const int nn = l & 15;
  const int ci = ((l >> 4) << 3) + j;
  const int ty = s / 3, tx = s - ty * 3;
  ushort v = 0;
  if (nn < 3)
    v = f2bf(w[((size_t)ci * 3 + nn) * 9 + (2 - ty) * 3 + (2 - tx)]);
  wT[i] = v;
}

__device__ __forceinline__ void d_w1b(const float* __restrict__ w,
                                      ushort* __restrict__ wT, int vb,
                                      int tid) {
  int i = vb * 256 + tid;
  if (i >= 1024) return;
  const int j = i & 7, l = (i >> 3) & 63, f = i >> 9;
  const int c = 2 * (l & 15) + f;
  const int k = ((l >> 4) << 3) + j;
  ushort v = 0;
  if (k < 27) {
    const int ci = k / 9, r = k - ci * 9;
    v = f2bf(w[((size_t)c * 3 + ci) * 9 + r]);
  }
  wT[i] = v;
}

__device__ __forceinline__ void d_fcdec(const float* __restrict__ in,
                                        const float* __restrict__ bin,
                                        float* __restrict__ out,
                                        float* __restrict__ bout, int vb,
                                        int tid) {
  int i = vb * 256 + tid;
  int k = i >> 8, d = i & 255;
  int kp = (k & 15) * 256 + (k >> 4);
  out[(size_t)kp * 256 + d] = in[i];
  if (d == 0) bout[kp] = bin[k];
}

__device__ __forceinline__ void d_rowsq(const float* __restrict__ cb,
                                        float* __restrict__ csq, int vb,
                                        int tid) {
  const int row = vb * 4 + (tid >> 6);
  const int ln = tid & 63;
  const float4 v = ((const float4*)(cb + (size_t)row * 256))[ln];
  float s = v.x * v.x + v.y * v.y + v.z * v.z + v.w * v.w;
#pragma unroll
  for (int off = 32; off > 0; off >>= 1) s += __shfl_down(s, off);
  if (ln == 0) csq[row] = s;
}

// block ranges: 72|288|1152|1152|288|72|36|18|4|4096|2048|1 = 9227
__global__ __launch_bounds__(256) void fused_pre(
    const float* __restrict__ ew2, ushort* __restrict__ wTc2,
    const float* __restrict__ ew3, ushort* __restrict__ wTc3,
    const float* __restrict__ ew4, ushort* __restrict__ wTc4,
    const float* __restrict__ wt1, ushort* __restrict__ wTt1,
    const float* __restrict__ wt2, ushort* __restrict__ wTt2,
    const float* __restrict__ wt3, ushort* __restrict__ wTt3,
    const float* __restrict__ wt31, ushort* __restrict__ wTt31,
    const float* __restrict__ wt4, ushort* __restrict__ wT4,
    const float* __restrict__ ew1, ushort* __restrict__ wb1,
    const float* __restrict__ wfc, const float* __restrict__ bfc,
    float* __restrict__ wfcT, float* __restrict__ bfcT,
    const float* __restrict__ cb, float* __restrict__ csq,
    const float* __restrict__ bmu, const float* __restrict__ bcov,
    float* __restrict__ bcat) {
  const int tid = threadIdx.x;
  int b = blockIdx.x;
  if (b < 72) { d_convw(ew2, wTc2, 32, 64, 18432, 1, b, tid); return; }
  b -= 72;
  if (b < 288) { d_convw(ew3, wTc3, 64, 128, 73728, 1, b, tid); return; }
  b -= 288;
  if (b < 1152) { d_convw(ew4, wTc4, 128, 256, 294912, 0, b, tid); return; }
  b -= 1152;
  if (b < 1152) { d_convtw(wt1, wTt1, 256, 128, 294912, b, tid); return; }
  b -= 1152;
  if (b < 288) { d_convtw(wt2, wTt2, 128, 64, 73728, b, tid); return; }
  b -= 288;
  if (b < 72) { d_convtw_tc(wt3, wTt3, 64, 32, 18432, b, tid); return; }
  b -= 72;
  if (b < 36) { d_convtw_tc(wt31, wTt31, 32, 32, 9216, b, tid); return; }
  b -= 36;
  if (b < 18) { d_w4(wt4, wT4, b, tid); return; }
  b -= 18;
  if (b < 4) { d_w1b(ew1, wb1, b, tid); return; }
  b -= 4;
  if (b < 4096) { d_fcdec(wfc, bfc, wfcT, bfcT, b, tid); return; }
  b -= 4096;
  if (b < 2048) { d_rowsq(cb, csq, b, tid); return; }
  bcat[tid] = (tid < 128) ? bmu[tid] : bcov[tid - 128];
}

// ======================= bf16 MFMA implicit-GEMM conv / convT ==============
// R14 pipeline. OUTBF: packed-bf16 output, slot f*16+l = channel 4l+f.
// OUTNCHW (MODE 0 only): scalar fp32 stores directly in NCHW [n][c][px].
template <int TN, int MODE, int IH, int CIN, int COUT, bool HASN, bool INBF,
          bool OUTBF, bool OUTNCHW>
__global__ __launch_bounds__(256) void mfmaconv(
    const float* __restrict__ X, const ushort* __restrict__ WT,
    const float* __restrict__ bias, const float* __restrict__ st, float invN,
    float* __restrict__ Y, float* __restrict__ stOut) {
  constexpr int OH = (MODE == 0) ? IH / 2 : 2 * IH;
  constexpr int NF = TN / 16;
  static_assert(!OUTBF || NF == 4, "OUTBF requires NF==4");
  __shared__ short As[2][64][40];
  __shared__ short Bs[2][TN][40];
  __shared__ float nrm0[HASN ? CIN : 4], nrm1[HASN ? CIN : 4];
  __shared__ float redS[4][TN], redQ[4][TN];
  const int tid = threadIdx.x;
  const int wv = tid >> 6, lane = tid & 63;
  const int quad = lane >> 4, ln15 = tid & 15;
  if (HASN) {
    for (int c = tid; c < CIN; c += 256) {
      float m = st[c] * invN;
      float var = st[256 + c] * invN - m * m;
      float s = rsqrtf(var + EPS_BN);
      nrm0[c] = s;
      nrm1[c] = m * s;
    }
    __syncthreads();
  }
  int py = 0, px = 0, nx = 1, K = 9 * CIN;
  const ushort* W = WT;
  if (MODE == 1) {
    const int pz = blockIdx.z;
    py = pz >> 1;
    px = pz & 1;
    nx = px ? 2 : 1;
    const int ny = py ? 2 : 1;
    K = ny * nx * CIN;
    const int pre[4] = {0, 1, 3, 5};
    W = WT + (size_t)pre[pz] * CIN * COUT;
  }
  const int gyTM = blockIdx.y * 64;
  const int gxTN = blockIdx.x * TN;

  const int sm = tid & 63, skg = (tid >> 6) * 8;
  const int bn = tid >> 2, bkg = (tid & 3) * 8;
  int baseNB, baseIY, baseIX;
  {
    const int gm = gyTM + sm;
    if (MODE == 0) {
      const int ni = gm / (OH * OH), r = gm % (OH * OH);
      baseNB = ni * IH * IH;
      baseIY = 2 * (r / OH) - 1;
      baseIX = 2 * (r % OH) - 1;
    } else {
      const int ni = gm / (IH * IH), r = gm % (IH * IH);
      baseNB = ni * IH * IH;
      baseIY = r / IH;
      baseIX = r % IH;
    }
  }
  f32x4 acc[NF];
#pragma unroll
  for (int f = 0; f < NF; ++f) acc[f] = (f32x4){0.f, 0.f, 0.f, 0.f};

  const int nsteps = K / 32;

  // ---- prologue: stage step 0 into buf 0 ----
  {
    int iy, ix;
    if (MODE == 0) {
      iy = baseIY;
      ix = baseIX;
    } else {
      iy = baseIY + (py ? 1 : 0);
      ix = baseIX + (px ? 1 : 0);
    }
    const bool ok =
        ((unsigned)iy < (unsigned)IH) && ((unsigned)ix < (unsigned)IH);
    float v[8] = {0.f, 0.f, 0.f, 0.f, 0.f, 0.f, 0.f, 0.f};
    if (ok) {
      if constexpr (INBF) {
        const ushort* xp =
            (const ushort*)X + ((size_t)baseNB + iy * IH + ix) * CIN + skg;
        const short8 raw = *(const short8*)xp;
#pragma unroll
        for (int u = 0; u < 8; ++u) v[u] = bf2f((ushort)raw[u]);
      } else {
        const float* xp = &X[((size_t)baseNB + iy * IH + ix) * CIN + skg];
        const float4 va = *(const float4*)xp, vb = *(const float4*)(xp + 4);
        v[0] = va.x; v[1] = va.y; v[2] = va.z; v[3] = va.w;
        v[4] = vb.x; v[5] = vb.y; v[6] = vb.z; v[7] = vb.w;
      }
      if (HASN) {
#pragma unroll
        for (int u = 0; u < 8; ++u)
          v[u] = fmaf(v[u], nrm0[skg + u], -nrm1[skg + u]);
      }
    }
    short8 o;
#pragma unroll
    for (int u = 0; u < 8; ++u) o[u] = (short)f2bf(v[u]);
    *(short8*)&As[0][sm][skg] = o;
    if (tid < TN * 4)
      *(short8*)&Bs[0][bn][bkg] =
          *(const short8*)&W[(size_t)(gxTN + bn) * K + bkg];
  }
  __syncthreads();

  for (int kk = 0; kk < nsteps; ++kk) {
    const int cur = kk & 1, nxt = cur ^ 1;

    bool okN = false;
    int ci0N = 0;
    short8 rawN;
    float4 vaN, vbN;
    short8 rawBN;
    const bool hasNext = (kk + 1 < nsteps);
    if (hasNext) {
      const int k0n = (kk + 1) * 32;
      const int t = k0n / CIN;
      ci0N = k0n - t * CIN;
      int iy, ix;
      if (MODE == 0) {
        iy = baseIY + t / 3;
        ix = baseIX + (t - (t / 3) * 3);
      } else {
        const int kyi = t / nx, kxi = t - (t / nx) * nx;
        iy = baseIY + ((py && kyi == 0) ? 1 : 0);
        ix = baseIX + ((px && kxi == 0) ? 1 : 0);
      }
      okN = ((unsigned)iy < (unsigned)IH) && ((unsigned)ix < (unsigned)IH);
      if (okN) {
        if constexpr (INBF) {
          const ushort* xp = (const ushort*)X +
                             ((size_t)baseNB + iy * IH + ix) * CIN + ci0N + skg;
          rawN = *(const short8*)xp;
        } else {
          const float* xp =
              &X[((size_t)baseNB + iy * IH + ix) * CIN + ci0N + skg];
          vaN = *(const float4*)xp;
          vbN = *(const float4*)(xp + 4);
        }
      }
      if (tid < TN * 4)
        rawBN = *(const short8*)&W[(size_t)(gxTN + bn) * K + k0n + bkg];
    }

    const short8 a = *(const short8*)&As[cur][wv * 16 + ln15][quad * 8];
#pragma unroll
    for (int f = 0; f < NF; ++f) {
      const short8 b = *(const short8*)&Bs[cur][f * 16 + ln15][quad * 8];
      acc[f] = __builtin_amdgcn_mfma_f32_16x16x32_bf16(a, b, acc[f], 0, 0, 0);
    }

    if (hasNext) {
      float v[8] = {0.f, 0.f, 0.f, 0.f, 0.f, 0.f, 0.f, 0.f};
      if (okN) {
        if constexpr (INBF) {
#pragma unroll
          for (int u = 0; u < 8; ++u) v[u] = bf2f((ushort)rawN[u]);
        } else {
          v[0] = vaN.x; v[1] = vaN.y; v[2] = vaN.z; v[3] = vaN.w;
          v[4] = vbN.x; v[5] = vbN.y; v[6] = vbN.z; v[7] = vbN.w;
        }
        if (HASN) {
          const int c = ci0N + skg;
#pragma unroll
          for (int u = 0; u < 8; ++u)
            v[u] = fmaf(v[u], nrm0[c + u], -nrm1[c + u]);
        }
      }
      short8 o;
#pragma unroll
      for (int u = 0; u < 8; ++u) o[u] = (short)f2bf(v[u]);
      *(short8*)&As[nxt][sm][skg] = o;
      if (tid < TN * 4) *(short8*)&Bs[nxt][bn][bkg] = rawBN;
    }
    __syncthreads();
  }

  size_t maddr[4];
#pragma unroll
  for (int r = 0; r < 4; ++r) {
    const int m = gyTM + wv * 16 + quad * 4 + r;
    if (MODE == 0) {
      const int ni = m / (OH * OH), rr = m % (OH * OH);
      if constexpr (OUTNCHW)
        maddr[r] = (size_t)ni * COUT * (OH * OH) + rr;
      else
        maddr[r] = (((size_t)ni * OH + rr / OH) * OH + rr % OH) * COUT;
    } else {
      const int ni = m / (IH * IH), rr = m % (IH * IH);
      const int oy = 2 * (rr / IH) + py, ox = 2 * (rr % IH) + px;
      maddr[r] = (((size_t)ni * OH + oy) * OH + ox) * COUT;
    }
  }
  if constexpr (OUTBF) {
    const int ch0 = gxTN + 4 * ln15;
    const float b0 = bias[ch0 + 0], b1 = bias[ch0 + 1];
    const float b2 = bias[ch0 + 2], b3 = bias[ch0 + 3];
    ushort* Yb = (ushort*)Y;
    float cS[4] = {0.f, 0.f, 0.f, 0.f}, cQ[4] = {0.f, 0.f, 0.f, 0.f};
#pragma unroll
    for (int r = 0; r < 4; ++r) {
      const float o0 = lrelu(acc[0][r] + b0);
      const float o1 = lrelu(acc[1][r] + b1);
      const float o2 = lrelu(acc[2][r] + b2);
      const float o3 = lrelu(acc[3][r] + b3);
      cS[0] += o0; cQ[0] += o0 * o0;
      cS[1] += o1; cQ[1] += o1 * o1;
      cS[2] += o2; cQ[2] += o2 * o2;
      cS[3] += o3; cQ[3] += o3 * o3;
      uint2 pk;
      pk.x = (unsigned)f2bf(o0) | ((unsigned)f2bf(o1) << 16);
      pk.y = (unsigned)f2bf(o2) | ((unsigned)f2bf(o3) << 16);
      *(uint2*)&Yb[maddr[r] + ch0] = pk;
    }
#pragma unroll
    for (int f = 0; f < 4; ++f) {
      float s_ = cS[f], q_ = cQ[f];
      s_ += __shfl_down(s_, 32); s_ += __shfl_down(s_, 16);
      q_ += __shfl_down(q_, 32); q_ += __shfl_down(q_, 16);
      if (lane < 16) { redS[wv][f * 16 + ln15] = s_; redQ[wv][f * 16 + ln15] = q_; }
    }
    __syncthreads();
    if (tid < TN) {
      float S = redS[0][tid] + redS[1][tid] + redS[2][tid] + redS[3][tid];
      float Q = redQ[0][tid] + redQ[1][tid] + redQ[2][tid] + redQ[3][tid];
      const int ch = gxTN + 4 * (tid & 15) + (tid >> 4);
      atomicAdd(&stOut[ch], S);
      atomicAdd(&stOut[256 + ch], Q);
    }
  } else {
#pragma unroll
    for (int f = 0; f < NF; ++f) {
      const int col = gxTN + f * 16 + ln15;
      const float bv = bias[col];
      float cS = 0.f, cQ = 0.f;
#pragma unroll
      for (int r = 0; r < 4; ++r) {
        const float o = lrelu(acc[f][r] + bv);
        cS += o;
        cQ += o * o;
        if constexpr (OUTNCHW)
          Y[maddr[r] + (size_t)col * (OH * OH)] = o;
        else
          Y[maddr[r] + col] = o;
      }
      cS += __shfl_down(cS, 32); cS += __shfl_down(cS, 16);
      cQ += __shfl_down(cQ, 32); cQ += __shfl_down(cQ, 16);
      if (lane < 16) { redS[wv][f * 16 + ln15] = cS; redQ[wv][f * 16 + ln15] = cQ; }
    }
    __syncthreads();
    if (tid < TN) {
      float S = redS[0][tid] + redS[1][tid] + redS[2][tid] + redS[3][tid];
      float Q = redQ[0][tid] + redQ[1][tid] + redQ[2][tid] + redQ[3][tid];
      atomicAdd(&stOut[gxTN + tid], S);
      atomicAdd(&stOut[256 + gxTN + tid], Q);
    }
  }
}

// ======================= bf16 MFMA dense GEMM: C = alpha*(A.B^T) + bias ====
__global__ __launch_bounds__(256) void gemm_bf_abt(
    const float* __restrict__ A, const float* __restrict__ B,
    const float* __restrict__ bias, float* __restrict__ C, int K, int N,
    float alpha) {
  __shared__ short As[2][64][40];
  __shared__ short Bs[2][64][40];
  const int tid = threadIdx.x;
  const int wv = tid >> 6, lane = tid & 63;
  const int quad = lane >> 4, ln15 = lane & 15;
  const int gm0 = blockIdx.y * 64, gn0 = blockIdx.x * 64;
  const int sm = tid & 63, skg = (tid >> 6) * 8;
  const int bn = tid >> 2, bkg = (tid & 3) * 8;
  const float* Ap = A + (size_t)(gm0 + sm) * K + skg;
  const float* Bp = B + (size_t)(gn0 + bn) * K + bkg;
  f32x4 acc[4];
#pragma unroll
  for (int f = 0; f < 4; ++f) acc[f] = (f32x4){0.f, 0.f, 0.f, 0.f};
  const int nsteps = K / 32;

  {
    const float4 va = *(const float4*)Ap, vb = *(const float4*)(Ap + 4);
    short8 o;
    o[0] = (short)f2bf(va.x); o[1] = (short)f2bf(va.y);
    o[2] = (short)f2bf(va.z); o[3] = (short)f2bf(va.w);
    o[4] = (short)f2bf(vb.x); o[5] = (short)f2bf(vb.y);
    o[6] = (short)f2bf(vb.z); o[7] = (short)f2bf(vb.w);
    *(short8*)&As[0][sm][skg] = o;
    const float4 wa = *(const float4*)Bp, wb = *(const float4*)(Bp + 4);
    short8 p;
    p[0] = (short)f2bf(wa.x); p[1] = (short)f2bf(wa.y);
    p[2] = (short)f2bf(wa.z); p[3] = (short)f2bf(wa.w);
    p[4] = (short)f2bf(wb.x); p[5] = (short)f2bf(wb.y);
    p[6] = (short)f2bf(wb.z); p[7] = (short)f2bf(wb.w);
    *(short8*)&Bs[0][bn][bkg] = p;
  }
  __syncthreads();

  for (int kk = 0; kk < nsteps; ++kk) {
    const int cur = kk & 1, nxt = cur ^ 1;
    const bool hasNext = (kk + 1 < nsteps);
    float4 vaN, vbN, waN, wbN;
    if (hasNext) {
      const int k0n = (kk + 1) * 32;
      vaN = *(const float4*)(Ap + k0n);
      vbN = *(const float4*)(Ap + k0n + 4);
      waN = *(const float4*)(Bp + k0n);
      wbN = *(const float4*)(Bp + k0n + 4);
    }

    const short8 a = *(const short8*)&As[cur][wv * 16 + ln15][quad * 8];
#pragma unroll
    for (int f = 0; f < 4; ++f) {
      const short8 b = *(const short8*)&Bs[cur][f * 16 + ln15][quad * 8];
      acc[f] = __builtin_amdgcn_mfma_f32_16x16x32_bf16(a, b, acc[f], 0, 0, 0);
    }

    if (hasNext) {
      short8 o;
      o[0] = (short)f2bf(vaN.x); o[1] = (short)f2bf(vaN.y);
      o[2] = (short)f2bf(vaN.z); o[3] = (short)f2bf(vaN.w);
      o[4] = (short)f2bf(vbN.x); o[5] = (short)f2bf(vbN.y);
      o[6] = (short)f2bf(vbN.z); o[7] = (short)f2bf(vbN.w);
      *(short8*)&As[nxt][sm][skg] = o;
      short8 p;
      p[0] = (short)f2bf(waN.x); p[1] = (short)f2bf(waN.y);
      p[2] = (short)f2bf(waN.z); p[3] = (short)f2bf(waN.w);
      p[4] = (short)f2bf(wbN.x); p[5] = (short)f2bf(wbN.y);
      p[6] = (short)f2bf(wbN.z); p[7] = (short)f2bf(wbN.w);
      *(short8*)&Bs[nxt][bn][bkg] = p;
    }
    __syncthreads();
  }

#pragma unroll
  for (int f = 0; f < 4; ++f) {
    const int col = gn0 + f * 16 + ln15;
    const float bv = bias[col];
#pragma unroll
    for (int r = 0; r < 4; ++r) {
      const int row = gm0 + wv * 16 + quad * 4 + r;
      C[(size_t)row * N + col] = fmaf(alpha, acc[f][r], bv);
    }
  }
}

// ======================= halo-tile merged convT (COUT=32, CIN<=64) =========
// R20: strip loop NOT unrolled (unroll 1) -> VGPR stays single-strip.
template <int IH, int CIN, bool HASN, bool INBF, int NSTRIP>
__global__ __launch_bounds__(256) void convt_mfma(
    const float* __restrict__ X, const ushort* __restrict__ WT,
    const float* __restrict__ bias, const float* __restrict__ st, float invN,
    float* __restrict__ Y, float* __restrict__ stOut) {
  constexpr int OH = 2 * IH;
  constexpr int L = (IH == 32) ? 5 : 4;
  constexpr int RSPAN = 64 / IH;
  constexpr int NP = (RSPAN + 1) * (IH + 1);
  constexpr int LK = CIN + 8;
  constexpr int TI = NP * (CIN / 8);
  constexpr int ITER = (TI + 255) / 256;
  __shared__ short As[2][NP][LK];
  __shared__ short Ws[9 * 32][LK];
  __shared__ float nrm0[HASN ? CIN : 4], nrm1[HASN ? CIN : 4];
  __shared__ float redS[4][32], redQ[4][32];
  const int tid = threadIdx.x;
  const int wv = tid >> 6, lane = tid & 63;
  const int quad = lane >> 4, ln15 = lane & 15;
  if (HASN) {
    for (int c = tid; c < CIN; c += 256) {
      float m = st[c] * invN;
      float var = st[256 + c] * invN - m * m;
      float s = rsqrtf(var + EPS_BN);
      nrm0[c] = s;
      nrm1[c] = m * s;
    }
  }
  for (int i = tid; i < 9 * 32 * (CIN / 8); i += 256) {
    const int row = i / (CIN / 8), kg = (i % (CIN / 8)) * 8;
    *(short8*)&Ws[row][kg] = *(const short8*)&WT[(size_t)row * CIN + kg];
  }
  __syncthreads();

  const int strip0 = blockIdx.x * NSTRIP;
  const int n = (strip0 * 64) / (IH * IH);
  const int iy0base = (strip0 * 64 - n * (IH * IH)) >> L;

#pragma unroll
  for (int it = 0; it < ITER; ++it) {
    const int i = tid + it * 256;
    if (i < TI) {
      const int slot = i / (CIN / 8), kg = (i % (CIN / 8)) * 8;
      const int ty = slot / (IH + 1), tx = slot - ty * (IH + 1);
      const int iy = iy0base + ty;
      short8 o = {0, 0, 0, 0, 0, 0, 0, 0};
      if (iy < IH && tx < IH) {
        float v[8];
        if constexpr (INBF) {
          const ushort* xp =
              (const ushort*)X + (((size_t)n * IH + iy) * IH + tx) * CIN + kg;
          const short8 raw = *(const short8*)xp;
#pragma unroll
          for (int u = 0; u < 8; ++u) v[u] = bf2f((ushort)raw[u]);
        } else {
          const float* xp = &X[(((size_t)n * IH + iy) * IH + tx) * CIN + kg];
          const float4 va = *(const float4*)xp, vb = *(const float4*)(xp + 4);
          v[0] = va.x; v[1] = va.y; v[2] = va.z; v[3] = va.w;
          v[4] = vb.x; v[5] = vb.y; v[6] = vb.z; v[7] = vb.w;
        }
        if (HASN) {
#pragma unroll
          for (int u = 0; u < 8; ++u)
            v[u] = fmaf(v[u], nrm0[kg + u], -nrm1[kg + u]);
        }
#pragma unroll
        for (int u = 0; u < 8; ++u) o[u] = (short)f2bf(v[u]);
      }
      *(short8*)&As[0][slot][kg] = o;
    }
  }
  __syncthreads();

  const int rA = wv * 16 + ln15;
  const int baseIdx = (rA >> L) * (IH + 1) + (rA & (IH - 1));
  constexpr int NT[4] = {4, 2, 2, 1};
  constexpr int TT[4][4] = {{4, 5, 7, 8}, {3, 6, 0, 0}, {1, 2, 0, 0}, {0, 0, 0, 0}};
  const float bv0 = bias[2 * ln15], bv1 = bias[2 * ln15 + 1];
  unsigned* Yp = (unsigned*)Y;
  float cS[2] = {0.f, 0.f}, cQ[2] = {0.f, 0.f};

#pragma unroll 1
  for (int s = 0; s < NSTRIP; ++s) {
    const int cur = s & 1, nxt = cur ^ 1;
    const int iy0 = iy0base + s * RSPAN;

    short8 rbf[ITER];
    float4 rva[ITER], rvb[ITER];
    bool vld[ITER];
    if (s + 1 < NSTRIP) {
      const int iyN0 = iy0 + RSPAN;
#pragma unroll
      for (int it = 0; it < ITER; ++it) {
        vld[it] = false;
        const int i = tid + it * 256;
        if (i < TI) {
          const int slot = i / (CIN / 8), kg = (i % (CIN / 8)) * 8;
          const int ty = slot / (IH + 1), tx = slot - ty * (IH + 1);
          const int iy = iyN0 + ty;
          if (iy < IH && tx < IH) {
            vld[it] = true;
            if constexpr (INBF) {
              const ushort* xp = (const ushort*)X +
                                 (((size_t)n * IH + iy) * IH + tx) * CIN + kg;
              rbf[it] = *(const short8*)xp;
            } else {
              const float* xp =
                  &X[(((size_t)n * IH + iy) * IH + tx) * CIN + kg];
              rva[it] = *(const float4*)xp;
              rvb[it] = *(const float4*)(xp + 4);
            }
          }
        }
      }
    }

    f32x4 acc[4][2];
#pragma unroll
    for (int p = 0; p < 4; ++p)
#pragma unroll
      for (int f = 0; f < 2; ++f) acc[p][f] = (f32x4){0.f, 0.f, 0.f, 0.f};
#pragma unroll
    for (int sh = 0; sh < 4; ++sh) {
      const int off = (sh >> 1) * (IH + 1) + (sh & 1);
#pragma unroll
      for (int j = 0; j < NT[sh]; ++j) {
        const int t = TT[sh][j];
        const int ky = t / 3, kx = t - ky * 3;
        const int par = ((ky == 1) ? 0 : 2) + ((kx == 1) ? 0 : 1);
#pragma unroll
        for (int ks = 0; ks < CIN / 32; ++ks) {
          const short8 a =
              *(const short8*)&As[cur][baseIdx + off][ks * 32 + quad * 8];
#pragma unroll
          for (int f = 0; f < 2; ++f) {
            const short8 b =
                *(const short8*)&Ws[t * 32 + f * 16 + ln15][ks * 32 + quad * 8];
            acc[par][f] = __builtin_amdgcn_mfma_f32_16x16x32_bf16(
                a, b, acc[par][f], 0, 0, 0);
          }
        }
      }
    }

#pragma unroll
    for (int i = 0; i < 4; ++i) {
      const int rD = wv * 16 + quad * 4 + i;
      const int ry = rD >> L, rx = rD & (IH - 1);
      const int iy = iy0 + ry;
#pragma unroll
      for (int p = 0; p < 4; ++p) {
        const int a = p >> 1, b = p & 1;
        const size_t base =
            (((size_t)n * OH + 2 * iy + a) * OH + 2 * rx + b) * 32;
        const float o0 = lrelu(acc[p][0][i] + bv0);
        const float o1 = lrelu(acc[p][1][i] + bv1);
        cS[0] += o0; cQ[0] += o0 * o0;
        cS[1] += o1; cQ[1] += o1 * o1;
        Yp[(base >> 1) + ln15] = (unsigned)f2bf(o0) | ((unsigned)f2bf(o1) << 16);
      }
    }

    if (s + 1 < NSTRIP) {
#pragma unroll
      for (int it = 0; it < ITER; ++it) {
        const int i = tid + it * 256;
        if (i < TI) {
          const int slot = i / (CIN / 8), kg = (i % (CIN / 8)) * 8;
          short8 o = {0, 0, 0, 0, 0, 0, 0, 0};
          if (vld[it]) {
            float v[8];
            if constexpr (INBF) {
#pragma unroll
              for (int u = 0; u < 8; ++u) v[u] = bf2f((ushort)rbf[it][u]);
            } else {
              v[0] = rva[it].x; v[1] = rva[it].y;
              v[2] = rva[it].z; v[3] = rva[it].w;
              v[4] = rvb[it].x; v[5] = rvb[it].y;
              v[6] = rvb[it].z; v[7] = rvb[it].w;
            }
            if (HASN) {
#pragma unroll
              for (int u = 0; u < 8; ++u)
                v[u] = fmaf(v[u], nrm0[kg + u], -nrm1[kg + u]);
            }
#pragma unroll
            for (int u = 0; u < 8; ++u) o[u] = (short)f2bf(v[u]);
          }
          *(short8*)&As[nxt][slot][kg] = o;
        }
      }
    }
    __syncthreads();
  }

#pragma unroll
  for (int f = 0; f < 2; ++f) {
    float s_ = cS[f], q_ = cQ[f];
    s_ += __shfl_down(s_, 32); s_ += __shfl_down(s_, 16);
    q_ += __shfl_down(q_, 32); q_ += __shfl_down(q_, 16);
    if (lane < 16) { redS[wv][f * 16 + ln15] = s_; redQ[wv][f * 16 + ln15] = q_; }
  }
  __syncthreads();
  if (tid < 32) {
    float S = redS[0][tid] + redS[1][tid] + redS[2][tid] + redS[3][tid];
    float Q = redQ[0][tid] + redQ[1][tid] + redQ[2][tid] + redQ[3][tid];
    const int ch = ((tid & 15) << 1) | (tid >> 4);
    atomicAdd(&stOut[ch], S);
    atomicAdd(&stOut[256 + ch], Q);
  }
}

// ======================= conv1 via MFMA im2col =============================
__global__ __launch_bounds__(256) void conv1_mfma(
    const float* __restrict__ x, const ushort* __restrict__ WT,
    const float* __restrict__ bias, ushort* __restrict__ y,
    float* __restrict__ st) {
  __shared__ float xin[3][17][67];
  __shared__ float redS[4][32], redQ[4][32];
  const int tid = threadIdx.x;
  const int wv = tid >> 6, lane = tid & 63;
  const int quad = lane >> 4, ln15 = lane & 15;
  const short8 bf0 = *(const short8*)&WT[(size_t)lane * 8];
  const short8 bf1 = *(const short8*)&WT[(size_t)(64 + lane) * 8];
  const int n = blockIdx.x >> 2;
  const int oy0 = (blockIdx.x & 3) * 8;
  const int iy0 = 2 * oy0 - 1;
  if (tid < 51) {
    const int ci = tid / 17, r = tid - ci * 17;
    xin[ci][r][0] = 0.f;
  }
  for (int i = tid; i < 816; i += 256) {
    const int ci = i / 272;
    const int r = (i - ci * 272) >> 4;
    const int c4 = (i & 15) << 2;
    const int iy = iy0 + r;
    float4 v = make_float4(0.f, 0.f, 0.f, 0.f);
    if ((unsigned)iy < 64u)
      v = *(const float4*)&x[((size_t)(n * 3 + ci) * 64 + iy) * 64 + c4];
    xin[ci][r][1 + c4] = v.x;
    xin[ci][r][2 + c4] = v.y;
    xin[ci][r][3 + c4] = v.z;
    xin[ci][r][4 + c4] = v.w;
  }
  __syncthreads();

  const float bv0 = bias[2 * ln15], bv1 = bias[2 * ln15 + 1];
  unsigned* Yp = (unsigned*)y;
  float cS[2] = {0.f, 0.f}, cQ[2] = {0.f, 0.f};
#pragma unroll
  for (int rr = 0; rr < 2; ++rr) {
    const int row = 2 * wv + rr;
#pragma unroll
    for (int h = 0; h < 2; ++h) {
      short8 a;
#pragma unroll
      for (int j = 0; j < 8; ++j) {
        const int k = quad * 8 + j;
        float val = 0.f;
        if (k < 27) {
          const int ci = k / 9, r2 = k - ci * 9;
          const int ky = r2 / 3, kx = r2 - ky * 3;
          val = xin[ci][2 * row + ky][2 * (h * 16 + ln15) + kx];
        }
        a[j] = (short)f2bf(val);
      }
      f32x4 acc0 = (f32x4){0.f, 0.f, 0.f, 0.f};
      f32x4 acc1 = (f32x4){0.f, 0.f, 0.f, 0.f};
      acc0 = __builtin_amdgcn_mfma_f32_16x16x32_bf16(a, bf0, acc0, 0, 0, 0);
      acc1 = __builtin_amdgcn_mfma_f32_16x16x32_bf16(a, bf1, acc1, 0, 0, 0);
#pragma unroll
      for (int r = 0; r < 4; ++r) {
        const int px = h * 16 + quad * 4 + r;
        const float o0 = lrelu(acc0[r] + bv0);
        const float o1 = lrelu(acc1[r] + bv1);
        cS[0] += o0; cQ[0] += o0 * o0;
        cS[1] += o1; cQ[1] += o1 * o1;
        Yp[((size_t)n * 1024 + (oy0 + row) * 32 + px) * 16 + ln15] =
            (unsigned)f2bf(o0) | ((unsigned)f2bf(o1) << 16);
      }
    }
  }
#pragma unroll
  for (int f = 0; f < 2; ++f) {
    float s_ = cS[f], q_ = cQ[f];
    s_ += __shfl_down(s_, 32); s_ += __shfl_down(s_, 16);
    q_ += __shfl_down(q_, 32); q_ += __shfl_down(q_, 16);
    if (lane < 16) { redS[wv][f * 16 + ln15] = s_; redQ[wv][f * 16 + ln15] = q_; }
  }
  __syncthreads();
  if (tid < 32) {
    float S = redS[0][tid] + redS[1][tid] + redS[2][tid] + redS[3][tid];
    float Q = redQ[0][tid] + redQ[1][tid] + redQ[2][tid] + redQ[3][tid];
    const int ch = ((tid & 15) << 1) | (tid >> 4);
    atomicAdd(&st[ch], S);
    atomicAdd(&st[256 + ch], Q);
  }
}

// ======================= final convT via MFMA + 4-row LDS ring =============
__global__ __launch_bounds__(256) void convt4_mfma(
    const float* __restrict__ X, const ushort* __restrict__ WT,
    const float* __restrict__ bias, const float* __restrict__ st, float invN,
    float* __restrict__ out) {
  __shared__ short ring[4][66][32];
  __shared__ float s0[32], s1[32];
  const int tid = threadIdx.x;
  const int wv = tid >> 6, lane = tid & 63;
  const int quad = lane >> 4, ln15 = lane & 15;
  if (tid < 32) {
    float m = st[tid] * invN;
    float var = st[256 + tid] * invN - m * m;
    float s = rsqrtf(var + EPS_BN);
    s0[tid] = s;
    s1[tid] = m * s;
  }
  if (tid >= 32 && tid < 64) {
    const int t = tid - 32;
    const int slot = t >> 3, h = (t >> 2) & 1, kg = (t & 3) * 8;
    short8 z = {0, 0, 0, 0, 0, 0, 0, 0};
    *(short8*)&ring[slot][h ? 65 : 0][kg] = z;
  }
  short8 bfrag[9];
#pragma unroll
  for (int s = 0; s < 9; ++s)
    bfrag[s] = *(const short8*)&WT[((size_t)s * 64 + lane) * 8];
  __syncthreads();

  const int n = blockIdx.x >> 2;
  const int y0 = (blockIdx.x & 3) * 16;
  const ushort* xn = (const ushort*)X + (size_t)n * 131072;
  const int spx = tid >> 2, skg = (tid & 3) * 8;

#pragma unroll
  for (int pr = 0; pr < 3; ++pr) {
    const int Y = y0 - 1 + pr;
    short8 o = {0, 0, 0, 0, 0, 0, 0, 0};
    if ((unsigned)Y < 64u) {
      const short8 raw = *(const short8*)&xn[((size_t)Y * 64 + spx) * 32 + skg];
#pragma unroll
      for (int u = 0; u < 8; ++u)
        o[u] = (short)f2bf(fmaf(bf2f((ushort)raw[u]), s0[skg + u], -s1[skg + u]));
    }
    *(short8*)&ring[Y & 3][spx + 1][skg] = o;
  }
  __syncthreads();

  const int x0 = wv * 16;
  const float bv = (ln15 < 3) ? bias[ln15] : 0.f;
  float* op = out + (size_t)n * 3 * 4096;

  for (int y = y0; y < y0 + 16; ++y) {
    const int Ypf = y + 2;
    const bool pre = (Ypf <= y0 + 16);
    short8 raw;
    bool vld = false;
    if (pre && (unsigned)Ypf < 64u) {
      raw = *(const short8*)&xn[((size_t)Ypf * 64 + spx) * 32 + skg];
      vld = true;
    }

    f32x4 acc0 = (f32x4){0.f, 0.f, 0.f, 0.f};
    f32x4 acc1 = (f32x4){0.f, 0.f, 0.f, 0.f};
#pragma unroll
    for (int ty = 0; ty < 3; ++ty) {
      const short* rp = &ring[(y - 1 + ty) & 3][0][0];
#pragma unroll
      for (int tx = 0; tx < 3; ++tx) {
        const short8 a = *(const short8*)&rp[(x0 + ln15 + tx) * 32 + quad * 8];
        const int s = ty * 3 + tx;
        if (s & 1)
          acc1 = __builtin_amdgcn_mfma_f32_16x16x32_bf16(a, bfrag[s], acc1, 0, 0, 0);
        else
          acc0 = __builtin_amdgcn_mfma_f32_16x16x32_bf16(a, bfrag[s], acc0, 0, 0, 0);
      }
    }

    if (ln15 < 3) {
      float4 o;
      float v;
      v = acc0[0] + acc1[0] + bv; o.x = 1.f / (1.f + __expf(-2.f * v));
      v = acc0[1] + acc1[1] + bv; o.y = 1.f / (1.f + __expf(-2.f * v));
      v = acc0[2] + acc1[2] + bv; o.z = 1.f / (1.f + __expf(-2.f * v));
      v = acc0[3] + acc1[3] + bv; o.w = 1.f / (1.f + __expf(-2.f * v));
      *(float4*)&op[(size_t)ln15 * 4096 + y * 64 + x0 + quad * 4] = o;
    }

    if (pre) {
      short8 o = {0, 0, 0, 0, 0, 0, 0, 0};
      if (vld) {
#pragma unroll
        for (int u = 0; u < 8; ++u)
          o[u] = (short)f2bf(
              fmaf(bf2f((ushort)raw[u]), s0[skg + u], -s1[skg + u]));
      }
      *(short8*)&ring[Ypf & 3][spx + 1][skg] = o;
    }
    __syncthreads();
  }
}

// ======================= encoder FC: fused mu||cov split-K fp32 ============
__global__ __launch_bounds__(256) void gemm_enc(
    const float* __restrict__ A, const float* __restrict__ B1,
    const float* __restrict__ B2, const float* __restrict__ stA, float invN,
    float* __restrict__ P, int K) {
  __shared__ float As[16][68];
  __shared__ float Bsh[16][68];
  __shared__ float nrm[2][256];
  const int tid = threadIdx.x;
  {
    const int c = tid;
    float m = stA[c] * invN;
    float var = stA[256 + c] * invN - m * m;
    float s = rsqrtf(var + EPS_BN);
    nrm[0][c] = s;
    nrm[1][c] = m * s;
    __syncthreads();
  }
  const int lm = tid >> 2, lk = (tid & 3) << 2;
  const int KS = gridDim.z;
  const int kChunk = K / KS;
  const int kStart = blockIdx.z * kChunk;
  const float* Bbase = (blockIdx.x < 2) ? B1 : B2;
  const int bx = (blockIdx.x < 2) ? blockIdx.x : blockIdx.x - 2;
  const float* Arow = A + (size_t)(blockIdx.y * 64 + lm) * K + lk;
  const float* Brow = Bbase + (size_t)(bx * 64 + lm) * K + lk;
  float acc[4][4] = {};
  const int m0 = (tid >> 4) << 2, n0 = (tid & 15) << 2;

  for (int k0 = kStart; k0 < kStart + kChunk; k0 += 16) {
    float4 av = *(const float4*)(Arow + k0);
    float4 bv = *(const float4*)(Brow + k0);
    {
      const int ch = (k0 + lk) >> 4;
      const float s = nrm[0][ch], ms = nrm[1][ch];
      av.x = fmaf(av.x, s, -ms);
      av.y = fmaf(av.y, s, -ms);
      av.z = fmaf(av.z, s, -ms);
      av.w = fmaf(av.w, s, -ms);
    }
    As[lk + 0][lm] = av.x; As[lk + 1][lm] = av.y;
    As[lk + 2][lm] = av.z; As[lk + 3][lm] = av.w;
    Bsh[lk + 0][lm] = bv.x; Bsh[lk + 1][lm] = bv.y;
    Bsh[lk + 2][lm] = bv.z; Bsh[lk + 3][lm] = bv.w;
    __syncthreads();
#pragma unroll
    for (int kk = 0; kk < 16; ++kk) {
      const float4 a = *(const float4*)&As[kk][m0];
      const float4 b = *(const float4*)&Bsh[kk][n0];
      acc[0][0] = fmaf(a.x, b.x, acc[0][0]); acc[0][1] = fmaf(a.x, b.y, acc[0][1]);
      acc[0][2] = fmaf(a.x, b.z, acc[0][2]); acc[0][3] = fmaf(a.x, b.w, acc[0][3]);
      acc[1][0] = fmaf(a.y, b.x, acc[1][0]); acc[1][1] = fmaf(a.y, b.y, acc[1][1]);
      acc[1][2] = fmaf(a.y, b.z, acc[1][2]); acc[1][3] = fmaf(a.y, b.w, acc[1][3]);
      acc[2][0] = fmaf(a.z, b.x, acc[2][0]); acc[2][1] = fmaf(a.z, b.y, acc[2][1]);
      acc[2][2] = fmaf(a.z, b.z, acc[2][2]); acc[2][3] = fmaf(a.z, b.w, acc[2][3]);
      acc[3][0] = fmaf(a.w, b.x, acc[3][0]); acc[3][1] = fmaf(a.w, b.y, acc[3][1]);
      acc[3][2] = fmaf(a.w, b.z, acc[3][2]); acc[3][3] = fmaf(a.w, b.w, acc[3][3]);
    }
    __syncthreads();
  }

  const int gm = blockIdx.y * 64 + m0;
  const int gn = blockIdx.x * 64 + n0;
#pragma unroll
  for (int i = 0; i < 4; ++i)
    *(float4*)&P[((size_t)blockIdx.z * 256 + gm + i) * 256 + gn] =
        make_float4(acc[i][0], acc[i][1], acc[i][2], acc[i][3]);
}

__global__ __launch_bounds__(256) void gemm_reduce_enc(
    const float* __restrict__ P, float* __restrict__ ze,
    const float* __restrict__ bcat, int KS) {
  const int idx = blockIdx.x * 256 + threadIdx.x;
  const int m = idx >> 8, n = idx & 255;
  float s = 0.f;
  for (int z = 0; z < KS; ++z) s += P[((size_t)z * 256 + m) * 256 + n];
  float v = s + bcat[n];
  if (n >= 128) v = fmaxf(v, 0.f);
  ze[idx] = v;
}

// ======================= VQ: fused argmin + gather + loss ==================
__global__ __launch_bounds__(256) void vq_argmin_gather(
    const float* __restrict__ d2, const float* __restrict__ ze,
    const float* __restrict__ cb, float* __restrict__ zq,
    float* __restrict__ lossacc) {
  const int b = blockIdx.x, t = threadIdx.x;
  const float* row = d2 + (size_t)b * 8192;
  float best = 3.4e38f;
  int bi = 0x7fffffff;
  for (int k = t; k < 8192; k += 256) {
    const float v = row[k];
    if (v < best) { best = v; bi = k; }
  }
  __shared__ float bval[256];
  __shared__ int bidx[256];
  bval[t] = best;
  bidx[t] = bi;
  __syncthreads();
  for (int s = 128; s > 0; s >>= 1) {
    if (t < s) {
      const float ov = bval[t + s];
      const int oi = bidx[t + s];
      if (ov < bval[t] || (ov == bval[t] && oi < bidx[t])) {
        bval[t] = ov;
        bidx[t] = oi;
      }
    }
    __syncthreads();
  }
  const int sel = bidx[0];
  const int i = b * 256 + t;
  const float q = cb[(size_t)sel * 256 + t];
  zq[i] = q;
  const float df = ze[i] - q;
  __syncthreads();
  bval[t] = df * df;
  __syncthreads();
  for (int s = 128; s > 0; s >>= 1) {
    if (t < s) bval[t] += bval[t + s];
    __syncthreads();
  }
  if (t == 0) atomicAdd(lossacc, bval[0]);
}

__global__ void write_loss(const float* __restrict__ lossacc,
                           float* __restrict__ out) {
  out[0] = 2.f * lossacc[0];
}

// ---------------------------------------------------------------------------
extern "C" void kernel_launch(void* const* d_in, const int* in_sizes, int n_in,
                              void* d_out, int out_size, void* d_ws,
                              size_t ws_size, hipStream_t stream) {
  const float* x = (const float*)d_in[0];
  const float* ew1 = (const float*)d_in[1];
  const float* eb1 = (const float*)d_in[2];
  const float* ew2 = (const float*)d_in[3];
  const float* eb2 = (const float*)d_in[4];
  const float* ew3 = (const float*)d_in[5];
  const float* eb3 = (const float*)d_in[6];
  const float* ew4 = (const float*)d_in[7];
  const float* eb4 = (const float*)d_in[8];
  const float* wmu = (const float*)d_in[9];
  const float* bmu = (const float*)d_in[10];
  const float* wcov = (const float*)d_in[11];
  const float* bcov = (const float*)d_in[12];
  const float* cb = (const float*)d_in[13];
  const float* wfc = (const float*)d_in[14];
  const float* bfc = (const float*)d_in[15];
  const float* wt1 = (const float*)d_in[16];
  const float* bt1 = (const float*)d_in[17];
  const float* wt2 = (const float*)d_in[18];
  const float* bt2 = (const float*)d_in[19];
  const float* wt3 = (const float*)d_in[20];
  const float* bt3 = (const float*)d_in[21];
  const float* wt31 = (const float*)d_in[22];
  const float* bt31 = (const float*)d_in[23];
  const float* wt4 = (const float*)d_in[24];
  const float* bt4 = (const float*)d_in[25];

  float* ws = (float*)d_ws;
  float* a1 = ws;               // NHWC [256,32,32,32] bf16 (reused as g3, bf16)
  float* a2 = a1 + 8388608;     // NHWC [256,16,16,64] bf16 (reused as g2, bf16)
  float* a3 = a2 + 4194304;     // NHWC [256,8,8,128] bf16  (reused as g1, bf16)
  float* a4 = a3 + 2097152;     // [256,256,4,4] region     (reused as g0, fp32)
  float* g31 = a4 + 1048576;    // NHWC [256,64,64,32] bf16 (region 33554432 f)
  float* d2 = g31;              // [256,8192]
  float* csq = g31 + 2359296;   // 8192
  float* a4n = g31 + 2367488;   // NCHW a4 (written directly by conv4)
  float* wfcT = g31 + 3416064;  // 1048576
  float* bfcT = g31 + 4464640;  // 4096
  ushort* wTc2 = (ushort*)(g31 + 4468736);  // 18432 bf16
  ushort* wTc3 = (ushort*)(g31 + 4487168);  // 73728 bf16
  ushort* wTc4 = (ushort*)(g31 + 4560896);  // 294912 bf16
  float* P = g31 + 8388608;     // [8][256][256] = 524288 (dead before d2/g31)
  float* ze = g31 + 33554432;   // [256,256]
  float* zq = ze + 65536;
  float* stats = zq + 65536;    // 8 layers x 512
  float* lossacc = stats + 4096;
  ushort* wTt1 = (ushort*)(lossacc + 4 + 256);  // 294912 bf16 (parity,perm)
  ushort* wTt2 = wTt1 + 294912;                 // 73728 bf16 (parity,perm)
  ushort* wTt3 = wTt2 + 73728;                  // 18432 bf16 (tap-major,perm)
  ushort* wTt31 = wTt3 + 18432;                 // 9216 bf16 (tap-major,perm)
  ushort* wT4 = wTt31 + 9216;                   // 4608 bf16 (convt4 B frags)
  ushort* wb1 = wT4 + 4608;                     // 1024 bf16 (conv1 B frags)
  float* bcat = (float*)(wb1 + 1024);           // 256 fp32 (bmu||bcov)
  float* g3 = a1;   // bf16 content
  float* g2 = a2;   // bf16 content
  float* g1 = a3;   // bf16 content
  float* g0 = a4;   // fp32

  float* st0 = stats + 0 * 512;
  float* st1 = stats + 1 * 512;
  float* st2 = stats + 2 * 512;
  float* st3 = stats + 3 * 512;
  float* st4 = stats + 4 * 512;
  float* st5 = stats + 5 * 512;
  float* st6 = stats + 6 * 512;
  float* st7 = stats + 7 * 512;

  hipMemsetAsync(stats, 0, (4096 + 8) * sizeof(float), stream);

  // ---- fused weight prep (12 sub-kernels -> 1) ----
  fused_pre<<<9227, 256, 0, stream>>>(ew2, wTc2, ew3, wTc3, ew4, wTc4, wt1,
                                      wTt1, wt2, wTt2, wt3, wTt3, wt31, wTt31,
                                      wt4, wT4, ew1, wb1, wfc, bfc, wfcT, bfcT,
                                      cb, csq, bmu, bcov, bcat);

  // ---- encoder ----
  conv1_mfma<<<1024, 256, 0, stream>>>(x, wb1, eb1, (ushort*)a1, st0);
  mfmaconv<64, 0, 32, 32, 64, true, true, true, false>
      <<<dim3(1, 1024), 256, 0, stream>>>(a1, wTc2, eb2, st0,
                                          1.f / (256.f * 1024.f), a2, st1);
  mfmaconv<64, 0, 16, 64, 128, true, true, true, false>
      <<<dim3(2, 256), 256, 0, stream>>>(a2, wTc3, eb3, st1,
                                         1.f / (256.f * 256.f), a3, st2);
  mfmaconv<64, 0, 8, 128, 256, true, true, false, true>
      <<<dim3(4, 64), 256, 0, stream>>>(a3, wTc4, eb4, st2,
                                        1.f / (256.f * 64.f), a4n, st3);

  // ---- encoder FC (fp32, fused mu||cov, split-K=8) ----
  gemm_enc<<<dim3(4, 4, 8), 256, 0, stream>>>(a4n, wmu, wcov, st3,
                                              1.f / 4096.f, P, 4096);
  gemm_reduce_enc<<<256, 256, 0, stream>>>(P, ze, bcat, 8);

  // ---- VQ: d2 = csq[n] - 2*ze.cb; fused argmin+gather+loss ----
  gemm_bf_abt<<<dim3(128, 4), 256, 0, stream>>>(ze, cb, csq, d2, 256, 8192,
                                                -2.f);
  vq_argmin_gather<<<256, 256, 0, stream>>>(d2, ze, cb, zq, lossacc);

  // ---- decoder FC (bf16 MFMA) ----
  gemm_bf_abt<<<dim3(64, 4), 256, 0, stream>>>(zq, wfcT, bfcT, g0, 256, 4096,
                                               1.f);

  // ---- decoder ----
  mfmaconv<64, 1, 4, 256, 128, false, false, true, false>
      <<<dim3(2, 64, 4), 256, 0, stream>>>(g0, wTt1, bt1, nullptr, 0.f, g1,
                                           st4);
  mfmaconv<64, 1, 8, 128, 64, true, true, true, false>
      <<<dim3(1, 256, 4), 256, 0, stream>>>(g1, wTt2, bt2, st4,
                                            1.f / (256.f * 64.f), g2, st5);
  convt_mfma<16, 64, true, true, 2><<<512, 256, 0, stream>>>(
      g2, wTt3, bt3, st5, 1.f / (256.f * 256.f), g3, st6);
  convt_mfma<32, 32, true, true, 8><<<512, 256, 0, stream>>>(
      g3, wTt31, bt31, st6, 1.f / (256.f * 1024.f), g31, st7);

  convt4_mfma<<<1024, 256, 0, stream>>>(g31, wT4, bt4, st7,
                                        1.f / (256.f * 4096.f), (float*)d_out);
  write_loss<<<1, 1, 0, stream>>>(lossacc, (float*)d_out + 3145728);
}